// Round 14
// baseline (422.537 us; speedup 1.0000x reference)
//
#include <hip/hip_runtime.h>
#include <hip/hip_bf16.h>

// SimpleMoE: B=2,S=2048 -> 4096 tokens, DIM=1024, FF=4096, E=8, top-2 routing.
// Round 14: r13 GEMM cores untouched (measured best). Rewrote transW1/transW2
// with per-lane 4x4 register transpose: float4 coalesced global reads (4x
// fewer load instrs), 8B LDS writes (~2-way conflicts), 64B-contiguous
// global writes. FC floor raised to 512 for the new tile geometry.

typedef __attribute__((ext_vector_type(8))) short bf16x8;
typedef __attribute__((ext_vector_type(4))) float f32x4;

#define MFMA16(a, b, c) __builtin_amdgcn_mfma_f32_16x16x32_bf16((a), (b), (c), 0, 0, 0)

__device__ __forceinline__ unsigned short f2bf(float f) {
  unsigned u = __builtin_bit_cast(unsigned, f);
  u += 0x7FFFu + ((u >> 16) & 1u);
  return (unsigned short)(u >> 16);
}

__device__ __forceinline__ float bf2f(unsigned short s) {
  return __builtin_bit_cast(float, (unsigned)s << 16);
}

__device__ __forceinline__ void gload_lds16(const void* g, void* l) {
  __builtin_amdgcn_global_load_lds(
      (const __attribute__((address_space(1))) unsigned int*)g,
      (__attribute__((address_space(3))) unsigned int*)l, 16, 0, 0);
}

// inline-asm LDS read: keeps the compiler from serializing ds_read behind
// in-flight global_load_lds (false alias) with a vmcnt(0).
__device__ __forceinline__ bf16x8 ldsr128(const void* p) {
  bf16x8 r;
  unsigned a = (unsigned)(unsigned long long)p;
  asm volatile("ds_read_b128 %0, %1" : "=v"(r) : "v"(a));
  return r;
}

// ---------------- gate: logits (fp64), softmax, top-2, counts; also x->bf16 --
__global__ __launch_bounds__(256) void gate_kernel(
    const float* __restrict__ x, const float* __restrict__ Wg,
    const float* __restrict__ bg, int* __restrict__ tok_e,
    float* __restrict__ tok_w, int* __restrict__ counts,
    unsigned short* __restrict__ xb) {
  const int wave = threadIdx.x >> 6;
  const int lane = threadIdx.x & 63;
  const int t = blockIdx.x * 4 + wave;
  const float* xr = x + (size_t)t * 1024;
  unsigned short* xrow = xb + (size_t)t * 1024;
  double acc[8] = {0, 0, 0, 0, 0, 0, 0, 0};
  for (int i = 0; i < 16; ++i) {
    const int d = i * 64 + lane;
    const float vx = xr[d];
    xrow[d] = f2bf(vx);
    const double xv = (double)vx;
    const float* wr = Wg + d * 8;
#pragma unroll
    for (int e = 0; e < 8; ++e) acc[e] += xv * (double)wr[e];
  }
#pragma unroll
  for (int e = 0; e < 8; ++e) {
    double v = acc[e];
#pragma unroll
    for (int off = 32; off > 0; off >>= 1) v += __shfl_xor(v, off, 64);
    acc[e] = v + (double)bg[e];
  }
  if (lane == 0) {
    int e0 = 0;
#pragma unroll
    for (int e = 1; e < 8; ++e)
      if (acc[e] > acc[e0]) e0 = e;
    int e1 = (e0 == 0) ? 1 : 0;
#pragma unroll
    for (int e = 0; e < 8; ++e) {
      if (e != e0 && acc[e] > acc[e1]) e1 = e;
    }
    const double m = acc[e0];
    double s = 0.0;
#pragma unroll
    for (int e = 0; e < 8; ++e) s += exp(acc[e] - m);
    const double p0 = exp(acc[e0] - m) / s;
    const double p1 = exp(acc[e1] - m) / s;
    const double den = p0 + p1 + 1e-9;
    tok_e[2 * t] = e0;
    tok_e[2 * t + 1] = e1;
    tok_w[2 * t] = (float)(p0 / den);
    tok_w[2 * t + 1] = (float)(p1 / den);
    atomicAdd(&counts[e0], 1);
    atomicAdd(&counts[e1], 1);
  }
}

// ---------------- scan + scatter fused (single block) ----------------
__global__ __launch_bounds__(256) void scan_scatter_kernel(
    const int* __restrict__ counts, const int* __restrict__ tok_e,
    int* __restrict__ offsets, int* __restrict__ pair_token,
    int* __restrict__ tok_slot) {
  __shared__ int scur[8];
  const int tid = threadIdx.x;
  if (tid == 0) {
    int s = 0;
    for (int e = 0; e < 8; ++e) {
      offsets[e] = s;
      scur[e] = s;
      s += counts[e];
    }
  }
  __syncthreads();
  for (int t = tid; t < 4096; t += 256) {
#pragma unroll
    for (int j = 0; j < 2; ++j) {
      const int e = tok_e[2 * t + j];
      const int slot = atomicAdd(&scur[e], 1);
      pair_token[slot] = t;
      tok_slot[2 * t + j] = slot;
    }
  }
}

// -------- W1[e][k][f] -> W1t[e][f-f0][k] (bf16) --------------------------
// 64f x 512k tile; per-lane 4x4 register transpose: float4 coalesced reads,
// 8B LDS writes, 64B-contiguous global writes. grid (FC/64, 2, 8).
__global__ __launch_bounds__(256) void transW1_kernel(
    const float* __restrict__ W1, unsigned short* __restrict__ W1t, int FC,
    int f0) {
  const int e = blockIdx.z;
  const int fb = blockIdx.x * 64;   // f_local base
  const int kb = blockIdx.y * 512;  // k base
  __shared__ __align__(16) unsigned short T[64][520];

  const int tid = threadIdx.x;
  const int fi = (tid & 15) * 4;  // 0..60 (f quad)
  const int kq = (tid >> 4) * 4;  // 0..60 (k quad)
#pragma unroll
  for (int it = 0; it < 8; ++it) {
    const int k0 = it * 64 + kq;
    const float* s = W1 + ((size_t)e * 1024 + kb + k0) * 4096 + f0 + fb + fi;
    const float4 r0 = *(const float4*)s;
    const float4 r1 = *(const float4*)(s + 4096);
    const float4 r2 = *(const float4*)(s + 8192);
    const float4 r3 = *(const float4*)(s + 12288);
    uint2 u;
    u.x = (unsigned)f2bf(r0.x) | ((unsigned)f2bf(r1.x) << 16);
    u.y = (unsigned)f2bf(r2.x) | ((unsigned)f2bf(r3.x) << 16);
    *(uint2*)&T[fi + 0][k0] = u;
    u.x = (unsigned)f2bf(r0.y) | ((unsigned)f2bf(r1.y) << 16);
    u.y = (unsigned)f2bf(r2.y) | ((unsigned)f2bf(r3.y) << 16);
    *(uint2*)&T[fi + 1][k0] = u;
    u.x = (unsigned)f2bf(r0.z) | ((unsigned)f2bf(r1.z) << 16);
    u.y = (unsigned)f2bf(r2.z) | ((unsigned)f2bf(r3.z) << 16);
    *(uint2*)&T[fi + 2][k0] = u;
    u.x = (unsigned)f2bf(r0.w) | ((unsigned)f2bf(r1.w) << 16);
    u.y = (unsigned)f2bf(r2.w) | ((unsigned)f2bf(r3.w) << 16);
    *(uint2*)&T[fi + 3][k0] = u;
  }
  __syncthreads();
  const int fr = tid >> 2;  // 0..63
  const int sg = tid & 3;
  unsigned short* dst = W1t + ((size_t)e * FC + fb + fr) * 1024 + kb;
#pragma unroll
  for (int j = 0; j < 16; ++j) {
    const int c = sg + j * 4;  // 64 x 16B chunks; 4 lanes -> 64B contiguous
    *(uint4*)(dst + c * 8) = *(const uint4*)&T[fr][c * 8];
  }
}

// -------- W2[e][f][d] -> W2t[e][d][f-f0] (bf16) --------------------------
// 64d x 512f tile; same per-lane 4x4 transpose. grid (16, FC/512, 8).
__global__ __launch_bounds__(256) void transW2_kernel(
    const float* __restrict__ W2, unsigned short* __restrict__ W2t, int FC,
    int f0) {
  const int e = blockIdx.z;
  const int db = blockIdx.x * 64;   // d base
  const int fbl = blockIdx.y * 512; // f_local base
  __shared__ __align__(16) unsigned short T[64][520];

  const int tid = threadIdx.x;
  const int di = (tid & 15) * 4;  // d quad
  const int fq = (tid >> 4) * 4;  // f quad
#pragma unroll
  for (int it = 0; it < 8; ++it) {
    const int fl = it * 64 + fq;
    const float* s =
        W2 + ((size_t)e * 4096 + f0 + fbl + fl) * 1024 + db + di;
    const float4 r0 = *(const float4*)s;
    const float4 r1 = *(const float4*)(s + 1024);
    const float4 r2 = *(const float4*)(s + 2048);
    const float4 r3 = *(const float4*)(s + 3072);
    uint2 u;
    u.x = (unsigned)f2bf(r0.x) | ((unsigned)f2bf(r1.x) << 16);
    u.y = (unsigned)f2bf(r2.x) | ((unsigned)f2bf(r3.x) << 16);
    *(uint2*)&T[di + 0][fl] = u;
    u.x = (unsigned)f2bf(r0.y) | ((unsigned)f2bf(r1.y) << 16);
    u.y = (unsigned)f2bf(r2.y) | ((unsigned)f2bf(r3.y) << 16);
    *(uint2*)&T[di + 1][fl] = u;
    u.x = (unsigned)f2bf(r0.z) | ((unsigned)f2bf(r1.z) << 16);
    u.y = (unsigned)f2bf(r2.z) | ((unsigned)f2bf(r3.z) << 16);
    *(uint2*)&T[di + 2][fl] = u;
    u.x = (unsigned)f2bf(r0.w) | ((unsigned)f2bf(r1.w) << 16);
    u.y = (unsigned)f2bf(r2.w) | ((unsigned)f2bf(r3.w) << 16);
    *(uint2*)&T[di + 3][fl] = u;
  }
  __syncthreads();
  const int dr = tid >> 2;  // 0..63
  const int sg = tid & 3;
  unsigned short* dst = W2t + ((size_t)e * 1024 + db + dr) * FC + fbl;
#pragma unroll
  for (int j = 0; j < 16; ++j) {
    const int c = sg + j * 4;
    *(uint4*)(dst + c * 8) = *(const uint4*)&T[dr][c * 8];
  }
}

// Interleaved ds_read / MFMA compute body (counted lgkmcnt; DS in-order).
#define COMPUTE_BODY(ALDS, BLDS)                                          \
  {                                                                       \
    bf16x8 af[4], bfr[4];                                                 \
    af[0] = ldsr128(&ALDS[rdA[0]]);                                       \
    bfr[0] = ldsr128(&BLDS[rdB[0]]);                                      \
    af[1] = ldsr128(&ALDS[rdA[1]]);                                       \
    bfr[1] = ldsr128(&BLDS[rdB[1]]);                                      \
    af[2] = ldsr128(&ALDS[rdA[2]]);                                       \
    bfr[2] = ldsr128(&BLDS[rdB[2]]);                                      \
    af[3] = ldsr128(&ALDS[rdA[3]]);                                       \
    bfr[3] = ldsr128(&BLDS[rdB[3]]);                                      \
    asm volatile("s_waitcnt lgkmcnt(6)" ::: "memory");                    \
    __builtin_amdgcn_sched_barrier(0);                                    \
    acc[0][0] = MFMA16(af[0], bfr[0], acc[0][0]);                         \
    __builtin_amdgcn_sched_barrier(0);                                    \
    asm volatile("s_waitcnt lgkmcnt(4)" ::: "memory");                    \
    __builtin_amdgcn_sched_barrier(0);                                    \
    acc[0][1] = MFMA16(af[0], bfr[1], acc[0][1]);                         \
    acc[1][0] = MFMA16(af[1], bfr[0], acc[1][0]);                         \
    acc[1][1] = MFMA16(af[1], bfr[1], acc[1][1]);                         \
    __builtin_amdgcn_sched_barrier(0);                                    \
    asm volatile("s_waitcnt lgkmcnt(2)" ::: "memory");                    \
    __builtin_amdgcn_sched_barrier(0);                                    \
    acc[0][2] = MFMA16(af[0], bfr[2], acc[0][2]);                         \
    acc[1][2] = MFMA16(af[1], bfr[2], acc[1][2]);                         \
    acc[2][0] = MFMA16(af[2], bfr[0], acc[2][0]);                         \
    acc[2][1] = MFMA16(af[2], bfr[1], acc[2][1]);                         \
    acc[2][2] = MFMA16(af[2], bfr[2], acc[2][2]);                         \
    __builtin_amdgcn_sched_barrier(0);                                    \
    asm volatile("s_waitcnt lgkmcnt(0)" ::: "memory");                    \
    __builtin_amdgcn_sched_barrier(0);                                    \
    acc[0][3] = MFMA16(af[0], bfr[3], acc[0][3]);                         \
    acc[1][3] = MFMA16(af[1], bfr[3], acc[1][3]);                         \
    acc[2][3] = MFMA16(af[2], bfr[3], acc[2][3]);                         \
    acc[3][0] = MFMA16(af[3], bfr[0], acc[3][0]);                         \
    acc[3][1] = MFMA16(af[3], bfr[1], acc[3][1]);                         \
    acc[3][2] = MFMA16(af[3], bfr[2], acc[3][2]);                         \
    acc[3][3] = MFMA16(af[3], bfr[3], acc[3][3]);                         \
    __builtin_amdgcn_sched_barrier(0);                                    \
  }

// ---------------- GEMM1: H[slot][n] = relu(xb[tok] @ W1t[e] + b1) -----------
// 128x128 tile, BK=32, 4 waves 2x2, gload_lds + XOR swizzle, 2-buf counted.
// n-fastest tile order (r10/r13).
__global__ __launch_bounds__(256) void gemm1_kernel(
    const unsigned short* __restrict__ xb,
    const unsigned short* __restrict__ W1t, const float* __restrict__ b1,
    const int* __restrict__ counts, const int* __restrict__ offsets,
    const int* __restrict__ pair_token, unsigned short* __restrict__ H, int FC,
    int f0, int NT) {
  const int bid = blockIdx.x;
  const int e = bid & 7;  // XCD pinning
  const int lid = bid >> 3;
  const int n0 = (lid % NT) * 128;
  const int m0 = (lid / NT) * 128;
  const int count = counts[e];
  if (m0 >= count) return;
  const int offset = offsets[e];

  __shared__ __align__(16) unsigned short Alds[2][128 * 32];
  __shared__ __align__(16) unsigned short Blds[2][128 * 32];
  __shared__ int toklds[128];

  const int tid = threadIdx.x;
  if (tid < 128) {
    int r = m0 + tid;
    if (r >= count) r = count - 1;
    toklds[tid] = pair_token[offset + r];
  }
  __syncthreads();

  const int lane = tid & 63;
  const int wave = tid >> 6;
  const int srow = lane >> 2;
  const int kc = lane & 3;
  const unsigned short* aga[2];
  const unsigned short* bga[2];
  int ldso[2];
#pragma unroll
  for (int i = 0; i < 2; ++i) {
    const int ar = wave * 32 + i * 16 + srow;
    const int xr = (ar >> 1) & 3;  // source-chunk XOR swizzle
    aga[i] = xb + (size_t)toklds[ar] * 1024 + (kc ^ xr) * 8;
    bga[i] = W1t + ((size_t)e * FC + n0 + ar) * 1024 + (kc ^ xr) * 8;
    ldso[i] = (wave * 32 + i * 16) * 32;
  }

  const int wm = (wave >> 1) * 64;
  const int wn = (wave & 1) * 64;
  const int l16 = lane & 15;
  const int lk = lane >> 4;
  int rdA[4], rdB[4];
#pragma unroll
  for (int mi = 0; mi < 4; ++mi) {
    const int row = wm + mi * 16 + l16;
    rdA[mi] = row * 32 + ((lk ^ ((row >> 1) & 3)) << 3);
  }
#pragma unroll
  for (int nj = 0; nj < 4; ++nj) {
    const int f = wn + nj * 16 + l16;
    rdB[nj] = f * 32 + ((lk ^ ((f >> 1) & 3)) << 3);
  }

  f32x4 acc[4][4] = {};

  auto STAGE = [&](int kt, int buf) {
#pragma unroll
    for (int i = 0; i < 2; ++i) {
      gload_lds16(aga[i] + kt, &Alds[buf][ldso[i]]);
      gload_lds16(bga[i] + kt, &Blds[buf][ldso[i]]);
    }
  };

  const int NTk = 32;  // K = 1024
  STAGE(0, 0);
  for (int t = 0; t < NTk; ++t) {
    __builtin_amdgcn_s_barrier();  // all waves done reading buf[(t+1)&1]
    if (t + 1 < NTk) {
      STAGE((t + 1) * 32, (t + 1) & 1);
      asm volatile("s_waitcnt vmcnt(4)" ::: "memory");  // t's loads landed
    } else {
      asm volatile("s_waitcnt vmcnt(0)" ::: "memory");
    }
    __builtin_amdgcn_s_barrier();  // buf[t&1] staged by all waves
    __builtin_amdgcn_sched_barrier(0);
    COMPUTE_BODY(Alds[t & 1], Blds[t & 1]);
  }

#pragma unroll
  for (int mi = 0; mi < 4; ++mi) {
#pragma unroll
    for (int r = 0; r < 4; ++r) {
      const int rl = m0 + wm + mi * 16 + lk * 4 + r;
      if (rl >= count) continue;
      unsigned short* hrow = H + (size_t)(offset + rl) * FC;
#pragma unroll
      for (int nj = 0; nj < 4; ++nj) {
        const int c = n0 + wn + nj * 16 + l16;
        float v = acc[mi][nj][r] + b1[e * 4096 + f0 + c];
        hrow[c] = f2bf(v > 0.f ? v : 0.f);
      }
    }
  }
}

// ------- GEMM2: P[ks][slot][d] (bf16) = slice_ks(H[slot] @ W2t[e]) (+ b2) ---
// split-K=2, private bf16 partial buffers, n-fastest (r10/r13 order).
__global__ __launch_bounds__(256) void gemm2_kernel(
    const unsigned short* __restrict__ H,
    const unsigned short* __restrict__ W2t, const float* __restrict__ b2,
    const int* __restrict__ counts, const int* __restrict__ offsets,
    unsigned short* __restrict__ P, int FC, int firstChunk) {
  const int bid = blockIdx.x;
  const int e = bid & 7;  // XCD pinning
  const int r2 = bid >> 3;
  const int n0 = (r2 & 7) * 128;          // 8 n-tiles (N=1024), fastest
  const int m0 = ((r2 >> 3) & 31) * 128;  // 32 m-tiles
  const int ks = r2 >> 8;                 // K split 0/1
  const int count = counts[e];
  if (m0 >= count) return;
  const int offset = offsets[e];
  const int KS = FC / 2;
  const int kb = ks * KS;
  unsigned short* Pb = P + (size_t)ks * 8192 * 1024;

  __shared__ __align__(16) unsigned short Alds[2][128 * 32];
  __shared__ __align__(16) unsigned short Blds[2][128 * 32];

  const int tid = threadIdx.x;
  const int lane = tid & 63;
  const int wave = tid >> 6;
  const int srow = lane >> 2;
  const int kc = lane & 3;
  const unsigned short* aga[2];
  const unsigned short* bga[2];
  int ldso[2];
#pragma unroll
  for (int i = 0; i < 2; ++i) {
    const int tr = wave * 32 + i * 16 + srow;
    int ar = m0 + tr;
    if (ar >= count) ar = count - 1;
    const int xr = (tr >> 1) & 3;
    aga[i] = H + (size_t)(offset + ar) * FC + kb + (kc ^ xr) * 8;
    bga[i] = W2t + ((size_t)e * 1024 + n0 + tr) * FC + kb + (kc ^ xr) * 8;
    ldso[i] = (wave * 32 + i * 16) * 32;
  }

  const int wm = (wave >> 1) * 64;
  const int wn = (wave & 1) * 64;
  const int l16 = lane & 15;
  const int lk = lane >> 4;
  int rdA[4], rdB[4];
#pragma unroll
  for (int mi = 0; mi < 4; ++mi) {
    const int row = wm + mi * 16 + l16;
    rdA[mi] = row * 32 + ((lk ^ ((row >> 1) & 3)) << 3);
  }
#pragma unroll
  for (int nj = 0; nj < 4; ++nj) {
    const int f = wn + nj * 16 + l16;
    rdB[nj] = f * 32 + ((lk ^ ((f >> 1) & 3)) << 3);
  }

  f32x4 acc[4][4] = {};

  auto STAGE = [&](int kt, int buf) {
#pragma unroll
    for (int i = 0; i < 2; ++i) {
      gload_lds16(aga[i] + kt, &Alds[buf][ldso[i]]);
      gload_lds16(bga[i] + kt, &Blds[buf][ldso[i]]);
    }
  };

  const int NTk = KS / 32;
  STAGE(0, 0);
  for (int t = 0; t < NTk; ++t) {
    __builtin_amdgcn_s_barrier();
    if (t + 1 < NTk) {
      STAGE((t + 1) * 32, (t + 1) & 1);
      asm volatile("s_waitcnt vmcnt(4)" ::: "memory");
    } else {
      asm volatile("s_waitcnt vmcnt(0)" ::: "memory");
    }
    __builtin_amdgcn_s_barrier();
    __builtin_amdgcn_sched_barrier(0);
    COMPUTE_BODY(Alds[t & 1], Blds[t & 1]);
  }

#pragma unroll
  for (int mi = 0; mi < 4; ++mi) {
#pragma unroll
    for (int r = 0; r < 4; ++r) {
      const int rl = m0 + wm + mi * 16 + lk * 4 + r;
      if (rl >= count) continue;
      unsigned short* prow = Pb + (size_t)(offset + rl) * 1024;
#pragma unroll
      for (int nj = 0; nj < 4; ++nj) {
        const int c = n0 + wn + nj * 16 + l16;
        float v = acc[mi][nj][r];
        if (ks == 0 && firstChunk) v += b2[e * 1024 + c];
        if (firstChunk) {
          prow[c] = f2bf(v);
        } else {
          prow[c] = f2bf(bf2f(prow[c]) + v);
        }
      }
    }
  }
}

// ---- combine: out[t] = w0*(P0[s0]+P1[s0]) + w1*(P0[s1]+P1[s1]) (bf16 P) ----
__global__ __launch_bounds__(256) void combine_kernel(
    const unsigned short* __restrict__ P, const int* __restrict__ tok_slot,
    const float* __restrict__ tok_w, float* __restrict__ out) {
  const int t = blockIdx.x;
  const int d = threadIdx.x * 4;
  const int s0 = tok_slot[2 * t];
  const int s1 = tok_slot[2 * t + 1];
  const float w0 = tok_w[2 * t];
  const float w1 = tok_w[2 * t + 1];
  const ushort4 a0 = *(const ushort4*)&P[(size_t)s0 * 1024 + d];
  const ushort4 a1 = *(const ushort4*)&P[(size_t)(8192 + s0) * 1024 + d];
  const ushort4 c0 = *(const ushort4*)&P[(size_t)s1 * 1024 + d];
  const ushort4 c1 = *(const ushort4*)&P[(size_t)(8192 + s1) * 1024 + d];
  float4 r;
  r.x = w0 * (bf2f(a0.x) + bf2f(a1.x)) + w1 * (bf2f(c0.x) + bf2f(c1.x));
  r.y = w0 * (bf2f(a0.y) + bf2f(a1.y)) + w1 * (bf2f(c0.y) + bf2f(c1.y));
  r.z = w0 * (bf2f(a0.z) + bf2f(a1.z)) + w1 * (bf2f(c0.z) + bf2f(c1.z));
  r.w = w0 * (bf2f(a0.w) + bf2f(a1.w)) + w1 * (bf2f(c0.w) + bf2f(c1.w));
  *(float4*)&out[(size_t)t * 1024 + d] = r;
}

extern "C" void kernel_launch(void* const* d_in, const int* in_sizes, int n_in,
                              void* d_out, int out_size, void* d_ws,
                              size_t ws_size, hipStream_t stream) {
  const float* x = (const float*)d_in[0];
  const float* Wg = (const float*)d_in[1];
  const float* bg = (const float*)d_in[2];
  const float* W1 = (const float*)d_in[3];
  const float* b1 = (const float*)d_in[4];
  const float* W2 = (const float*)d_in[5];
  const float* b2 = (const float*)d_in[6];
  float* out = (float*)d_out;

  char* w = (char*)d_ws;
  int* counts = (int*)w;
  int* offsets = counts + 16;
  int* tok_e = (int*)(w + 1024);
  float* tok_w = (float*)(w + 1024 + 32768);
  int* pair_token = (int*)(w + 1024 + 65536);
  int* tok_slot = (int*)(w + 1024 + 98304);
  unsigned short* xb = (unsigned short*)(w + 256 * 1024);  // 8MB
  unsigned short* P =
      (unsigned short*)(w + 256 * 1024 + 8 * 1024 * 1024);  // 32MB bf16 x2
  char* big = w + 256 * 1024 + 8 * 1024 * 1024 + 32 * 1024 * 1024;
  const size_t avail =
      ws_size - (256 * 1024 + 8 * 1024 * 1024 + 32 * 1024 * 1024);

  // per-chunk: W1t 16384*FC + W2t 16384*FC + H 16384*FC bytes
  int FC = 4096;
  while (FC > 512 && (size_t)FC * 49152 > avail) FC >>= 1;

  unsigned short* W1t = (unsigned short*)big;
  unsigned short* W2t = W1t + (size_t)8 * FC * 1024;
  unsigned short* Hc = W2t + (size_t)8 * 1024 * FC;

  (void)hipMemsetAsync(counts, 0, 64, stream);

  gate_kernel<<<1024, 256, 0, stream>>>(x, Wg, bg, tok_e, tok_w, counts, xb);
  scan_scatter_kernel<<<1, 256, 0, stream>>>(counts, tok_e, offsets,
                                             pair_token, tok_slot);

  const int NT = FC / 128;
  for (int f0 = 0; f0 < 4096; f0 += FC) {
    transW1_kernel<<<dim3(FC / 64, 2, 8), 256, 0, stream>>>(W1, W1t, FC, f0);
    transW2_kernel<<<dim3(16, FC / 512, 8), 256, 0, stream>>>(W2, W2t, FC, f0);
    gemm1_kernel<<<8 * 32 * NT, 256, 0, stream>>>(
        xb, W1t, b1, counts, offsets, pair_token, Hc, FC, f0, NT);
    gemm2_kernel<<<8 * 8 * 32 * 2, 256, 0, stream>>>(
        Hc, W2t, b2, counts, offsets, P, FC, f0 == 0 ? 1 : 0);
  }
  combine_kernel<<<4096, 256, 0, stream>>>(P, tok_slot, tok_w, out);
}

// Round 15
// 340.910 us; speedup vs baseline: 1.2394x; 1.2394x over previous
//
#include <hip/hip_runtime.h>
#include <hip/hip_bf16.h>

// SimpleMoE: B=2,S=2048 -> 4096 tokens, DIM=1024, FF=4096, E=8, top-2 routing.
// Round 15: GEMM cores frozen (r13 best). Launch-count + traffic cuts:
//  - transW1+transW2 merged into one kernel (1-D grid decode)
//  - counts computed in scan_scatter (no memset, no gate atomics)
//  - gemm2 split-K removed (was neutral; halves P traffic, 1 less rounding)
// 10 launches -> 6.

typedef __attribute__((ext_vector_type(8))) short bf16x8;
typedef __attribute__((ext_vector_type(4))) float f32x4;

#define MFMA16(a, b, c) __builtin_amdgcn_mfma_f32_16x16x32_bf16((a), (b), (c), 0, 0, 0)

__device__ __forceinline__ unsigned short f2bf(float f) {
  unsigned u = __builtin_bit_cast(unsigned, f);
  u += 0x7FFFu + ((u >> 16) & 1u);
  return (unsigned short)(u >> 16);
}

__device__ __forceinline__ float bf2f(unsigned short s) {
  return __builtin_bit_cast(float, (unsigned)s << 16);
}

__device__ __forceinline__ void gload_lds16(const void* g, void* l) {
  __builtin_amdgcn_global_load_lds(
      (const __attribute__((address_space(1))) unsigned int*)g,
      (__attribute__((address_space(3))) unsigned int*)l, 16, 0, 0);
}

// inline-asm LDS read: keeps the compiler from serializing ds_read behind
// in-flight global_load_lds (false alias) with a vmcnt(0).
__device__ __forceinline__ bf16x8 ldsr128(const void* p) {
  bf16x8 r;
  unsigned a = (unsigned)(unsigned long long)p;
  asm volatile("ds_read_b128 %0, %1" : "=v"(r) : "v"(a));
  return r;
}

// ---------------- gate: logits (fp64), softmax, top-2; also x->bf16 ---------
__global__ __launch_bounds__(256) void gate_kernel(
    const float* __restrict__ x, const float* __restrict__ Wg,
    const float* __restrict__ bg, int* __restrict__ tok_e,
    float* __restrict__ tok_w, unsigned short* __restrict__ xb) {
  const int wave = threadIdx.x >> 6;
  const int lane = threadIdx.x & 63;
  const int t = blockIdx.x * 4 + wave;
  const float* xr = x + (size_t)t * 1024;
  unsigned short* xrow = xb + (size_t)t * 1024;
  double acc[8] = {0, 0, 0, 0, 0, 0, 0, 0};
  for (int i = 0; i < 16; ++i) {
    const int d = i * 64 + lane;
    const float vx = xr[d];
    xrow[d] = f2bf(vx);
    const double xv = (double)vx;
    const float* wr = Wg + d * 8;
#pragma unroll
    for (int e = 0; e < 8; ++e) acc[e] += xv * (double)wr[e];
  }
#pragma unroll
  for (int e = 0; e < 8; ++e) {
    double v = acc[e];
#pragma unroll
    for (int off = 32; off > 0; off >>= 1) v += __shfl_xor(v, off, 64);
    acc[e] = v + (double)bg[e];
  }
  if (lane == 0) {
    int e0 = 0;
#pragma unroll
    for (int e = 1; e < 8; ++e)
      if (acc[e] > acc[e0]) e0 = e;
    int e1 = (e0 == 0) ? 1 : 0;
#pragma unroll
    for (int e = 0; e < 8; ++e) {
      if (e != e0 && acc[e] > acc[e1]) e1 = e;
    }
    const double m = acc[e0];
    double s = 0.0;
#pragma unroll
    for (int e = 0; e < 8; ++e) s += exp(acc[e] - m);
    const double p0 = exp(acc[e0] - m) / s;
    const double p1 = exp(acc[e1] - m) / s;
    const double den = p0 + p1 + 1e-9;
    tok_e[2 * t] = e0;
    tok_e[2 * t + 1] = e1;
    tok_w[2 * t] = (float)(p0 / den);
    tok_w[2 * t + 1] = (float)(p1 / den);
  }
}

// ------- scan + scatter (single block); computes counts internally ----------
__global__ __launch_bounds__(256) void scan_scatter_kernel(
    const int* __restrict__ tok_e, int* __restrict__ counts,
    int* __restrict__ offsets, int* __restrict__ pair_token,
    int* __restrict__ tok_slot) {
  __shared__ int scnt[8];
  __shared__ int scur[8];
  const int tid = threadIdx.x;
  if (tid < 8) scnt[tid] = 0;
  __syncthreads();
  for (int i = tid; i < 8192; i += 256) atomicAdd(&scnt[tok_e[i]], 1);
  __syncthreads();
  if (tid == 0) {
    int s = 0;
    for (int e = 0; e < 8; ++e) {
      counts[e] = scnt[e];
      offsets[e] = s;
      scur[e] = s;
      s += scnt[e];
    }
  }
  __syncthreads();
  for (int t = tid; t < 4096; t += 256) {
#pragma unroll
    for (int j = 0; j < 2; ++j) {
      const int e = tok_e[2 * t + j];
      const int slot = atomicAdd(&scur[e], 1);
      pair_token[slot] = t;
      tok_slot[2 * t + j] = slot;
    }
  }
}

// -------- merged weight transpose: W1 -> W1t and W2 -> W2t (bf16) -----------
// W1 blocks: 64f x 512k tile of W1[e][k][f] -> W1t[e][f-f0][k]
// W2 blocks: 64d x 512f tile of W2[e][f][d] -> W2t[e][d][f-f0]
// per-lane 4x4 register transpose; float4 coalesced reads; 64B-contig writes.
__global__ __launch_bounds__(256) void transW_kernel(
    const float* __restrict__ W1, const float* __restrict__ W2,
    unsigned short* __restrict__ W1t, unsigned short* __restrict__ W2t, int FC,
    int f0, int nW1) {
  __shared__ __align__(16) unsigned short T[64][520];
  const int tid = threadIdx.x;
  const int qi = (tid & 15) * 4;  // inner (contiguous-dim) quad
  const int qo = (tid >> 4) * 4;  // outer quad

  const float* src;       // base of 4-row x 4-col fp32 block start
  size_t srcStride;       // stride between outer rows (fp32 elems)
  unsigned short* dstBase;  // output: row r (inner dim) -> dstBase + r*dstStride
  size_t dstStride;

  const int bid = blockIdx.x;
  if (bid < nW1) {
    const int nf = FC / 64;
    const int e = bid / (2 * nf);
    const int rem = bid % (2 * nf);
    const int fb = (rem % nf) * 64;
    const int kb = (rem / nf) * 512;
    src = W1 + ((size_t)e * 1024 + kb) * 4096 + f0 + fb + qi;
    srcStride = 4096;
    dstBase = W1t + ((size_t)e * FC + fb) * 1024 + kb;
    dstStride = 1024;
  } else {
    const int jd = bid - nW1;
    const int nf = FC / 512;
    const int e = jd / (16 * nf);
    const int rem = jd % (16 * nf);
    const int db = (rem % 16) * 64;
    const int fbl = (rem / 16) * 512;
    src = W2 + ((size_t)e * 4096 + f0 + fbl) * 1024 + db + qi;
    srcStride = 1024;
    dstBase = W2t + ((size_t)e * 1024 + db) * FC + fbl;
    dstStride = FC;
  }

#pragma unroll
  for (int it = 0; it < 8; ++it) {
    const int o0 = it * 64 + qo;
    const float* s = src + (size_t)o0 * srcStride;
    const float4 r0 = *(const float4*)s;
    const float4 r1 = *(const float4*)(s + srcStride);
    const float4 r2 = *(const float4*)(s + 2 * srcStride);
    const float4 r3 = *(const float4*)(s + 3 * srcStride);
    uint2 u;
    u.x = (unsigned)f2bf(r0.x) | ((unsigned)f2bf(r1.x) << 16);
    u.y = (unsigned)f2bf(r2.x) | ((unsigned)f2bf(r3.x) << 16);
    *(uint2*)&T[qi + 0][o0] = u;
    u.x = (unsigned)f2bf(r0.y) | ((unsigned)f2bf(r1.y) << 16);
    u.y = (unsigned)f2bf(r2.y) | ((unsigned)f2bf(r3.y) << 16);
    *(uint2*)&T[qi + 1][o0] = u;
    u.x = (unsigned)f2bf(r0.z) | ((unsigned)f2bf(r1.z) << 16);
    u.y = (unsigned)f2bf(r2.z) | ((unsigned)f2bf(r3.z) << 16);
    *(uint2*)&T[qi + 2][o0] = u;
    u.x = (unsigned)f2bf(r0.w) | ((unsigned)f2bf(r1.w) << 16);
    u.y = (unsigned)f2bf(r2.w) | ((unsigned)f2bf(r3.w) << 16);
    *(uint2*)&T[qi + 3][o0] = u;
  }
  __syncthreads();
  const int rr = tid >> 2;  // 0..63 (inner-dim row)
  const int sg = tid & 3;
  unsigned short* dst = dstBase + (size_t)rr * dstStride;
#pragma unroll
  for (int j = 0; j < 16; ++j) {
    const int c = sg + j * 4;  // 4 lanes -> 64B contiguous per instr
    *(uint4*)(dst + c * 8) = *(const uint4*)&T[rr][c * 8];
  }
}

// Interleaved ds_read / MFMA compute body (counted lgkmcnt; DS in-order).
#define COMPUTE_BODY(ALDS, BLDS)                                          \
  {                                                                       \
    bf16x8 af[4], bfr[4];                                                 \
    af[0] = ldsr128(&ALDS[rdA[0]]);                                       \
    bfr[0] = ldsr128(&BLDS[rdB[0]]);                                      \
    af[1] = ldsr128(&ALDS[rdA[1]]);                                       \
    bfr[1] = ldsr128(&BLDS[rdB[1]]);                                      \
    af[2] = ldsr128(&ALDS[rdA[2]]);                                       \
    bfr[2] = ldsr128(&BLDS[rdB[2]]);                                      \
    af[3] = ldsr128(&ALDS[rdA[3]]);                                       \
    bfr[3] = ldsr128(&BLDS[rdB[3]]);                                      \
    asm volatile("s_waitcnt lgkmcnt(6)" ::: "memory");                    \
    __builtin_amdgcn_sched_barrier(0);                                    \
    acc[0][0] = MFMA16(af[0], bfr[0], acc[0][0]);                         \
    __builtin_amdgcn_sched_barrier(0);                                    \
    asm volatile("s_waitcnt lgkmcnt(4)" ::: "memory");                    \
    __builtin_amdgcn_sched_barrier(0);                                    \
    acc[0][1] = MFMA16(af[0], bfr[1], acc[0][1]);                         \
    acc[1][0] = MFMA16(af[1], bfr[0], acc[1][0]);                         \
    acc[1][1] = MFMA16(af[1], bfr[1], acc[1][1]);                         \
    __builtin_amdgcn_sched_barrier(0);                                    \
    asm volatile("s_waitcnt lgkmcnt(2)" ::: "memory");                    \
    __builtin_amdgcn_sched_barrier(0);                                    \
    acc[0][2] = MFMA16(af[0], bfr[2], acc[0][2]);                         \
    acc[1][2] = MFMA16(af[1], bfr[2], acc[1][2]);                         \
    acc[2][0] = MFMA16(af[2], bfr[0], acc[2][0]);                         \
    acc[2][1] = MFMA16(af[2], bfr[1], acc[2][1]);                         \
    acc[2][2] = MFMA16(af[2], bfr[2], acc[2][2]);                         \
    __builtin_amdgcn_sched_barrier(0);                                    \
    asm volatile("s_waitcnt lgkmcnt(0)" ::: "memory");                    \
    __builtin_amdgcn_sched_barrier(0);                                    \
    acc[0][3] = MFMA16(af[0], bfr[3], acc[0][3]);                         \
    acc[1][3] = MFMA16(af[1], bfr[3], acc[1][3]);                         \
    acc[2][3] = MFMA16(af[2], bfr[3], acc[2][3]);                         \
    acc[3][0] = MFMA16(af[3], bfr[0], acc[3][0]);                         \
    acc[3][1] = MFMA16(af[3], bfr[1], acc[3][1]);                         \
    acc[3][2] = MFMA16(af[3], bfr[2], acc[3][2]);                         \
    acc[3][3] = MFMA16(af[3], bfr[3], acc[3][3]);                         \
    __builtin_amdgcn_sched_barrier(0);                                    \
  }

// ---------------- GEMM1: H[slot][n] = relu(xb[tok] @ W1t[e] + b1) -----------
// 128x128 tile, BK=32, 4 waves 2x2, gload_lds + XOR swizzle, 2-buf counted.
// n-fastest tile order (r10/r13).
__global__ __launch_bounds__(256) void gemm1_kernel(
    const unsigned short* __restrict__ xb,
    const unsigned short* __restrict__ W1t, const float* __restrict__ b1,
    const int* __restrict__ counts, const int* __restrict__ offsets,
    const int* __restrict__ pair_token, unsigned short* __restrict__ H, int FC,
    int f0, int NT) {
  const int bid = blockIdx.x;
  const int e = bid & 7;  // XCD pinning
  const int lid = bid >> 3;
  const int n0 = (lid % NT) * 128;
  const int m0 = (lid / NT) * 128;
  const int count = counts[e];
  if (m0 >= count) return;
  const int offset = offsets[e];

  __shared__ __align__(16) unsigned short Alds[2][128 * 32];
  __shared__ __align__(16) unsigned short Blds[2][128 * 32];
  __shared__ int toklds[128];

  const int tid = threadIdx.x;
  if (tid < 128) {
    int r = m0 + tid;
    if (r >= count) r = count - 1;
    toklds[tid] = pair_token[offset + r];
  }
  __syncthreads();

  const int lane = tid & 63;
  const int wave = tid >> 6;
  const int srow = lane >> 2;
  const int kc = lane & 3;
  const unsigned short* aga[2];
  const unsigned short* bga[2];
  int ldso[2];
#pragma unroll
  for (int i = 0; i < 2; ++i) {
    const int ar = wave * 32 + i * 16 + srow;
    const int xr = (ar >> 1) & 3;  // source-chunk XOR swizzle
    aga[i] = xb + (size_t)toklds[ar] * 1024 + (kc ^ xr) * 8;
    bga[i] = W1t + ((size_t)e * FC + n0 + ar) * 1024 + (kc ^ xr) * 8;
    ldso[i] = (wave * 32 + i * 16) * 32;
  }

  const int wm = (wave >> 1) * 64;
  const int wn = (wave & 1) * 64;
  const int l16 = lane & 15;
  const int lk = lane >> 4;
  int rdA[4], rdB[4];
#pragma unroll
  for (int mi = 0; mi < 4; ++mi) {
    const int row = wm + mi * 16 + l16;
    rdA[mi] = row * 32 + ((lk ^ ((row >> 1) & 3)) << 3);
  }
#pragma unroll
  for (int nj = 0; nj < 4; ++nj) {
    const int f = wn + nj * 16 + l16;
    rdB[nj] = f * 32 + ((lk ^ ((f >> 1) & 3)) << 3);
  }

  f32x4 acc[4][4] = {};

  auto STAGE = [&](int kt, int buf) {
#pragma unroll
    for (int i = 0; i < 2; ++i) {
      gload_lds16(aga[i] + kt, &Alds[buf][ldso[i]]);
      gload_lds16(bga[i] + kt, &Blds[buf][ldso[i]]);
    }
  };

  const int NTk = 32;  // K = 1024
  STAGE(0, 0);
  for (int t = 0; t < NTk; ++t) {
    __builtin_amdgcn_s_barrier();  // all waves done reading buf[(t+1)&1]
    if (t + 1 < NTk) {
      STAGE((t + 1) * 32, (t + 1) & 1);
      asm volatile("s_waitcnt vmcnt(4)" ::: "memory");  // t's loads landed
    } else {
      asm volatile("s_waitcnt vmcnt(0)" ::: "memory");
    }
    __builtin_amdgcn_s_barrier();  // buf[t&1] staged by all waves
    __builtin_amdgcn_sched_barrier(0);
    COMPUTE_BODY(Alds[t & 1], Blds[t & 1]);
  }

#pragma unroll
  for (int mi = 0; mi < 4; ++mi) {
#pragma unroll
    for (int r = 0; r < 4; ++r) {
      const int rl = m0 + wm + mi * 16 + lk * 4 + r;
      if (rl >= count) continue;
      unsigned short* hrow = H + (size_t)(offset + rl) * FC;
#pragma unroll
      for (int nj = 0; nj < 4; ++nj) {
        const int c = n0 + wn + nj * 16 + l16;
        float v = acc[mi][nj][r] + b1[e * 4096 + f0 + c];
        hrow[c] = f2bf(v > 0.f ? v : 0.f);
      }
    }
  }
}

// ------- GEMM2: P[slot][d] (bf16) (+)= H[slot] @ W2t[e] (+ b2) --------------
// no split-K; n-fastest (r10/r13 order).
__global__ __launch_bounds__(256) void gemm2_kernel(
    const unsigned short* __restrict__ H,
    const unsigned short* __restrict__ W2t, const float* __restrict__ b2,
    const int* __restrict__ counts, const int* __restrict__ offsets,
    unsigned short* __restrict__ P, int FC, int firstChunk) {
  const int bid = blockIdx.x;
  const int e = bid & 7;  // XCD pinning
  const int r2 = bid >> 3;
  const int n0 = (r2 & 7) * 128;   // 8 n-tiles (N=1024), fastest
  const int m0 = (r2 >> 3) * 128;  // 32 m-tiles
  const int count = counts[e];
  if (m0 >= count) return;
  const int offset = offsets[e];

  __shared__ __align__(16) unsigned short Alds[2][128 * 32];
  __shared__ __align__(16) unsigned short Blds[2][128 * 32];

  const int tid = threadIdx.x;
  const int lane = tid & 63;
  const int wave = tid >> 6;
  const int srow = lane >> 2;
  const int kc = lane & 3;
  const unsigned short* aga[2];
  const unsigned short* bga[2];
  int ldso[2];
#pragma unroll
  for (int i = 0; i < 2; ++i) {
    const int tr = wave * 32 + i * 16 + srow;
    int ar = m0 + tr;
    if (ar >= count) ar = count - 1;
    const int xr = (tr >> 1) & 3;
    aga[i] = H + (size_t)(offset + ar) * FC + (kc ^ xr) * 8;
    bga[i] = W2t + ((size_t)e * 1024 + n0 + tr) * FC + (kc ^ xr) * 8;
    ldso[i] = (wave * 32 + i * 16) * 32;
  }

  const int wm = (wave >> 1) * 64;
  const int wn = (wave & 1) * 64;
  const int l16 = lane & 15;
  const int lk = lane >> 4;
  int rdA[4], rdB[4];
#pragma unroll
  for (int mi = 0; mi < 4; ++mi) {
    const int row = wm + mi * 16 + l16;
    rdA[mi] = row * 32 + ((lk ^ ((row >> 1) & 3)) << 3);
  }
#pragma unroll
  for (int nj = 0; nj < 4; ++nj) {
    const int f = wn + nj * 16 + l16;
    rdB[nj] = f * 32 + ((lk ^ ((f >> 1) & 3)) << 3);
  }

  f32x4 acc[4][4] = {};

  auto STAGE = [&](int kt, int buf) {
#pragma unroll
    for (int i = 0; i < 2; ++i) {
      gload_lds16(aga[i] + kt, &Alds[buf][ldso[i]]);
      gload_lds16(bga[i] + kt, &Blds[buf][ldso[i]]);
    }
  };

  const int NTk = FC / 32;
  STAGE(0, 0);
  for (int t = 0; t < NTk; ++t) {
    __builtin_amdgcn_s_barrier();
    if (t + 1 < NTk) {
      STAGE((t + 1) * 32, (t + 1) & 1);
      asm volatile("s_waitcnt vmcnt(4)" ::: "memory");
    } else {
      asm volatile("s_waitcnt vmcnt(0)" ::: "memory");
    }
    __builtin_amdgcn_s_barrier();
    __builtin_amdgcn_sched_barrier(0);
    COMPUTE_BODY(Alds[t & 1], Blds[t & 1]);
  }

#pragma unroll
  for (int mi = 0; mi < 4; ++mi) {
#pragma unroll
    for (int r = 0; r < 4; ++r) {
      const int rl = m0 + wm + mi * 16 + lk * 4 + r;
      if (rl >= count) continue;
      unsigned short* prow = P + (size_t)(offset + rl) * 1024;
#pragma unroll
      for (int nj = 0; nj < 4; ++nj) {
        const int c = n0 + wn + nj * 16 + l16;
        float v = acc[mi][nj][r];
        if (firstChunk) {
          prow[c] = f2bf(v + b2[e * 1024 + c]);
        } else {
          prow[c] = f2bf(bf2f(prow[c]) + v);
        }
      }
    }
  }
}

// ---------------- combine: out[t] = w0*P[s0] + w1*P[s1] (bf16 P) ------------
__global__ __launch_bounds__(256) void combine_kernel(
    const unsigned short* __restrict__ P, const int* __restrict__ tok_slot,
    const float* __restrict__ tok_w, float* __restrict__ out) {
  const int t = blockIdx.x;
  const int d = threadIdx.x * 4;
  const int s0 = tok_slot[2 * t];
  const int s1 = tok_slot[2 * t + 1];
  const float w0 = tok_w[2 * t];
  const float w1 = tok_w[2 * t + 1];
  const ushort4 a = *(const ushort4*)&P[(size_t)s0 * 1024 + d];
  const ushort4 b = *(const ushort4*)&P[(size_t)s1 * 1024 + d];
  float4 r;
  r.x = w0 * bf2f(a.x) + w1 * bf2f(b.x);
  r.y = w0 * bf2f(a.y) + w1 * bf2f(b.y);
  r.z = w0 * bf2f(a.z) + w1 * bf2f(b.z);
  r.w = w0 * bf2f(a.w) + w1 * bf2f(b.w);
  *(float4*)&out[(size_t)t * 1024 + d] = r;
}

extern "C" void kernel_launch(void* const* d_in, const int* in_sizes, int n_in,
                              void* d_out, int out_size, void* d_ws,
                              size_t ws_size, hipStream_t stream) {
  const float* x = (const float*)d_in[0];
  const float* Wg = (const float*)d_in[1];
  const float* bg = (const float*)d_in[2];
  const float* W1 = (const float*)d_in[3];
  const float* b1 = (const float*)d_in[4];
  const float* W2 = (const float*)d_in[5];
  const float* b2 = (const float*)d_in[6];
  float* out = (float*)d_out;

  char* w = (char*)d_ws;
  int* counts = (int*)w;
  int* offsets = counts + 16;
  int* tok_e = (int*)(w + 1024);
  float* tok_w = (float*)(w + 1024 + 32768);
  int* pair_token = (int*)(w + 1024 + 65536);
  int* tok_slot = (int*)(w + 1024 + 98304);
  unsigned short* xb = (unsigned short*)(w + 256 * 1024);  // 8MB
  unsigned short* P =
      (unsigned short*)(w + 256 * 1024 + 8 * 1024 * 1024);  // 16MB bf16
  char* big = w + 256 * 1024 + 8 * 1024 * 1024 + 16 * 1024 * 1024;
  const size_t avail =
      ws_size - (256 * 1024 + 8 * 1024 * 1024 + 16 * 1024 * 1024);

  // per-chunk: W1t 16384*FC + W2t 16384*FC + H 16384*FC bytes
  int FC = 4096;
  while (FC > 512 && (size_t)FC * 49152 > avail) FC >>= 1;

  unsigned short* W1t = (unsigned short*)big;
  unsigned short* W2t = W1t + (size_t)8 * FC * 1024;
  unsigned short* Hc = W2t + (size_t)8 * 1024 * FC;

  gate_kernel<<<1024, 256, 0, stream>>>(x, Wg, bg, tok_e, tok_w, xb);
  scan_scatter_kernel<<<1, 256, 0, stream>>>(tok_e, counts, offsets,
                                             pair_token, tok_slot);

  const int NT = FC / 128;
  const int nW1 = (FC / 64) * 2 * 8;     // W1 transpose blocks
  const int nW2 = 16 * (FC / 512) * 8;   // W2 transpose blocks
  for (int f0 = 0; f0 < 4096; f0 += FC) {
    transW_kernel<<<nW1 + nW2, 256, 0, stream>>>(W1, W2, W1t, W2t, FC, f0,
                                                 nW1);
    gemm1_kernel<<<8 * 32 * NT, 256, 0, stream>>>(
        xb, W1t, b1, counts, offsets, pair_token, Hc, FC, f0, NT);
    gemm2_kernel<<<8 * 8 * 32, 256, 0, stream>>>(
        Hc, W2t, b2, counts, offsets, P, FC, f0 == 0 ? 1 : 0);
  }
  combine_kernel<<<4096, 256, 0, stream>>>(P, tok_slot, tok_w, out);
}

// Round 16
// 333.343 us; speedup vs baseline: 1.2676x; 1.0227x over previous
//
#include <hip/hip_runtime.h>
#include <hip/hip_bf16.h>

// SimpleMoE: B=2,S=2048 -> 4096 tokens, DIM=1024, FF=4096, E=8, top-2 routing.
// Round 16: BK=32 -> BK=64 in both GEMMs (32 MFMA per barrier-pair, halved
// sync frequency; vmcnt(8) staging, lgkmcnt(8/0) two-half compute; 3-bit XOR
// chunk swizzle for the 128B-row-stride LDS tiles). Rest identical to r15.

typedef __attribute__((ext_vector_type(8))) short bf16x8;
typedef __attribute__((ext_vector_type(4))) float f32x4;

#define MFMA16(a, b, c) __builtin_amdgcn_mfma_f32_16x16x32_bf16((a), (b), (c), 0, 0, 0)

__device__ __forceinline__ unsigned short f2bf(float f) {
  unsigned u = __builtin_bit_cast(unsigned, f);
  u += 0x7FFFu + ((u >> 16) & 1u);
  return (unsigned short)(u >> 16);
}

__device__ __forceinline__ float bf2f(unsigned short s) {
  return __builtin_bit_cast(float, (unsigned)s << 16);
}

__device__ __forceinline__ void gload_lds16(const void* g, void* l) {
  __builtin_amdgcn_global_load_lds(
      (const __attribute__((address_space(1))) unsigned int*)g,
      (__attribute__((address_space(3))) unsigned int*)l, 16, 0, 0);
}

// inline-asm LDS read: keeps the compiler from serializing ds_read behind
// in-flight global_load_lds (false alias) with a vmcnt(0).
__device__ __forceinline__ bf16x8 ldsr128(const void* p) {
  bf16x8 r;
  unsigned a = (unsigned)(unsigned long long)p;
  asm volatile("ds_read_b128 %0, %1" : "=v"(r) : "v"(a));
  return r;
}

// ---------------- gate: logits (fp64), softmax, top-2; also x->bf16 ---------
__global__ __launch_bounds__(256) void gate_kernel(
    const float* __restrict__ x, const float* __restrict__ Wg,
    const float* __restrict__ bg, int* __restrict__ tok_e,
    float* __restrict__ tok_w, unsigned short* __restrict__ xb) {
  const int wave = threadIdx.x >> 6;
  const int lane = threadIdx.x & 63;
  const int t = blockIdx.x * 4 + wave;
  const float* xr = x + (size_t)t * 1024;
  unsigned short* xrow = xb + (size_t)t * 1024;
  double acc[8] = {0, 0, 0, 0, 0, 0, 0, 0};
  for (int i = 0; i < 16; ++i) {
    const int d = i * 64 + lane;
    const float vx = xr[d];
    xrow[d] = f2bf(vx);
    const double xv = (double)vx;
    const float* wr = Wg + d * 8;
#pragma unroll
    for (int e = 0; e < 8; ++e) acc[e] += xv * (double)wr[e];
  }
#pragma unroll
  for (int e = 0; e < 8; ++e) {
    double v = acc[e];
#pragma unroll
    for (int off = 32; off > 0; off >>= 1) v += __shfl_xor(v, off, 64);
    acc[e] = v + (double)bg[e];
  }
  if (lane == 0) {
    int e0 = 0;
#pragma unroll
    for (int e = 1; e < 8; ++e)
      if (acc[e] > acc[e0]) e0 = e;
    int e1 = (e0 == 0) ? 1 : 0;
#pragma unroll
    for (int e = 0; e < 8; ++e) {
      if (e != e0 && acc[e] > acc[e1]) e1 = e;
    }
    const double m = acc[e0];
    double s = 0.0;
#pragma unroll
    for (int e = 0; e < 8; ++e) s += exp(acc[e] - m);
    const double p0 = exp(acc[e0] - m) / s;
    const double p1 = exp(acc[e1] - m) / s;
    const double den = p0 + p1 + 1e-9;
    tok_e[2 * t] = e0;
    tok_e[2 * t + 1] = e1;
    tok_w[2 * t] = (float)(p0 / den);
    tok_w[2 * t + 1] = (float)(p1 / den);
  }
}

// ------- scan + scatter (single block); computes counts internally ----------
__global__ __launch_bounds__(256) void scan_scatter_kernel(
    const int* __restrict__ tok_e, int* __restrict__ counts,
    int* __restrict__ offsets, int* __restrict__ pair_token,
    int* __restrict__ tok_slot) {
  __shared__ int scnt[8];
  __shared__ int scur[8];
  const int tid = threadIdx.x;
  if (tid < 8) scnt[tid] = 0;
  __syncthreads();
  for (int i = tid; i < 8192; i += 256) atomicAdd(&scnt[tok_e[i]], 1);
  __syncthreads();
  if (tid == 0) {
    int s = 0;
    for (int e = 0; e < 8; ++e) {
      counts[e] = scnt[e];
      offsets[e] = s;
      scur[e] = s;
      s += scnt[e];
    }
  }
  __syncthreads();
  for (int t = tid; t < 4096; t += 256) {
#pragma unroll
    for (int j = 0; j < 2; ++j) {
      const int e = tok_e[2 * t + j];
      const int slot = atomicAdd(&scur[e], 1);
      pair_token[slot] = t;
      tok_slot[2 * t + j] = slot;
    }
  }
}

// -------- merged weight transpose: W1 -> W1t and W2 -> W2t (bf16) -----------
__global__ __launch_bounds__(256) void transW_kernel(
    const float* __restrict__ W1, const float* __restrict__ W2,
    unsigned short* __restrict__ W1t, unsigned short* __restrict__ W2t, int FC,
    int f0, int nW1) {
  __shared__ __align__(16) unsigned short T[64][520];
  const int tid = threadIdx.x;
  const int qi = (tid & 15) * 4;  // inner (contiguous-dim) quad
  const int qo = (tid >> 4) * 4;  // outer quad

  const float* src;
  size_t srcStride;
  unsigned short* dstBase;
  size_t dstStride;

  const int bid = blockIdx.x;
  if (bid < nW1) {
    const int nf = FC / 64;
    const int e = bid / (2 * nf);
    const int rem = bid % (2 * nf);
    const int fb = (rem % nf) * 64;
    const int kb = (rem / nf) * 512;
    src = W1 + ((size_t)e * 1024 + kb) * 4096 + f0 + fb + qi;
    srcStride = 4096;
    dstBase = W1t + ((size_t)e * FC + fb) * 1024 + kb;
    dstStride = 1024;
  } else {
    const int jd = bid - nW1;
    const int nf = FC / 512;
    const int e = jd / (16 * nf);
    const int rem = jd % (16 * nf);
    const int db = (rem % 16) * 64;
    const int fbl = (rem / 16) * 512;
    src = W2 + ((size_t)e * 4096 + f0 + fbl) * 1024 + db + qi;
    srcStride = 1024;
    dstBase = W2t + ((size_t)e * 1024 + db) * FC + fbl;
    dstStride = FC;
  }

#pragma unroll
  for (int it = 0; it < 8; ++it) {
    const int o0 = it * 64 + qo;
    const float* s = src + (size_t)o0 * srcStride;
    const float4 r0 = *(const float4*)s;
    const float4 r1 = *(const float4*)(s + srcStride);
    const float4 r2 = *(const float4*)(s + 2 * srcStride);
    const float4 r3 = *(const float4*)(s + 3 * srcStride);
    uint2 u;
    u.x = (unsigned)f2bf(r0.x) | ((unsigned)f2bf(r1.x) << 16);
    u.y = (unsigned)f2bf(r2.x) | ((unsigned)f2bf(r3.x) << 16);
    *(uint2*)&T[qi + 0][o0] = u;
    u.x = (unsigned)f2bf(r0.y) | ((unsigned)f2bf(r1.y) << 16);
    u.y = (unsigned)f2bf(r2.y) | ((unsigned)f2bf(r3.y) << 16);
    *(uint2*)&T[qi + 1][o0] = u;
    u.x = (unsigned)f2bf(r0.z) | ((unsigned)f2bf(r1.z) << 16);
    u.y = (unsigned)f2bf(r2.z) | ((unsigned)f2bf(r3.z) << 16);
    *(uint2*)&T[qi + 2][o0] = u;
    u.x = (unsigned)f2bf(r0.w) | ((unsigned)f2bf(r1.w) << 16);
    u.y = (unsigned)f2bf(r2.w) | ((unsigned)f2bf(r3.w) << 16);
    *(uint2*)&T[qi + 3][o0] = u;
  }
  __syncthreads();
  const int rr = tid >> 2;
  const int sg = tid & 3;
  unsigned short* dst = dstBase + (size_t)rr * dstStride;
#pragma unroll
  for (int j = 0; j < 16; ++j) {
    const int c = sg + j * 4;
    *(uint4*)(dst + c * 8) = *(const uint4*)&T[rr][c * 8];
  }
}

// BK=64 compute: 16 ds_read up-front, lgkmcnt(8) gates half 0, lgkmcnt(0)
// gates half 1; 32 MFMA total (DS completes in order).
#define COMPUTE64(ALDS, BLDS)                                             \
  {                                                                       \
    bf16x8 a0[4], b0[4], a1[4], b1[4];                                    \
    a0[0] = ldsr128(&ALDS[rdA[0][0]]);                                    \
    a0[1] = ldsr128(&ALDS[rdA[0][1]]);                                    \
    a0[2] = ldsr128(&ALDS[rdA[0][2]]);                                    \
    a0[3] = ldsr128(&ALDS[rdA[0][3]]);                                    \
    b0[0] = ldsr128(&BLDS[rdB[0][0]]);                                    \
    b0[1] = ldsr128(&BLDS[rdB[0][1]]);                                    \
    b0[2] = ldsr128(&BLDS[rdB[0][2]]);                                    \
    b0[3] = ldsr128(&BLDS[rdB[0][3]]);                                    \
    a1[0] = ldsr128(&ALDS[rdA[1][0]]);                                    \
    a1[1] = ldsr128(&ALDS[rdA[1][1]]);                                    \
    a1[2] = ldsr128(&ALDS[rdA[1][2]]);                                    \
    a1[3] = ldsr128(&ALDS[rdA[1][3]]);                                    \
    b1[0] = ldsr128(&BLDS[rdB[1][0]]);                                    \
    b1[1] = ldsr128(&BLDS[rdB[1][1]]);                                    \
    b1[2] = ldsr128(&BLDS[rdB[1][2]]);                                    \
    b1[3] = ldsr128(&BLDS[rdB[1][3]]);                                    \
    asm volatile("s_waitcnt lgkmcnt(8)" ::: "memory");                    \
    __builtin_amdgcn_sched_barrier(0);                                    \
    _Pragma("unroll") for (int mi = 0; mi < 4; ++mi)                      \
        _Pragma("unroll") for (int nj = 0; nj < 4; ++nj)                  \
        acc[mi][nj] = MFMA16(a0[mi], b0[nj], acc[mi][nj]);                \
    __builtin_amdgcn_sched_barrier(0);                                    \
    asm volatile("s_waitcnt lgkmcnt(0)" ::: "memory");                    \
    __builtin_amdgcn_sched_barrier(0);                                    \
    _Pragma("unroll") for (int mi = 0; mi < 4; ++mi)                      \
        _Pragma("unroll") for (int nj = 0; nj < 4; ++nj)                  \
        acc[mi][nj] = MFMA16(a1[mi], b1[nj], acc[mi][nj]);                \
    __builtin_amdgcn_sched_barrier(0);                                    \
  }

// ---------------- GEMM1: H[slot][n] = relu(xb[tok] @ W1t[e] + b1) -----------
// 128x128 tile, BK=64, 4 waves 2x2, gload_lds + 3-bit XOR chunk swizzle,
// 2-buf counted (vmcnt(8)), n-fastest tile order.
__global__ __launch_bounds__(256) void gemm1_kernel(
    const unsigned short* __restrict__ xb,
    const unsigned short* __restrict__ W1t, const float* __restrict__ b1,
    const int* __restrict__ counts, const int* __restrict__ offsets,
    const int* __restrict__ pair_token, unsigned short* __restrict__ H, int FC,
    int f0, int NT) {
  const int bid = blockIdx.x;
  const int e = bid & 7;  // XCD pinning
  const int lid = bid >> 3;
  const int n0 = (lid % NT) * 128;
  const int m0 = (lid / NT) * 128;
  const int count = counts[e];
  if (m0 >= count) return;
  const int offset = offsets[e];

  __shared__ __align__(16) unsigned short Alds[2][128 * 64];
  __shared__ __align__(16) unsigned short Blds[2][128 * 64];
  __shared__ int toklds[128];

  const int tid = threadIdx.x;
  if (tid < 128) {
    int r = m0 + tid;
    if (r >= count) r = count - 1;
    toklds[tid] = pair_token[offset + r];
  }
  __syncthreads();

  const int lane = tid & 63;
  const int wave = tid >> 6;

  // staging: chunk g = tid + 256*j (j=0..3); row = g>>3, phys chunk c = g&7;
  // source chunk = c ^ (row&7); LDS dest linear (wave-uniform base).
  const unsigned short* agp[4];
  const unsigned short* bgp[4];
  int ldso[4];
#pragma unroll
  for (int j = 0; j < 4; ++j) {
    const int g = tid + 256 * j;
    const int row = g >> 3;
    const int c = g & 7;
    const int sc = c ^ (row & 7);
    agp[j] = xb + (size_t)toklds[row] * 1024 + sc * 8;
    bgp[j] = W1t + ((size_t)e * FC + n0 + row) * 1024 + sc * 8;
    ldso[j] = (wave * 64 + 256 * j) * 8;  // shorts; lane adds 16B each
  }

  const int wm = (wave >> 1) * 64;
  const int wn = (wave & 1) * 64;
  const int l16 = lane & 15;
  const int lk = lane >> 4;
  int rdA[2][4], rdB[2][4];
#pragma unroll
  for (int h = 0; h < 2; ++h) {
#pragma unroll
    for (int mi = 0; mi < 4; ++mi) {
      const int row = wm + mi * 16 + l16;
      rdA[h][mi] = row * 64 + (((h * 4 + lk) ^ (row & 7)) << 3);
    }
#pragma unroll
    for (int nj = 0; nj < 4; ++nj) {
      const int row = wn + nj * 16 + l16;
      rdB[h][nj] = row * 64 + (((h * 4 + lk) ^ (row & 7)) << 3);
    }
  }

  f32x4 acc[4][4] = {};

  auto STAGE = [&](int kt, int buf) {  // kt in units of 64-k tiles
#pragma unroll
    for (int j = 0; j < 4; ++j) gload_lds16(agp[j] + kt * 64, &Alds[buf][ldso[j]]);
#pragma unroll
    for (int j = 0; j < 4; ++j) gload_lds16(bgp[j] + kt * 64, &Blds[buf][ldso[j]]);
  };

  const int NTk = 16;  // K = 1024 / 64
  STAGE(0, 0);
  for (int t = 0; t < NTk; ++t) {
    __builtin_amdgcn_s_barrier();  // all waves done reading buf[(t+1)&1]
    if (t + 1 < NTk) {
      STAGE(t + 1, (t + 1) & 1);
      asm volatile("s_waitcnt vmcnt(8)" ::: "memory");  // t's loads landed
    } else {
      asm volatile("s_waitcnt vmcnt(0)" ::: "memory");
    }
    __builtin_amdgcn_s_barrier();  // buf[t&1] staged by all waves
    __builtin_amdgcn_sched_barrier(0);
    COMPUTE64(Alds[t & 1], Blds[t & 1]);
  }

#pragma unroll
  for (int mi = 0; mi < 4; ++mi) {
#pragma unroll
    for (int r = 0; r < 4; ++r) {
      const int rl = m0 + wm + mi * 16 + lk * 4 + r;
      if (rl >= count) continue;
      unsigned short* hrow = H + (size_t)(offset + rl) * FC;
#pragma unroll
      for (int nj = 0; nj < 4; ++nj) {
        const int c = n0 + wn + nj * 16 + l16;
        float v = acc[mi][nj][r] + b1[e * 4096 + f0 + c];
        hrow[c] = f2bf(v > 0.f ? v : 0.f);
      }
    }
  }
}

// ------- GEMM2: P[slot][d] (bf16) (+)= H[slot] @ W2t[e] (+ b2) --------------
__global__ __launch_bounds__(256) void gemm2_kernel(
    const unsigned short* __restrict__ H,
    const unsigned short* __restrict__ W2t, const float* __restrict__ b2,
    const int* __restrict__ counts, const int* __restrict__ offsets,
    unsigned short* __restrict__ P, int FC, int firstChunk) {
  const int bid = blockIdx.x;
  const int e = bid & 7;  // XCD pinning
  const int r2 = bid >> 3;
  const int n0 = (r2 & 7) * 128;   // 8 n-tiles (N=1024), fastest
  const int m0 = (r2 >> 3) * 128;  // 32 m-tiles
  const int count = counts[e];
  if (m0 >= count) return;
  const int offset = offsets[e];

  __shared__ __align__(16) unsigned short Alds[2][128 * 64];
  __shared__ __align__(16) unsigned short Blds[2][128 * 64];

  const int tid = threadIdx.x;
  const int lane = tid & 63;
  const int wave = tid >> 6;

  const unsigned short* agp[4];
  const unsigned short* bgp[4];
  int ldso[4];
#pragma unroll
  for (int j = 0; j < 4; ++j) {
    const int g = tid + 256 * j;
    const int row = g >> 3;
    const int c = g & 7;
    const int sc = c ^ (row & 7);
    int ar = m0 + row;
    if (ar >= count) ar = count - 1;
    agp[j] = H + (size_t)(offset + ar) * FC + sc * 8;
    bgp[j] = W2t + ((size_t)e * 1024 + n0 + row) * FC + sc * 8;
    ldso[j] = (wave * 64 + 256 * j) * 8;
  }

  const int wm = (wave >> 1) * 64;
  const int wn = (wave & 1) * 64;
  const int l16 = lane & 15;
  const int lk = lane >> 4;
  int rdA[2][4], rdB[2][4];
#pragma unroll
  for (int h = 0; h < 2; ++h) {
#pragma unroll
    for (int mi = 0; mi < 4; ++mi) {
      const int row = wm + mi * 16 + l16;
      rdA[h][mi] = row * 64 + (((h * 4 + lk) ^ (row & 7)) << 3);
    }
#pragma unroll
    for (int nj = 0; nj < 4; ++nj) {
      const int row = wn + nj * 16 + l16;
      rdB[h][nj] = row * 64 + (((h * 4 + lk) ^ (row & 7)) << 3);
    }
  }

  f32x4 acc[4][4] = {};

  auto STAGE = [&](int kt, int buf) {
#pragma unroll
    for (int j = 0; j < 4; ++j) gload_lds16(agp[j] + kt * 64, &Alds[buf][ldso[j]]);
#pragma unroll
    for (int j = 0; j < 4; ++j) gload_lds16(bgp[j] + kt * 64, &Blds[buf][ldso[j]]);
  };

  const int NTk = FC / 64;
  STAGE(0, 0);
  for (int t = 0; t < NTk; ++t) {
    __builtin_amdgcn_s_barrier();
    if (t + 1 < NTk) {
      STAGE(t + 1, (t + 1) & 1);
      asm volatile("s_waitcnt vmcnt(8)" ::: "memory");
    } else {
      asm volatile("s_waitcnt vmcnt(0)" ::: "memory");
    }
    __builtin_amdgcn_s_barrier();
    __builtin_amdgcn_sched_barrier(0);
    COMPUTE64(Alds[t & 1], Blds[t & 1]);
  }

#pragma unroll
  for (int mi = 0; mi < 4; ++mi) {
#pragma unroll
    for (int r = 0; r < 4; ++r) {
      const int rl = m0 + wm + mi * 16 + lk * 4 + r;
      if (rl >= count) continue;
      unsigned short* prow = P + (size_t)(offset + rl) * 1024;
#pragma unroll
      for (int nj = 0; nj < 4; ++nj) {
        const int c = n0 + wn + nj * 16 + l16;
        float v = acc[mi][nj][r];
        if (firstChunk) {
          prow[c] = f2bf(v + b2[e * 1024 + c]);
        } else {
          prow[c] = f2bf(bf2f(prow[c]) + v);
        }
      }
    }
  }
}

// ---------------- combine: out[t] = w0*P[s0] + w1*P[s1] (bf16 P) ------------
__global__ __launch_bounds__(256) void combine_kernel(
    const unsigned short* __restrict__ P, const int* __restrict__ tok_slot,
    const float* __restrict__ tok_w, float* __restrict__ out) {
  const int t = blockIdx.x;
  const int d = threadIdx.x * 4;
  const int s0 = tok_slot[2 * t];
  const int s1 = tok_slot[2 * t + 1];
  const float w0 = tok_w[2 * t];
  const float w1 = tok_w[2 * t + 1];
  const ushort4 a = *(const ushort4*)&P[(size_t)s0 * 1024 + d];
  const ushort4 b = *(const ushort4*)&P[(size_t)s1 * 1024 + d];
  float4 r;
  r.x = w0 * bf2f(a.x) + w1 * bf2f(b.x);
  r.y = w0 * bf2f(a.y) + w1 * bf2f(b.y);
  r.z = w0 * bf2f(a.z) + w1 * bf2f(b.z);
  r.w = w0 * bf2f(a.w) + w1 * bf2f(b.w);
  *(float4*)&out[(size_t)t * 1024 + d] = r;
}

extern "C" void kernel_launch(void* const* d_in, const int* in_sizes, int n_in,
                              void* d_out, int out_size, void* d_ws,
                              size_t ws_size, hipStream_t stream) {
  const float* x = (const float*)d_in[0];
  const float* Wg = (const float*)d_in[1];
  const float* bg = (const float*)d_in[2];
  const float* W1 = (const float*)d_in[3];
  const float* b1 = (const float*)d_in[4];
  const float* W2 = (const float*)d_in[5];
  const float* b2 = (const float*)d_in[6];
  float* out = (float*)d_out;

  char* w = (char*)d_ws;
  int* counts = (int*)w;
  int* offsets = counts + 16;
  int* tok_e = (int*)(w + 1024);
  float* tok_w = (float*)(w + 1024 + 32768);
  int* pair_token = (int*)(w + 1024 + 65536);
  int* tok_slot = (int*)(w + 1024 + 98304);
  unsigned short* xb = (unsigned short*)(w + 256 * 1024);  // 8MB
  unsigned short* P =
      (unsigned short*)(w + 256 * 1024 + 8 * 1024 * 1024);  // 16MB bf16
  char* big = w + 256 * 1024 + 8 * 1024 * 1024 + 16 * 1024 * 1024;
  const size_t avail =
      ws_size - (256 * 1024 + 8 * 1024 * 1024 + 16 * 1024 * 1024);

  // per-chunk: W1t 16384*FC + W2t 16384*FC + H 16384*FC bytes
  int FC = 4096;
  while (FC > 512 && (size_t)FC * 49152 > avail) FC >>= 1;

  unsigned short* W1t = (unsigned short*)big;
  unsigned short* W2t = W1t + (size_t)8 * FC * 1024;
  unsigned short* Hc = W2t + (size_t)8 * 1024 * FC;

  gate_kernel<<<1024, 256, 0, stream>>>(x, Wg, bg, tok_e, tok_w, xb);
  scan_scatter_kernel<<<1, 256, 0, stream>>>(tok_e, counts, offsets,
                                             pair_token, tok_slot);

  const int NT = FC / 128;
  const int nW1 = (FC / 64) * 2 * 8;    // W1 transpose blocks
  const int nW2 = 16 * (FC / 512) * 8;  // W2 transpose blocks
  for (int f0 = 0; f0 < 4096; f0 += FC) {
    transW_kernel<<<nW1 + nW2, 256, 0, stream>>>(W1, W2, W1t, W2t, FC, f0,
                                                 nW1);
    gemm1_kernel<<<8 * 32 * NT, 256, 0, stream>>>(
        xb, W1t, b1, counts, offsets, pair_token, Hc, FC, f0, NT);
    gemm2_kernel<<<8 * 8 * 32, 256, 0, stream>>>(
        Hc, W2t, b2, counts, offsets, P, FC, f0 == 0 ? 1 : 0);
  }
  combine_kernel<<<4096, 256, 0, stream>>>(P, tok_slot, tok_w, out);
}

// Round 17
// 333.298 us; speedup vs baseline: 1.2677x; 1.0001x over previous
//
#include <hip/hip_runtime.h>
#include <hip/hip_bf16.h>

// SimpleMoE: B=2,S=2048 -> 4096 tokens, DIM=1024, FF=4096, E=8, top-2 routing.
// Round 17: 256x128 GEMM tiles, wave tile 128x64 (acc 8x4): LDS reads per
// MFMA 0.5 -> 0.375, staging bytes/output -25%. BK=32, 2-barrier counted
// vmcnt(6) pipeline, r13 XOR chunk swizzle. gemm2 split-K=2 (bf16 P x2)
// restores 2 blocks/CU. Rest identical to r15/r16.

typedef __attribute__((ext_vector_type(8))) short bf16x8;
typedef __attribute__((ext_vector_type(4))) float f32x4;

#define MFMA16(a, b, c) __builtin_amdgcn_mfma_f32_16x16x32_bf16((a), (b), (c), 0, 0, 0)

__device__ __forceinline__ unsigned short f2bf(float f) {
  unsigned u = __builtin_bit_cast(unsigned, f);
  u += 0x7FFFu + ((u >> 16) & 1u);
  return (unsigned short)(u >> 16);
}

__device__ __forceinline__ float bf2f(unsigned short s) {
  return __builtin_bit_cast(float, (unsigned)s << 16);
}

__device__ __forceinline__ void gload_lds16(const void* g, void* l) {
  __builtin_amdgcn_global_load_lds(
      (const __attribute__((address_space(1))) unsigned int*)g,
      (__attribute__((address_space(3))) unsigned int*)l, 16, 0, 0);
}

// inline-asm LDS read: keeps the compiler from serializing ds_read behind
// in-flight global_load_lds (false alias) with a vmcnt(0).
__device__ __forceinline__ bf16x8 ldsr128(const void* p) {
  bf16x8 r;
  unsigned a = (unsigned)(unsigned long long)p;
  asm volatile("ds_read_b128 %0, %1" : "=v"(r) : "v"(a));
  return r;
}

// ---------------- gate: logits (fp64), softmax, top-2; also x->bf16 ---------
__global__ __launch_bounds__(256) void gate_kernel(
    const float* __restrict__ x, const float* __restrict__ Wg,
    const float* __restrict__ bg, int* __restrict__ tok_e,
    float* __restrict__ tok_w, unsigned short* __restrict__ xb) {
  const int wave = threadIdx.x >> 6;
  const int lane = threadIdx.x & 63;
  const int t = blockIdx.x * 4 + wave;
  const float* xr = x + (size_t)t * 1024;
  unsigned short* xrow = xb + (size_t)t * 1024;
  double acc[8] = {0, 0, 0, 0, 0, 0, 0, 0};
  for (int i = 0; i < 16; ++i) {
    const int d = i * 64 + lane;
    const float vx = xr[d];
    xrow[d] = f2bf(vx);
    const double xv = (double)vx;
    const float* wr = Wg + d * 8;
#pragma unroll
    for (int e = 0; e < 8; ++e) acc[e] += xv * (double)wr[e];
  }
#pragma unroll
  for (int e = 0; e < 8; ++e) {
    double v = acc[e];
#pragma unroll
    for (int off = 32; off > 0; off >>= 1) v += __shfl_xor(v, off, 64);
    acc[e] = v + (double)bg[e];
  }
  if (lane == 0) {
    int e0 = 0;
#pragma unroll
    for (int e = 1; e < 8; ++e)
      if (acc[e] > acc[e0]) e0 = e;
    int e1 = (e0 == 0) ? 1 : 0;
#pragma unroll
    for (int e = 0; e < 8; ++e) {
      if (e != e0 && acc[e] > acc[e1]) e1 = e;
    }
    const double m = acc[e0];
    double s = 0.0;
#pragma unroll
    for (int e = 0; e < 8; ++e) s += exp(acc[e] - m);
    const double p0 = exp(acc[e0] - m) / s;
    const double p1 = exp(acc[e1] - m) / s;
    const double den = p0 + p1 + 1e-9;
    tok_e[2 * t] = e0;
    tok_e[2 * t + 1] = e1;
    tok_w[2 * t] = (float)(p0 / den);
    tok_w[2 * t + 1] = (float)(p1 / den);
  }
}

// ------- scan + scatter (single block); computes counts internally ----------
__global__ __launch_bounds__(256) void scan_scatter_kernel(
    const int* __restrict__ tok_e, int* __restrict__ counts,
    int* __restrict__ offsets, int* __restrict__ pair_token,
    int* __restrict__ tok_slot) {
  __shared__ int scnt[8];
  __shared__ int scur[8];
  const int tid = threadIdx.x;
  if (tid < 8) scnt[tid] = 0;
  __syncthreads();
  for (int i = tid; i < 8192; i += 256) atomicAdd(&scnt[tok_e[i]], 1);
  __syncthreads();
  if (tid == 0) {
    int s = 0;
    for (int e = 0; e < 8; ++e) {
      counts[e] = scnt[e];
      offsets[e] = s;
      scur[e] = s;
      s += scnt[e];
    }
  }
  __syncthreads();
  for (int t = tid; t < 4096; t += 256) {
#pragma unroll
    for (int j = 0; j < 2; ++j) {
      const int e = tok_e[2 * t + j];
      const int slot = atomicAdd(&scur[e], 1);
      pair_token[slot] = t;
      tok_slot[2 * t + j] = slot;
    }
  }
}

// -------- merged weight transpose: W1 -> W1t and W2 -> W2t (bf16) -----------
__global__ __launch_bounds__(256) void transW_kernel(
    const float* __restrict__ W1, const float* __restrict__ W2,
    unsigned short* __restrict__ W1t, unsigned short* __restrict__ W2t, int FC,
    int f0, int nW1) {
  __shared__ __align__(16) unsigned short T[64][520];
  const int tid = threadIdx.x;
  const int qi = (tid & 15) * 4;  // inner (contiguous-dim) quad
  const int qo = (tid >> 4) * 4;  // outer quad

  const float* src;
  size_t srcStride;
  unsigned short* dstBase;
  size_t dstStride;

  const int bid = blockIdx.x;
  if (bid < nW1) {
    const int nf = FC / 64;
    const int e = bid / (2 * nf);
    const int rem = bid % (2 * nf);
    const int fb = (rem % nf) * 64;
    const int kb = (rem / nf) * 512;
    src = W1 + ((size_t)e * 1024 + kb) * 4096 + f0 + fb + qi;
    srcStride = 4096;
    dstBase = W1t + ((size_t)e * FC + fb) * 1024 + kb;
    dstStride = 1024;
  } else {
    const int jd = bid - nW1;
    const int nf = FC / 512;
    const int e = jd / (16 * nf);
    const int rem = jd % (16 * nf);
    const int db = (rem % 16) * 64;
    const int fbl = (rem / 16) * 512;
    src = W2 + ((size_t)e * 4096 + f0 + fbl) * 1024 + db + qi;
    srcStride = 1024;
    dstBase = W2t + ((size_t)e * 1024 + db) * FC + fbl;
    dstStride = FC;
  }

#pragma unroll
  for (int it = 0; it < 8; ++it) {
    const int o0 = it * 64 + qo;
    const float* s = src + (size_t)o0 * srcStride;
    const float4 r0 = *(const float4*)s;
    const float4 r1 = *(const float4*)(s + srcStride);
    const float4 r2 = *(const float4*)(s + 2 * srcStride);
    const float4 r3 = *(const float4*)(s + 3 * srcStride);
    uint2 u;
    u.x = (unsigned)f2bf(r0.x) | ((unsigned)f2bf(r1.x) << 16);
    u.y = (unsigned)f2bf(r2.x) | ((unsigned)f2bf(r3.x) << 16);
    *(uint2*)&T[qi + 0][o0] = u;
    u.x = (unsigned)f2bf(r0.y) | ((unsigned)f2bf(r1.y) << 16);
    u.y = (unsigned)f2bf(r2.y) | ((unsigned)f2bf(r3.y) << 16);
    *(uint2*)&T[qi + 1][o0] = u;
    u.x = (unsigned)f2bf(r0.z) | ((unsigned)f2bf(r1.z) << 16);
    u.y = (unsigned)f2bf(r2.z) | ((unsigned)f2bf(r3.z) << 16);
    *(uint2*)&T[qi + 2][o0] = u;
    u.x = (unsigned)f2bf(r0.w) | ((unsigned)f2bf(r1.w) << 16);
    u.y = (unsigned)f2bf(r2.w) | ((unsigned)f2bf(r3.w) << 16);
    *(uint2*)&T[qi + 3][o0] = u;
  }
  __syncthreads();
  const int rr = tid >> 2;
  const int sg = tid & 3;
  unsigned short* dst = dstBase + (size_t)rr * dstStride;
#pragma unroll
  for (int j = 0; j < 16; ++j) {
    const int c = sg + j * 4;
    *(uint4*)(dst + c * 8) = *(const uint4*)&T[rr][c * 8];
  }
}

// COMPUTE for 128x64 wave tile: 12 ds_read -> 32 MFMA.
#define COMPUTE32(ALDS, BLDS)                                             \
  {                                                                       \
    bf16x8 a[8], b[4];                                                    \
    _Pragma("unroll") for (int mi = 0; mi < 8; ++mi)                      \
        a[mi] = ldsr128(&ALDS[rdA[mi]]);                                  \
    _Pragma("unroll") for (int nj = 0; nj < 4; ++nj)                      \
        b[nj] = ldsr128(&BLDS[rdB[nj]]);                                  \
    asm volatile("s_waitcnt lgkmcnt(0)" ::: "memory");                    \
    __builtin_amdgcn_sched_barrier(0);                                    \
    _Pragma("unroll") for (int mi = 0; mi < 8; ++mi)                      \
        _Pragma("unroll") for (int nj = 0; nj < 4; ++nj)                  \
        acc[mi][nj] = MFMA16(a[mi], b[nj], acc[mi][nj]);                  \
    __builtin_amdgcn_sched_barrier(0);                                    \
  }

// ---------------- GEMM1: H[slot][n] = relu(xb[tok] @ W1t[e] + b1) -----------
// 256x128 tile, BK=32, 4 waves 2Mx2N (wave tile 128x64), gload_lds + XOR
// swizzle, 2-buf counted vmcnt(6), n-fastest tile order.
__global__ __launch_bounds__(256, 2) void gemm1_kernel(
    const unsigned short* __restrict__ xb,
    const unsigned short* __restrict__ W1t, const float* __restrict__ b1,
    const int* __restrict__ counts, const int* __restrict__ offsets,
    const int* __restrict__ pair_token, unsigned short* __restrict__ H, int FC,
    int f0, int NT) {
  const int bid = blockIdx.x;
  const int e = bid & 7;  // XCD pinning
  const int lid = bid >> 3;
  const int n0 = (lid % NT) * 128;
  const int m0 = (lid / NT) * 256;
  const int count = counts[e];
  if (m0 >= count) return;
  const int offset = offsets[e];

  __shared__ __align__(16) unsigned short Alds[2][256 * 32];
  __shared__ __align__(16) unsigned short Blds[2][128 * 32];
  __shared__ int toklds[256];

  const int tid = threadIdx.x;
  {
    int r = m0 + tid;
    if (r >= count) r = count - 1;
    toklds[tid] = pair_token[offset + r];
  }
  __syncthreads();

  const int lane = tid & 63;
  const int wave = tid >> 6;

  // staging: A 1024 chunks (4/thread), B 512 chunks (2/thread)
  const unsigned short* agp[4];
  const unsigned short* bgp[2];
  int ldsoA[4], ldsoB[2];
#pragma unroll
  for (int j = 0; j < 4; ++j) {
    const int g = tid + 256 * j;
    const int row = g >> 2;
    const int sc = (g & 3) ^ ((row >> 1) & 3);
    agp[j] = xb + (size_t)toklds[row] * 1024 + sc * 8;
    ldsoA[j] = (wave * 64 + 256 * j) * 8;
  }
#pragma unroll
  for (int j = 0; j < 2; ++j) {
    const int g = tid + 256 * j;
    const int row = g >> 2;
    const int sc = (g & 3) ^ ((row >> 1) & 3);
    bgp[j] = W1t + ((size_t)e * FC + n0 + row) * 1024 + sc * 8;
    ldsoB[j] = (wave * 64 + 256 * j) * 8;
  }

  const int wm = (wave >> 1) * 128;
  const int wn = (wave & 1) * 64;
  const int l16 = lane & 15;
  const int lk = lane >> 4;
  int rdA[8], rdB[4];
#pragma unroll
  for (int mi = 0; mi < 8; ++mi) {
    const int row = wm + mi * 16 + l16;
    rdA[mi] = row * 32 + ((lk ^ ((row >> 1) & 3)) << 3);
  }
#pragma unroll
  for (int nj = 0; nj < 4; ++nj) {
    const int row = wn + nj * 16 + l16;
    rdB[nj] = row * 32 + ((lk ^ ((row >> 1) & 3)) << 3);
  }

  f32x4 acc[8][4] = {};

  auto STAGE = [&](int kt, int buf) {  // kt in shorts (k index)
#pragma unroll
    for (int j = 0; j < 4; ++j) gload_lds16(agp[j] + kt, &Alds[buf][ldsoA[j]]);
#pragma unroll
    for (int j = 0; j < 2; ++j) gload_lds16(bgp[j] + kt, &Blds[buf][ldsoB[j]]);
  };

  const int NTk = 32;  // K = 1024 / 32
  STAGE(0, 0);
  for (int t = 0; t < NTk; ++t) {
    __builtin_amdgcn_s_barrier();  // all waves done reading buf[(t+1)&1]
    if (t + 1 < NTk) {
      STAGE((t + 1) * 32, (t + 1) & 1);
      asm volatile("s_waitcnt vmcnt(6)" ::: "memory");  // t's loads landed
    } else {
      asm volatile("s_waitcnt vmcnt(0)" ::: "memory");
    }
    __builtin_amdgcn_s_barrier();  // buf[t&1] staged by all waves
    __builtin_amdgcn_sched_barrier(0);
    COMPUTE32(Alds[t & 1], Blds[t & 1]);
  }

#pragma unroll
  for (int mi = 0; mi < 8; ++mi) {
#pragma unroll
    for (int r = 0; r < 4; ++r) {
      const int rl = m0 + wm + mi * 16 + lk * 4 + r;
      if (rl >= count) continue;
      unsigned short* hrow = H + (size_t)(offset + rl) * FC;
#pragma unroll
      for (int nj = 0; nj < 4; ++nj) {
        const int c = n0 + wn + nj * 16 + l16;
        float v = acc[mi][nj][r] + b1[e * 4096 + f0 + c];
        hrow[c] = f2bf(v > 0.f ? v : 0.f);
      }
    }
  }
}

// ------- GEMM2: P[ks][slot][d] (bf16) = slice_ks(H[slot] @ W2t[e]) (+ b2) ---
// 256x128 tile, split-K=2, private bf16 partial buffers.
__global__ __launch_bounds__(256, 2) void gemm2_kernel(
    const unsigned short* __restrict__ H,
    const unsigned short* __restrict__ W2t, const float* __restrict__ b2,
    const int* __restrict__ counts, const int* __restrict__ offsets,
    unsigned short* __restrict__ P, int FC, int firstChunk) {
  const int bid = blockIdx.x;
  const int e = bid & 7;  // XCD pinning
  const int r2 = bid >> 3;
  const int n0 = (r2 & 7) * 128;          // 8 n-tiles (N=1024), fastest
  const int m0 = ((r2 >> 3) & 15) * 256;  // 16 m-tiles of 256
  const int ks = r2 >> 7;                 // K split 0/1
  const int count = counts[e];
  if (m0 >= count) return;
  const int offset = offsets[e];
  const int KS = FC / 2;
  const int kb = ks * KS;
  unsigned short* Pb = P + (size_t)ks * 8192 * 1024;

  __shared__ __align__(16) unsigned short Alds[2][256 * 32];
  __shared__ __align__(16) unsigned short Blds[2][128 * 32];

  const int tid = threadIdx.x;
  const int lane = tid & 63;
  const int wave = tid >> 6;

  const unsigned short* agp[4];
  const unsigned short* bgp[2];
  int ldsoA[4], ldsoB[2];
#pragma unroll
  for (int j = 0; j < 4; ++j) {
    const int g = tid + 256 * j;
    const int row = g >> 2;
    const int sc = (g & 3) ^ ((row >> 1) & 3);
    int ar = m0 + row;
    if (ar >= count) ar = count - 1;
    agp[j] = H + (size_t)(offset + ar) * FC + kb + sc * 8;
    ldsoA[j] = (wave * 64 + 256 * j) * 8;
  }
#pragma unroll
  for (int j = 0; j < 2; ++j) {
    const int g = tid + 256 * j;
    const int row = g >> 2;
    const int sc = (g & 3) ^ ((row >> 1) & 3);
    bgp[j] = W2t + ((size_t)e * 1024 + n0 + row) * FC + kb + sc * 8;
    ldsoB[j] = (wave * 64 + 256 * j) * 8;
  }

  const int wm = (wave >> 1) * 128;
  const int wn = (wave & 1) * 64;
  const int l16 = lane & 15;
  const int lk = lane >> 4;
  int rdA[8], rdB[4];
#pragma unroll
  for (int mi = 0; mi < 8; ++mi) {
    const int row = wm + mi * 16 + l16;
    rdA[mi] = row * 32 + ((lk ^ ((row >> 1) & 3)) << 3);
  }
#pragma unroll
  for (int nj = 0; nj < 4; ++nj) {
    const int row = wn + nj * 16 + l16;
    rdB[nj] = row * 32 + ((lk ^ ((row >> 1) & 3)) << 3);
  }

  f32x4 acc[8][4] = {};

  auto STAGE = [&](int kt, int buf) {
#pragma unroll
    for (int j = 0; j < 4; ++j) gload_lds16(agp[j] + kt, &Alds[buf][ldsoA[j]]);
#pragma unroll
    for (int j = 0; j < 2; ++j) gload_lds16(bgp[j] + kt, &Blds[buf][ldsoB[j]]);
  };

  const int NTk = KS / 32;
  STAGE(0, 0);
  for (int t = 0; t < NTk; ++t) {
    __builtin_amdgcn_s_barrier();
    if (t + 1 < NTk) {
      STAGE((t + 1) * 32, (t + 1) & 1);
      asm volatile("s_waitcnt vmcnt(6)" ::: "memory");
    } else {
      asm volatile("s_waitcnt vmcnt(0)" ::: "memory");
    }
    __builtin_amdgcn_s_barrier();
    __builtin_amdgcn_sched_barrier(0);
    COMPUTE32(Alds[t & 1], Blds[t & 1]);
  }

#pragma unroll
  for (int mi = 0; mi < 8; ++mi) {
#pragma unroll
    for (int r = 0; r < 4; ++r) {
      const int rl = m0 + wm + mi * 16 + lk * 4 + r;
      if (rl >= count) continue;
      unsigned short* prow = Pb + (size_t)(offset + rl) * 1024;
#pragma unroll
      for (int nj = 0; nj < 4; ++nj) {
        const int c = n0 + wn + nj * 16 + l16;
        float v = acc[mi][nj][r];
        if (ks == 0 && firstChunk) v += b2[e * 1024 + c];
        if (firstChunk) {
          prow[c] = f2bf(v);
        } else {
          prow[c] = f2bf(bf2f(prow[c]) + v);
        }
      }
    }
  }
}

// ---- combine: out[t] = w0*(P0[s0]+P1[s0]) + w1*(P0[s1]+P1[s1]) (bf16 P) ----
__global__ __launch_bounds__(256) void combine_kernel(
    const unsigned short* __restrict__ P, const int* __restrict__ tok_slot,
    const float* __restrict__ tok_w, float* __restrict__ out) {
  const int t = blockIdx.x;
  const int d = threadIdx.x * 4;
  const int s0 = tok_slot[2 * t];
  const int s1 = tok_slot[2 * t + 1];
  const float w0 = tok_w[2 * t];
  const float w1 = tok_w[2 * t + 1];
  const ushort4 a0 = *(const ushort4*)&P[(size_t)s0 * 1024 + d];
  const ushort4 a1 = *(const ushort4*)&P[(size_t)(8192 + s0) * 1024 + d];
  const ushort4 c0 = *(const ushort4*)&P[(size_t)s1 * 1024 + d];
  const ushort4 c1 = *(const ushort4*)&P[(size_t)(8192 + s1) * 1024 + d];
  float4 r;
  r.x = w0 * (bf2f(a0.x) + bf2f(a1.x)) + w1 * (bf2f(c0.x) + bf2f(c1.x));
  r.y = w0 * (bf2f(a0.y) + bf2f(a1.y)) + w1 * (bf2f(c0.y) + bf2f(c1.y));
  r.z = w0 * (bf2f(a0.z) + bf2f(a1.z)) + w1 * (bf2f(c0.z) + bf2f(c1.z));
  r.w = w0 * (bf2f(a0.w) + bf2f(a1.w)) + w1 * (bf2f(c0.w) + bf2f(c1.w));
  *(float4*)&out[(size_t)t * 1024 + d] = r;
}

extern "C" void kernel_launch(void* const* d_in, const int* in_sizes, int n_in,
                              void* d_out, int out_size, void* d_ws,
                              size_t ws_size, hipStream_t stream) {
  const float* x = (const float*)d_in[0];
  const float* Wg = (const float*)d_in[1];
  const float* bg = (const float*)d_in[2];
  const float* W1 = (const float*)d_in[3];
  const float* b1 = (const float*)d_in[4];
  const float* W2 = (const float*)d_in[5];
  const float* b2 = (const float*)d_in[6];
  float* out = (float*)d_out;

  char* w = (char*)d_ws;
  int* counts = (int*)w;
  int* offsets = counts + 16;
  int* tok_e = (int*)(w + 1024);
  float* tok_w = (float*)(w + 1024 + 32768);
  int* pair_token = (int*)(w + 1024 + 65536);
  int* tok_slot = (int*)(w + 1024 + 98304);
  unsigned short* xb = (unsigned short*)(w + 256 * 1024);  // 8MB
  unsigned short* P =
      (unsigned short*)(w + 256 * 1024 + 8 * 1024 * 1024);  // 32MB bf16 x2
  char* big = w + 256 * 1024 + 8 * 1024 * 1024 + 32 * 1024 * 1024;
  const size_t avail =
      ws_size - (256 * 1024 + 8 * 1024 * 1024 + 32 * 1024 * 1024);

  // per-chunk: W1t 16384*FC + W2t 16384*FC + H 16384*FC bytes
  int FC = 4096;
  while (FC > 512 && (size_t)FC * 49152 > avail) FC >>= 1;

  unsigned short* W1t = (unsigned short*)big;
  unsigned short* W2t = W1t + (size_t)8 * FC * 1024;
  unsigned short* Hc = W2t + (size_t)8 * 1024 * FC;

  gate_kernel<<<1024, 256, 0, stream>>>(x, Wg, bg, tok_e, tok_w, xb);
  scan_scatter_kernel<<<1, 256, 0, stream>>>(tok_e, counts, offsets,
                                             pair_token, tok_slot);

  const int NT = FC / 128;
  const int nW1 = (FC / 64) * 2 * 8;    // W1 transpose blocks
  const int nW2 = 16 * (FC / 512) * 8;  // W2 transpose blocks
  for (int f0 = 0; f0 < 4096; f0 += FC) {
    transW_kernel<<<nW1 + nW2, 256, 0, stream>>>(W1, W2, W1t, W2t, FC, f0,
                                                 nW1);
    gemm1_kernel<<<8 * 16 * NT, 256, 0, stream>>>(
        xb, W1t, b1, counts, offsets, pair_token, Hc, FC, f0, NT);
    gemm2_kernel<<<8 * 8 * 16 * 2, 256, 0, stream>>>(
        Hc, W2t, b2, counts, offsets, P, FC, f0 == 0 ? 1 : 0);
  }
  combine_kernel<<<4096, 256, 0, stream>>>(P, tok_slot, tok_w, out);
}

// Round 18
// 330.293 us; speedup vs baseline: 1.2793x; 1.0091x over previous
//
#include <hip/hip_runtime.h>
#include <hip/hip_bf16.h>

// SimpleMoE: B=2,S=2048 -> 4096 tokens, DIM=1024, FF=4096, E=8, top-2 routing.
// Round 18: r17 GEMM cores frozen. gate + weight-transpose merged into ONE
// prep kernel (block-decode; gate blocks co-schedule with BW-bound transpose
// blocks). 5 launches total when FC=4096. Everything else identical to r17.

typedef __attribute__((ext_vector_type(8))) short bf16x8;
typedef __attribute__((ext_vector_type(4))) float f32x4;

#define MFMA16(a, b, c) __builtin_amdgcn_mfma_f32_16x16x32_bf16((a), (b), (c), 0, 0, 0)

__device__ __forceinline__ unsigned short f2bf(float f) {
  unsigned u = __builtin_bit_cast(unsigned, f);
  u += 0x7FFFu + ((u >> 16) & 1u);
  return (unsigned short)(u >> 16);
}

__device__ __forceinline__ float bf2f(unsigned short s) {
  return __builtin_bit_cast(float, (unsigned)s << 16);
}

__device__ __forceinline__ void gload_lds16(const void* g, void* l) {
  __builtin_amdgcn_global_load_lds(
      (const __attribute__((address_space(1))) unsigned int*)g,
      (__attribute__((address_space(3))) unsigned int*)l, 16, 0, 0);
}

// inline-asm LDS read: keeps the compiler from serializing ds_read behind
// in-flight global_load_lds (false alias) with a vmcnt(0).
__device__ __forceinline__ bf16x8 ldsr128(const void* p) {
  bf16x8 r;
  unsigned a = (unsigned)(unsigned long long)p;
  asm volatile("ds_read_b128 %0, %1" : "=v"(r) : "v"(a));
  return r;
}

// ---------------- gate device body (one 256-thr block handles 4 tokens) -----
__device__ __forceinline__ void gate_body(
    int blk, const float* __restrict__ x, const float* __restrict__ Wg,
    const float* __restrict__ bg, int* __restrict__ tok_e,
    float* __restrict__ tok_w, unsigned short* __restrict__ xb) {
  const int wave = threadIdx.x >> 6;
  const int lane = threadIdx.x & 63;
  const int t = blk * 4 + wave;
  const float* xr = x + (size_t)t * 1024;
  unsigned short* xrow = xb + (size_t)t * 1024;
  double acc[8] = {0, 0, 0, 0, 0, 0, 0, 0};
  for (int i = 0; i < 16; ++i) {
    const int d = i * 64 + lane;
    const float vx = xr[d];
    xrow[d] = f2bf(vx);
    const double xv = (double)vx;
    const float* wr = Wg + d * 8;
#pragma unroll
    for (int e = 0; e < 8; ++e) acc[e] += xv * (double)wr[e];
  }
#pragma unroll
  for (int e = 0; e < 8; ++e) {
    double v = acc[e];
#pragma unroll
    for (int off = 32; off > 0; off >>= 1) v += __shfl_xor(v, off, 64);
    acc[e] = v + (double)bg[e];
  }
  if (lane == 0) {
    int e0 = 0;
#pragma unroll
    for (int e = 1; e < 8; ++e)
      if (acc[e] > acc[e0]) e0 = e;
    int e1 = (e0 == 0) ? 1 : 0;
#pragma unroll
    for (int e = 0; e < 8; ++e) {
      if (e != e0 && acc[e] > acc[e1]) e1 = e;
    }
    const double m = acc[e0];
    double s = 0.0;
#pragma unroll
    for (int e = 0; e < 8; ++e) s += exp(acc[e] - m);
    const double p0 = exp(acc[e0] - m) / s;
    const double p1 = exp(acc[e1] - m) / s;
    const double den = p0 + p1 + 1e-9;
    tok_e[2 * t] = e0;
    tok_e[2 * t + 1] = e1;
    tok_w[2 * t] = (float)(p0 / den);
    tok_w[2 * t + 1] = (float)(p1 / den);
  }
}

// ---------------- transW device body (64x512 register-transpose tile) -------
__device__ __forceinline__ void transW_body(
    int bid, const float* __restrict__ W1, const float* __restrict__ W2,
    unsigned short* __restrict__ W1t, unsigned short* __restrict__ W2t, int FC,
    int f0, int nW1, unsigned short (*T)[520]) {
  const int tid = threadIdx.x;
  const int qi = (tid & 15) * 4;  // inner (contiguous-dim) quad
  const int qo = (tid >> 4) * 4;  // outer quad

  const float* src;
  size_t srcStride;
  unsigned short* dstBase;
  size_t dstStride;

  if (bid < nW1) {
    const int nf = FC / 64;
    const int e = bid / (2 * nf);
    const int rem = bid % (2 * nf);
    const int fb = (rem % nf) * 64;
    const int kb = (rem / nf) * 512;
    src = W1 + ((size_t)e * 1024 + kb) * 4096 + f0 + fb + qi;
    srcStride = 4096;
    dstBase = W1t + ((size_t)e * FC + fb) * 1024 + kb;
    dstStride = 1024;
  } else {
    const int jd = bid - nW1;
    const int nf = FC / 512;
    const int e = jd / (16 * nf);
    const int rem = jd % (16 * nf);
    const int db = (rem % 16) * 64;
    const int fbl = (rem / 16) * 512;
    src = W2 + ((size_t)e * 4096 + f0 + fbl) * 1024 + db + qi;
    srcStride = 1024;
    dstBase = W2t + ((size_t)e * 1024 + db) * FC + fbl;
    dstStride = FC;
  }

#pragma unroll
  for (int it = 0; it < 8; ++it) {
    const int o0 = it * 64 + qo;
    const float* s = src + (size_t)o0 * srcStride;
    const float4 r0 = *(const float4*)s;
    const float4 r1 = *(const float4*)(s + srcStride);
    const float4 r2 = *(const float4*)(s + 2 * srcStride);
    const float4 r3 = *(const float4*)(s + 3 * srcStride);
    uint2 u;
    u.x = (unsigned)f2bf(r0.x) | ((unsigned)f2bf(r1.x) << 16);
    u.y = (unsigned)f2bf(r2.x) | ((unsigned)f2bf(r3.x) << 16);
    *(uint2*)&T[qi + 0][o0] = u;
    u.x = (unsigned)f2bf(r0.y) | ((unsigned)f2bf(r1.y) << 16);
    u.y = (unsigned)f2bf(r2.y) | ((unsigned)f2bf(r3.y) << 16);
    *(uint2*)&T[qi + 1][o0] = u;
    u.x = (unsigned)f2bf(r0.z) | ((unsigned)f2bf(r1.z) << 16);
    u.y = (unsigned)f2bf(r2.z) | ((unsigned)f2bf(r3.z) << 16);
    *(uint2*)&T[qi + 2][o0] = u;
    u.x = (unsigned)f2bf(r0.w) | ((unsigned)f2bf(r1.w) << 16);
    u.y = (unsigned)f2bf(r2.w) | ((unsigned)f2bf(r3.w) << 16);
    *(uint2*)&T[qi + 3][o0] = u;
  }
  __syncthreads();
  const int rr = tid >> 2;
  const int sg = tid & 3;
  unsigned short* dst = dstBase + (size_t)rr * dstStride;
#pragma unroll
  for (int j = 0; j < 16; ++j) {
    const int c = sg + j * 4;
    *(uint4*)(dst + c * 8) = *(const uint4*)&T[rr][c * 8];
  }
}

// -------- merged prep: blocks [0,1024) gate, [1024, 1024+nW1+nW2) transW ----
__global__ __launch_bounds__(256) void prep_kernel(
    const float* __restrict__ x, const float* __restrict__ Wg,
    const float* __restrict__ bg, int* __restrict__ tok_e,
    float* __restrict__ tok_w, unsigned short* __restrict__ xb,
    const float* __restrict__ W1, const float* __restrict__ W2,
    unsigned short* __restrict__ W1t, unsigned short* __restrict__ W2t, int FC,
    int f0, int nW1) {
  __shared__ __align__(16) unsigned short T[64][520];
  const int bid = blockIdx.x;
  if (bid < 1024) {
    gate_body(bid, x, Wg, bg, tok_e, tok_w, xb);
  } else {
    transW_body(bid - 1024, W1, W2, W1t, W2t, FC, f0, nW1, T);
  }
}

// -------- standalone versions (fallback when FC < 4096, chunked) ------------
__global__ __launch_bounds__(256) void gate_kernel(
    const float* __restrict__ x, const float* __restrict__ Wg,
    const float* __restrict__ bg, int* __restrict__ tok_e,
    float* __restrict__ tok_w, unsigned short* __restrict__ xb) {
  gate_body(blockIdx.x, x, Wg, bg, tok_e, tok_w, xb);
}

__global__ __launch_bounds__(256) void transW_kernel(
    const float* __restrict__ W1, const float* __restrict__ W2,
    unsigned short* __restrict__ W1t, unsigned short* __restrict__ W2t, int FC,
    int f0, int nW1) {
  __shared__ __align__(16) unsigned short T[64][520];
  transW_body(blockIdx.x, W1, W2, W1t, W2t, FC, f0, nW1, T);
}

// ------- scan + scatter (single block); computes counts internally ----------
__global__ __launch_bounds__(256) void scan_scatter_kernel(
    const int* __restrict__ tok_e, int* __restrict__ counts,
    int* __restrict__ offsets, int* __restrict__ pair_token,
    int* __restrict__ tok_slot) {
  __shared__ int scnt[8];
  __shared__ int scur[8];
  const int tid = threadIdx.x;
  if (tid < 8) scnt[tid] = 0;
  __syncthreads();
  for (int i = tid; i < 8192; i += 256) atomicAdd(&scnt[tok_e[i]], 1);
  __syncthreads();
  if (tid == 0) {
    int s = 0;
    for (int e = 0; e < 8; ++e) {
      counts[e] = scnt[e];
      offsets[e] = s;
      scur[e] = s;
      s += scnt[e];
    }
  }
  __syncthreads();
  for (int t = tid; t < 4096; t += 256) {
#pragma unroll
    for (int j = 0; j < 2; ++j) {
      const int e = tok_e[2 * t + j];
      const int slot = atomicAdd(&scur[e], 1);
      pair_token[slot] = t;
      tok_slot[2 * t + j] = slot;
    }
  }
}

// COMPUTE for 128x64 wave tile: 12 ds_read -> 32 MFMA.
#define COMPUTE32(ALDS, BLDS)                                             \
  {                                                                       \
    bf16x8 a[8], b[4];                                                    \
    _Pragma("unroll") for (int mi = 0; mi < 8; ++mi)                      \
        a[mi] = ldsr128(&ALDS[rdA[mi]]);                                  \
    _Pragma("unroll") for (int nj = 0; nj < 4; ++nj)                      \
        b[nj] = ldsr128(&BLDS[rdB[nj]]);                                  \
    asm volatile("s_waitcnt lgkmcnt(0)" ::: "memory");                    \
    __builtin_amdgcn_sched_barrier(0);                                    \
    _Pragma("unroll") for (int mi = 0; mi < 8; ++mi)                      \
        _Pragma("unroll") for (int nj = 0; nj < 4; ++nj)                  \
        acc[mi][nj] = MFMA16(a[mi], b[nj], acc[mi][nj]);                  \
    __builtin_amdgcn_sched_barrier(0);                                    \
  }

// ---------------- GEMM1: H[slot][n] = relu(xb[tok] @ W1t[e] + b1) -----------
// 256x128 tile, BK=32, 4 waves 2Mx2N (wave tile 128x64), gload_lds + XOR
// swizzle, 2-buf counted vmcnt(6), n-fastest tile order.
__global__ __launch_bounds__(256, 2) void gemm1_kernel(
    const unsigned short* __restrict__ xb,
    const unsigned short* __restrict__ W1t, const float* __restrict__ b1,
    const int* __restrict__ counts, const int* __restrict__ offsets,
    const int* __restrict__ pair_token, unsigned short* __restrict__ H, int FC,
    int f0, int NT) {
  const int bid = blockIdx.x;
  const int e = bid & 7;  // XCD pinning
  const int lid = bid >> 3;
  const int n0 = (lid % NT) * 128;
  const int m0 = (lid / NT) * 256;
  const int count = counts[e];
  if (m0 >= count) return;
  const int offset = offsets[e];

  __shared__ __align__(16) unsigned short Alds[2][256 * 32];
  __shared__ __align__(16) unsigned short Blds[2][128 * 32];
  __shared__ int toklds[256];

  const int tid = threadIdx.x;
  {
    int r = m0 + tid;
    if (r >= count) r = count - 1;
    toklds[tid] = pair_token[offset + r];
  }
  __syncthreads();

  const int lane = tid & 63;
  const int wave = tid >> 6;

  // staging: A 1024 chunks (4/thread), B 512 chunks (2/thread)
  const unsigned short* agp[4];
  const unsigned short* bgp[2];
  int ldsoA[4], ldsoB[2];
#pragma unroll
  for (int j = 0; j < 4; ++j) {
    const int g = tid + 256 * j;
    const int row = g >> 2;
    const int sc = (g & 3) ^ ((row >> 1) & 3);
    agp[j] = xb + (size_t)toklds[row] * 1024 + sc * 8;
    ldsoA[j] = (wave * 64 + 256 * j) * 8;
  }
#pragma unroll
  for (int j = 0; j < 2; ++j) {
    const int g = tid + 256 * j;
    const int row = g >> 2;
    const int sc = (g & 3) ^ ((row >> 1) & 3);
    bgp[j] = W1t + ((size_t)e * FC + n0 + row) * 1024 + sc * 8;
    ldsoB[j] = (wave * 64 + 256 * j) * 8;
  }

  const int wm = (wave >> 1) * 128;
  const int wn = (wave & 1) * 64;
  const int l16 = lane & 15;
  const int lk = lane >> 4;
  int rdA[8], rdB[4];
#pragma unroll
  for (int mi = 0; mi < 8; ++mi) {
    const int row = wm + mi * 16 + l16;
    rdA[mi] = row * 32 + ((lk ^ ((row >> 1) & 3)) << 3);
  }
#pragma unroll
  for (int nj = 0; nj < 4; ++nj) {
    const int row = wn + nj * 16 + l16;
    rdB[nj] = row * 32 + ((lk ^ ((row >> 1) & 3)) << 3);
  }

  f32x4 acc[8][4] = {};

  auto STAGE = [&](int kt, int buf) {  // kt in shorts (k index)
#pragma unroll
    for (int j = 0; j < 4; ++j) gload_lds16(agp[j] + kt, &Alds[buf][ldsoA[j]]);
#pragma unroll
    for (int j = 0; j < 2; ++j) gload_lds16(bgp[j] + kt, &Blds[buf][ldsoB[j]]);
  };

  const int NTk = 32;  // K = 1024 / 32
  STAGE(0, 0);
  for (int t = 0; t < NTk; ++t) {
    __builtin_amdgcn_s_barrier();  // all waves done reading buf[(t+1)&1]
    if (t + 1 < NTk) {
      STAGE((t + 1) * 32, (t + 1) & 1);
      asm volatile("s_waitcnt vmcnt(6)" ::: "memory");  // t's loads landed
    } else {
      asm volatile("s_waitcnt vmcnt(0)" ::: "memory");
    }
    __builtin_amdgcn_s_barrier();  // buf[t&1] staged by all waves
    __builtin_amdgcn_sched_barrier(0);
    COMPUTE32(Alds[t & 1], Blds[t & 1]);
  }

#pragma unroll
  for (int mi = 0; mi < 8; ++mi) {
#pragma unroll
    for (int r = 0; r < 4; ++r) {
      const int rl = m0 + wm + mi * 16 + lk * 4 + r;
      if (rl >= count) continue;
      unsigned short* hrow = H + (size_t)(offset + rl) * FC;
#pragma unroll
      for (int nj = 0; nj < 4; ++nj) {
        const int c = n0 + wn + nj * 16 + l16;
        float v = acc[mi][nj][r] + b1[e * 4096 + f0 + c];
        hrow[c] = f2bf(v > 0.f ? v : 0.f);
      }
    }
  }
}

// ------- GEMM2: P[ks][slot][d] (bf16) = slice_ks(H[slot] @ W2t[e]) (+ b2) ---
// 256x128 tile, split-K=2, private bf16 partial buffers.
__global__ __launch_bounds__(256, 2) void gemm2_kernel(
    const unsigned short* __restrict__ H,
    const unsigned short* __restrict__ W2t, const float* __restrict__ b2,
    const int* __restrict__ counts, const int* __restrict__ offsets,
    unsigned short* __restrict__ P, int FC, int firstChunk) {
  const int bid = blockIdx.x;
  const int e = bid & 7;  // XCD pinning
  const int r2 = bid >> 3;
  const int n0 = (r2 & 7) * 128;          // 8 n-tiles (N=1024), fastest
  const int m0 = ((r2 >> 3) & 15) * 256;  // 16 m-tiles of 256
  const int ks = r2 >> 7;                 // K split 0/1
  const int count = counts[e];
  if (m0 >= count) return;
  const int offset = offsets[e];
  const int KS = FC / 2;
  const int kb = ks * KS;
  unsigned short* Pb = P + (size_t)ks * 8192 * 1024;

  __shared__ __align__(16) unsigned short Alds[2][256 * 32];
  __shared__ __align__(16) unsigned short Blds[2][128 * 32];

  const int tid = threadIdx.x;
  const int lane = tid & 63;
  const int wave = tid >> 6;

  const unsigned short* agp[4];
  const unsigned short* bgp[2];
  int ldsoA[4], ldsoB[2];
#pragma unroll
  for (int j = 0; j < 4; ++j) {
    const int g = tid + 256 * j;
    const int row = g >> 2;
    const int sc = (g & 3) ^ ((row >> 1) & 3);
    int ar = m0 + row;
    if (ar >= count) ar = count - 1;
    agp[j] = H + (size_t)(offset + ar) * FC + kb + sc * 8;
    ldsoA[j] = (wave * 64 + 256 * j) * 8;
  }
#pragma unroll
  for (int j = 0; j < 2; ++j) {
    const int g = tid + 256 * j;
    const int row = g >> 2;
    const int sc = (g & 3) ^ ((row >> 1) & 3);
    bgp[j] = W2t + ((size_t)e * 1024 + n0 + row) * FC + kb + sc * 8;
    ldsoB[j] = (wave * 64 + 256 * j) * 8;
  }

  const int wm = (wave >> 1) * 128;
  const int wn = (wave & 1) * 64;
  const int l16 = lane & 15;
  const int lk = lane >> 4;
  int rdA[8], rdB[4];
#pragma unroll
  for (int mi = 0; mi < 8; ++mi) {
    const int row = wm + mi * 16 + l16;
    rdA[mi] = row * 32 + ((lk ^ ((row >> 1) & 3)) << 3);
  }
#pragma unroll
  for (int nj = 0; nj < 4; ++nj) {
    const int row = wn + nj * 16 + l16;
    rdB[nj] = row * 32 + ((lk ^ ((row >> 1) & 3)) << 3);
  }

  f32x4 acc[8][4] = {};

  auto STAGE = [&](int kt, int buf) {
#pragma unroll
    for (int j = 0; j < 4; ++j) gload_lds16(agp[j] + kt, &Alds[buf][ldsoA[j]]);
#pragma unroll
    for (int j = 0; j < 2; ++j) gload_lds16(bgp[j] + kt, &Blds[buf][ldsoB[j]]);
  };

  const int NTk = KS / 32;
  STAGE(0, 0);
  for (int t = 0; t < NTk; ++t) {
    __builtin_amdgcn_s_barrier();
    if (t + 1 < NTk) {
      STAGE((t + 1) * 32, (t + 1) & 1);
      asm volatile("s_waitcnt vmcnt(6)" ::: "memory");
    } else {
      asm volatile("s_waitcnt vmcnt(0)" ::: "memory");
    }
    __builtin_amdgcn_s_barrier();
    __builtin_amdgcn_sched_barrier(0);
    COMPUTE32(Alds[t & 1], Blds[t & 1]);
  }

#pragma unroll
  for (int mi = 0; mi < 8; ++mi) {
#pragma unroll
    for (int r = 0; r < 4; ++r) {
      const int rl = m0 + wm + mi * 16 + lk * 4 + r;
      if (rl >= count) continue;
      unsigned short* prow = Pb + (size_t)(offset + rl) * 1024;
#pragma unroll
      for (int nj = 0; nj < 4; ++nj) {
        const int c = n0 + wn + nj * 16 + l16;
        float v = acc[mi][nj][r];
        if (ks == 0 && firstChunk) v += b2[e * 1024 + c];
        if (firstChunk) {
          prow[c] = f2bf(v);
        } else {
          prow[c] = f2bf(bf2f(prow[c]) + v);
        }
      }
    }
  }
}

// ---- combine: out[t] = w0*(P0[s0]+P1[s0]) + w1*(P0[s1]+P1[s1]) (bf16 P) ----
__global__ __launch_bounds__(256) void combine_kernel(
    const unsigned short* __restrict__ P, const int* __restrict__ tok_slot,
    const float* __restrict__ tok_w, float* __restrict__ out) {
  const int t = blockIdx.x;
  const int d = threadIdx.x * 4;
  const int s0 = tok_slot[2 * t];
  const int s1 = tok_slot[2 * t + 1];
  const float w0 = tok_w[2 * t];
  const float w1 = tok_w[2 * t + 1];
  const ushort4 a0 = *(const ushort4*)&P[(size_t)s0 * 1024 + d];
  const ushort4 a1 = *(const ushort4*)&P[(size_t)(8192 + s0) * 1024 + d];
  const ushort4 c0 = *(const ushort4*)&P[(size_t)s1 * 1024 + d];
  const ushort4 c1 = *(const ushort4*)&P[(size_t)(8192 + s1) * 1024 + d];
  float4 r;
  r.x = w0 * (bf2f(a0.x) + bf2f(a1.x)) + w1 * (bf2f(c0.x) + bf2f(c1.x));
  r.y = w0 * (bf2f(a0.y) + bf2f(a1.y)) + w1 * (bf2f(c0.y) + bf2f(c1.y));
  r.z = w0 * (bf2f(a0.z) + bf2f(a1.z)) + w1 * (bf2f(c0.z) + bf2f(c1.z));
  r.w = w0 * (bf2f(a0.w) + bf2f(a1.w)) + w1 * (bf2f(c0.w) + bf2f(c1.w));
  *(float4*)&out[(size_t)t * 1024 + d] = r;
}

extern "C" void kernel_launch(void* const* d_in, const int* in_sizes, int n_in,
                              void* d_out, int out_size, void* d_ws,
                              size_t ws_size, hipStream_t stream) {
  const float* x = (const float*)d_in[0];
  const float* Wg = (const float*)d_in[1];
  const float* bg = (const float*)d_in[2];
  const float* W1 = (const float*)d_in[3];
  const float* b1 = (const float*)d_in[4];
  const float* W2 = (const float*)d_in[5];
  const float* b2 = (const float*)d_in[6];
  float* out = (float*)d_out;

  char* w = (char*)d_ws;
  int* counts = (int*)w;
  int* offsets = counts + 16;
  int* tok_e = (int*)(w + 1024);
  float* tok_w = (float*)(w + 1024 + 32768);
  int* pair_token = (int*)(w + 1024 + 65536);
  int* tok_slot = (int*)(w + 1024 + 98304);
  unsigned short* xb = (unsigned short*)(w + 256 * 1024);  // 8MB
  unsigned short* P =
      (unsigned short*)(w + 256 * 1024 + 8 * 1024 * 1024);  // 32MB bf16 x2
  char* big = w + 256 * 1024 + 8 * 1024 * 1024 + 32 * 1024 * 1024;
  const size_t avail =
      ws_size - (256 * 1024 + 8 * 1024 * 1024 + 32 * 1024 * 1024);

  // per-chunk: W1t 16384*FC + W2t 16384*FC + H 16384*FC bytes
  int FC = 4096;
  while (FC > 512 && (size_t)FC * 49152 > avail) FC >>= 1;

  unsigned short* W1t = (unsigned short*)big;
  unsigned short* W2t = W1t + (size_t)8 * FC * 1024;
  unsigned short* Hc = W2t + (size_t)8 * 1024 * FC;

  const int NT = FC / 128;
  const int nW1 = (FC / 64) * 2 * 8;    // W1 transpose blocks
  const int nW2 = 16 * (FC / 512) * 8;  // W2 transpose blocks

  if (FC == 4096) {
    // single chunk: fuse gate + both weight transposes into one launch
    prep_kernel<<<1024 + nW1 + nW2, 256, 0, stream>>>(
        x, Wg, bg, tok_e, tok_w, xb, W1, W2, W1t, W2t, FC, 0, nW1);
    scan_scatter_kernel<<<1, 256, 0, stream>>>(tok_e, counts, offsets,
                                               pair_token, tok_slot);
    gemm1_kernel<<<8 * 16 * NT, 256, 0, stream>>>(
        xb, W1t, b1, counts, offsets, pair_token, Hc, FC, 0, NT);
    gemm2_kernel<<<8 * 8 * 16 * 2, 256, 0, stream>>>(
        Hc, W2t, b2, counts, offsets, P, FC, 1);
  } else {
    gate_kernel<<<1024, 256, 0, stream>>>(x, Wg, bg, tok_e, tok_w, xb);
    scan_scatter_kernel<<<1, 256, 0, stream>>>(tok_e, counts, offsets,
                                               pair_token, tok_slot);
    for (int f0 = 0; f0 < 4096; f0 += FC) {
      transW_kernel<<<nW1 + nW2, 256, 0, stream>>>(W1, W2, W1t, W2t, FC, f0,
                                                   nW1);
      gemm1_kernel<<<8 * 16 * NT, 256, 0, stream>>>(
          xb, W1t, b1, counts, offsets, pair_token, Hc, FC, f0, NT);
      gemm2_kernel<<<8 * 8 * 16 * 2, 256, 0, stream>>>(
          Hc, W2t, b2, counts, offsets, P, FC, f0 == 0 ? 1 : 0);
    }
  }
  combine_kernel<<<4096, 256, 0, stream>>>(P, tok_slot, tok_w, out);
}

// Round 19
// 323.311 us; speedup vs baseline: 1.3069x; 1.0216x over previous
//
#include <hip/hip_runtime.h>
#include <hip/hip_bf16.h>

// SimpleMoE: B=2,S=2048 -> 4096 tokens, DIM=1024, FF=4096, E=8, top-2 routing.
// Round 19: GEMM cores frozen (r17). prep kernel reworked for occupancy:
// transpose tile 64x256 (LDS 33.8KB -> 4 blocks/CU, 2x TLP) + XOR chunk
// swizzle on LDS writes/reads (8-way -> 4-way write conflict).

typedef __attribute__((ext_vector_type(8))) short bf16x8;
typedef __attribute__((ext_vector_type(4))) float f32x4;

#define MFMA16(a, b, c) __builtin_amdgcn_mfma_f32_16x16x32_bf16((a), (b), (c), 0, 0, 0)

__device__ __forceinline__ unsigned short f2bf(float f) {
  unsigned u = __builtin_bit_cast(unsigned, f);
  u += 0x7FFFu + ((u >> 16) & 1u);
  return (unsigned short)(u >> 16);
}

__device__ __forceinline__ float bf2f(unsigned short s) {
  return __builtin_bit_cast(float, (unsigned)s << 16);
}

__device__ __forceinline__ void gload_lds16(const void* g, void* l) {
  __builtin_amdgcn_global_load_lds(
      (const __attribute__((address_space(1))) unsigned int*)g,
      (__attribute__((address_space(3))) unsigned int*)l, 16, 0, 0);
}

// inline-asm LDS read: keeps the compiler from serializing ds_read behind
// in-flight global_load_lds (false alias) with a vmcnt(0).
__device__ __forceinline__ bf16x8 ldsr128(const void* p) {
  bf16x8 r;
  unsigned a = (unsigned)(unsigned long long)p;
  asm volatile("ds_read_b128 %0, %1" : "=v"(r) : "v"(a));
  return r;
}

// ---------------- gate device body (one 256-thr block handles 4 tokens) -----
__device__ __forceinline__ void gate_body(
    int blk, const float* __restrict__ x, const float* __restrict__ Wg,
    const float* __restrict__ bg, int* __restrict__ tok_e,
    float* __restrict__ tok_w, unsigned short* __restrict__ xb) {
  const int wave = threadIdx.x >> 6;
  const int lane = threadIdx.x & 63;
  const int t = blk * 4 + wave;
  const float* xr = x + (size_t)t * 1024;
  unsigned short* xrow = xb + (size_t)t * 1024;
  double acc[8] = {0, 0, 0, 0, 0, 0, 0, 0};
  for (int i = 0; i < 16; ++i) {
    const int d = i * 64 + lane;
    const float vx = xr[d];
    xrow[d] = f2bf(vx);
    const double xv = (double)vx;
    const float* wr = Wg + d * 8;
#pragma unroll
    for (int e = 0; e < 8; ++e) acc[e] += xv * (double)wr[e];
  }
#pragma unroll
  for (int e = 0; e < 8; ++e) {
    double v = acc[e];
#pragma unroll
    for (int off = 32; off > 0; off >>= 1) v += __shfl_xor(v, off, 64);
    acc[e] = v + (double)bg[e];
  }
  if (lane == 0) {
    int e0 = 0;
#pragma unroll
    for (int e = 1; e < 8; ++e)
      if (acc[e] > acc[e0]) e0 = e;
    int e1 = (e0 == 0) ? 1 : 0;
#pragma unroll
    for (int e = 0; e < 8; ++e) {
      if (e != e0 && acc[e] > acc[e1]) e1 = e;
    }
    const double m = acc[e0];
    double s = 0.0;
#pragma unroll
    for (int e = 0; e < 8; ++e) s += exp(acc[e] - m);
    const double p0 = exp(acc[e0] - m) / s;
    const double p1 = exp(acc[e1] - m) / s;
    const double den = p0 + p1 + 1e-9;
    tok_e[2 * t] = e0;
    tok_e[2 * t + 1] = e1;
    tok_w[2 * t] = (float)(p0 / den);
    tok_w[2 * t + 1] = (float)(p1 / den);
  }
}

// ------- transW device body: 64(inner) x 256(outer) register-transpose ------
// LDS swizzle: element (row, o) stored at chunk (o>>3) ^ ((row>>1)&7),
// offset o&7. Writes 8B (one half-chunk), reads 16B (one chunk) -> both legal.
__device__ __forceinline__ void transW_body(
    int bid, const float* __restrict__ W1, const float* __restrict__ W2,
    unsigned short* __restrict__ W1t, unsigned short* __restrict__ W2t, int FC,
    int f0, int nW1, unsigned short (*T)[264]) {
  const int tid = threadIdx.x;
  const int qi = (tid & 15) * 4;  // inner quad (contiguous source dim)
  const int ko = (tid >> 4) * 4;  // outer quad base

  const float* src;
  size_t srcStride;
  unsigned short* dstBase;
  size_t dstStride;

  if (bid < nW1) {
    // W1[e][k][f] -> W1t[e][f-f0][k]; inner=f (64), outer=k (256)
    const int nf = FC / 64;
    const int e = bid / (4 * nf);
    const int rem = bid % (4 * nf);
    const int fb = (rem % nf) * 64;
    const int kb = (rem / nf) * 256;
    src = W1 + ((size_t)e * 1024 + kb) * 4096 + f0 + fb + qi;
    srcStride = 4096;
    dstBase = W1t + ((size_t)e * FC + fb) * 1024 + kb;
    dstStride = 1024;
  } else {
    // W2[e][f][d] -> W2t[e][d][f-f0]; inner=d (64), outer=f (256)
    const int jd = bid - nW1;
    const int nf = FC / 256;
    const int e = jd / (16 * nf);
    const int rem = jd % (16 * nf);
    const int db = (rem % 16) * 64;
    const int fbl = (rem / 16) * 256;
    src = W2 + ((size_t)e * 4096 + f0 + fbl) * 1024 + db + qi;
    srcStride = 1024;
    dstBase = W2t + ((size_t)e * 1024 + db) * FC + fbl;
    dstStride = FC;
  }

#pragma unroll
  for (int it = 0; it < 4; ++it) {
    const int o0 = it * 64 + ko;
    const float* s = src + (size_t)o0 * srcStride;
    const float4 r0 = *(const float4*)s;
    const float4 r1 = *(const float4*)(s + srcStride);
    const float4 r2 = *(const float4*)(s + 2 * srcStride);
    const float4 r3 = *(const float4*)(s + 3 * srcStride);
    const int c8 = o0 >> 3;
    const int off = o0 & 7;
#pragma unroll
    for (int i = 0; i < 4; ++i) {
      const float vx0 = (i == 0) ? r0.x : (i == 1) ? r0.y : (i == 2) ? r0.z : r0.w;
      const float vx1 = (i == 0) ? r1.x : (i == 1) ? r1.y : (i == 2) ? r1.z : r1.w;
      const float vx2 = (i == 0) ? r2.x : (i == 1) ? r2.y : (i == 2) ? r2.z : r2.w;
      const float vx3 = (i == 0) ? r3.x : (i == 1) ? r3.y : (i == 2) ? r3.z : r3.w;
      const int row = qi + i;
      const int cs = c8 ^ ((row >> 1) & 7);
      uint2 u;
      u.x = (unsigned)f2bf(vx0) | ((unsigned)f2bf(vx1) << 16);
      u.y = (unsigned)f2bf(vx2) | ((unsigned)f2bf(vx3) << 16);
      *(uint2*)&T[row][cs * 8 + off] = u;
    }
  }
  __syncthreads();
  const int rr = tid >> 2;  // 0..63 (inner-dim row)
  const int sg = tid & 3;
  unsigned short* dst = dstBase + (size_t)rr * dstStride;
  const int swz = (rr >> 1) & 7;
#pragma unroll
  for (int j = 0; j < 8; ++j) {
    const int c = sg + j * 4;  // logical 16B chunk; 4 lanes -> 64B contiguous
    *(uint4*)(dst + c * 8) = *(const uint4*)&T[rr][(c ^ swz) * 8];
  }
}

// -------- merged prep: blocks [0,1024) gate, [1024, 1024+nW1+nW2) transW ----
__global__ __launch_bounds__(256) void prep_kernel(
    const float* __restrict__ x, const float* __restrict__ Wg,
    const float* __restrict__ bg, int* __restrict__ tok_e,
    float* __restrict__ tok_w, unsigned short* __restrict__ xb,
    const float* __restrict__ W1, const float* __restrict__ W2,
    unsigned short* __restrict__ W1t, unsigned short* __restrict__ W2t, int FC,
    int f0, int nW1) {
  __shared__ __align__(16) unsigned short T[64][264];
  const int bid = blockIdx.x;
  if (bid < 1024) {
    gate_body(bid, x, Wg, bg, tok_e, tok_w, xb);
  } else {
    transW_body(bid - 1024, W1, W2, W1t, W2t, FC, f0, nW1, T);
  }
}

// -------- standalone versions (fallback when FC < 4096, chunked) ------------
__global__ __launch_bounds__(256) void gate_kernel(
    const float* __restrict__ x, const float* __restrict__ Wg,
    const float* __restrict__ bg, int* __restrict__ tok_e,
    float* __restrict__ tok_w, unsigned short* __restrict__ xb) {
  gate_body(blockIdx.x, x, Wg, bg, tok_e, tok_w, xb);
}

__global__ __launch_bounds__(256) void transW_kernel(
    const float* __restrict__ W1, const float* __restrict__ W2,
    unsigned short* __restrict__ W1t, unsigned short* __restrict__ W2t, int FC,
    int f0, int nW1) {
  __shared__ __align__(16) unsigned short T[64][264];
  transW_body(blockIdx.x, W1, W2, W1t, W2t, FC, f0, nW1, T);
}

// ------- scan + scatter (single block); computes counts internally ----------
__global__ __launch_bounds__(256) void scan_scatter_kernel(
    const int* __restrict__ tok_e, int* __restrict__ counts,
    int* __restrict__ offsets, int* __restrict__ pair_token,
    int* __restrict__ tok_slot) {
  __shared__ int scnt[8];
  __shared__ int scur[8];
  const int tid = threadIdx.x;
  if (tid < 8) scnt[tid] = 0;
  __syncthreads();
  for (int i = tid; i < 8192; i += 256) atomicAdd(&scnt[tok_e[i]], 1);
  __syncthreads();
  if (tid == 0) {
    int s = 0;
    for (int e = 0; e < 8; ++e) {
      counts[e] = scnt[e];
      offsets[e] = s;
      scur[e] = s;
      s += scnt[e];
    }
  }
  __syncthreads();
  for (int t = tid; t < 4096; t += 256) {
#pragma unroll
    for (int j = 0; j < 2; ++j) {
      const int e = tok_e[2 * t + j];
      const int slot = atomicAdd(&scur[e], 1);
      pair_token[slot] = t;
      tok_slot[2 * t + j] = slot;
    }
  }
}

// COMPUTE for 128x64 wave tile: 12 ds_read -> 32 MFMA.
#define COMPUTE32(ALDS, BLDS)                                             \
  {                                                                       \
    bf16x8 a[8], b[4];                                                    \
    _Pragma("unroll") for (int mi = 0; mi < 8; ++mi)                      \
        a[mi] = ldsr128(&ALDS[rdA[mi]]);                                  \
    _Pragma("unroll") for (int nj = 0; nj < 4; ++nj)                      \
        b[nj] = ldsr128(&BLDS[rdB[nj]]);                                  \
    asm volatile("s_waitcnt lgkmcnt(0)" ::: "memory");                    \
    __builtin_amdgcn_sched_barrier(0);                                    \
    _Pragma("unroll") for (int mi = 0; mi < 8; ++mi)                      \
        _Pragma("unroll") for (int nj = 0; nj < 4; ++nj)                  \
        acc[mi][nj] = MFMA16(a[mi], b[nj], acc[mi][nj]);                  \
    __builtin_amdgcn_sched_barrier(0);                                    \
  }

// ---------------- GEMM1: H[slot][n] = relu(xb[tok] @ W1t[e] + b1) -----------
// 256x128 tile, BK=32, 4 waves 2Mx2N (wave tile 128x64), gload_lds + XOR
// swizzle, 2-buf counted vmcnt(6), n-fastest tile order.
__global__ __launch_bounds__(256, 2) void gemm1_kernel(
    const unsigned short* __restrict__ xb,
    const unsigned short* __restrict__ W1t, const float* __restrict__ b1,
    const int* __restrict__ counts, const int* __restrict__ offsets,
    const int* __restrict__ pair_token, unsigned short* __restrict__ H, int FC,
    int f0, int NT) {
  const int bid = blockIdx.x;
  const int e = bid & 7;  // XCD pinning
  const int lid = bid >> 3;
  const int n0 = (lid % NT) * 128;
  const int m0 = (lid / NT) * 256;
  const int count = counts[e];
  if (m0 >= count) return;
  const int offset = offsets[e];

  __shared__ __align__(16) unsigned short Alds[2][256 * 32];
  __shared__ __align__(16) unsigned short Blds[2][128 * 32];
  __shared__ int toklds[256];

  const int tid = threadIdx.x;
  {
    int r = m0 + tid;
    if (r >= count) r = count - 1;
    toklds[tid] = pair_token[offset + r];
  }
  __syncthreads();

  const int lane = tid & 63;
  const int wave = tid >> 6;

  // staging: A 1024 chunks (4/thread), B 512 chunks (2/thread)
  const unsigned short* agp[4];
  const unsigned short* bgp[2];
  int ldsoA[4], ldsoB[2];
#pragma unroll
  for (int j = 0; j < 4; ++j) {
    const int g = tid + 256 * j;
    const int row = g >> 2;
    const int sc = (g & 3) ^ ((row >> 1) & 3);
    agp[j] = xb + (size_t)toklds[row] * 1024 + sc * 8;
    ldsoA[j] = (wave * 64 + 256 * j) * 8;
  }
#pragma unroll
  for (int j = 0; j < 2; ++j) {
    const int g = tid + 256 * j;
    const int row = g >> 2;
    const int sc = (g & 3) ^ ((row >> 1) & 3);
    bgp[j] = W1t + ((size_t)e * FC + n0 + row) * 1024 + sc * 8;
    ldsoB[j] = (wave * 64 + 256 * j) * 8;
  }

  const int wm = (wave >> 1) * 128;
  const int wn = (wave & 1) * 64;
  const int l16 = lane & 15;
  const int lk = lane >> 4;
  int rdA[8], rdB[4];
#pragma unroll
  for (int mi = 0; mi < 8; ++mi) {
    const int row = wm + mi * 16 + l16;
    rdA[mi] = row * 32 + ((lk ^ ((row >> 1) & 3)) << 3);
  }
#pragma unroll
  for (int nj = 0; nj < 4; ++nj) {
    const int row = wn + nj * 16 + l16;
    rdB[nj] = row * 32 + ((lk ^ ((row >> 1) & 3)) << 3);
  }

  f32x4 acc[8][4] = {};

  auto STAGE = [&](int kt, int buf) {  // kt in shorts (k index)
#pragma unroll
    for (int j = 0; j < 4; ++j) gload_lds16(agp[j] + kt, &Alds[buf][ldsoA[j]]);
#pragma unroll
    for (int j = 0; j < 2; ++j) gload_lds16(bgp[j] + kt, &Blds[buf][ldsoB[j]]);
  };

  const int NTk = 32;  // K = 1024 / 32
  STAGE(0, 0);
  for (int t = 0; t < NTk; ++t) {
    __builtin_amdgcn_s_barrier();  // all waves done reading buf[(t+1)&1]
    if (t + 1 < NTk) {
      STAGE((t + 1) * 32, (t + 1) & 1);
      asm volatile("s_waitcnt vmcnt(6)" ::: "memory");  // t's loads landed
    } else {
      asm volatile("s_waitcnt vmcnt(0)" ::: "memory");
    }
    __builtin_amdgcn_s_barrier();  // buf[t&1] staged by all waves
    __builtin_amdgcn_sched_barrier(0);
    COMPUTE32(Alds[t & 1], Blds[t & 1]);
  }

#pragma unroll
  for (int mi = 0; mi < 8; ++mi) {
#pragma unroll
    for (int r = 0; r < 4; ++r) {
      const int rl = m0 + wm + mi * 16 + lk * 4 + r;
      if (rl >= count) continue;
      unsigned short* hrow = H + (size_t)(offset + rl) * FC;
#pragma unroll
      for (int nj = 0; nj < 4; ++nj) {
        const int c = n0 + wn + nj * 16 + l16;
        float v = acc[mi][nj][r] + b1[e * 4096 + f0 + c];
        hrow[c] = f2bf(v > 0.f ? v : 0.f);
      }
    }
  }
}

// ------- GEMM2: P[ks][slot][d] (bf16) = slice_ks(H[slot] @ W2t[e]) (+ b2) ---
// 256x128 tile, split-K=2, private bf16 partial buffers.
__global__ __launch_bounds__(256, 2) void gemm2_kernel(
    const unsigned short* __restrict__ H,
    const unsigned short* __restrict__ W2t, const float* __restrict__ b2,
    const int* __restrict__ counts, const int* __restrict__ offsets,
    unsigned short* __restrict__ P, int FC, int firstChunk) {
  const int bid = blockIdx.x;
  const int e = bid & 7;  // XCD pinning
  const int r2 = bid >> 3;
  const int n0 = (r2 & 7) * 128;          // 8 n-tiles (N=1024), fastest
  const int m0 = ((r2 >> 3) & 15) * 256;  // 16 m-tiles of 256
  const int ks = r2 >> 7;                 // K split 0/1
  const int count = counts[e];
  if (m0 >= count) return;
  const int offset = offsets[e];
  const int KS = FC / 2;
  const int kb = ks * KS;
  unsigned short* Pb = P + (size_t)ks * 8192 * 1024;

  __shared__ __align__(16) unsigned short Alds[2][256 * 32];
  __shared__ __align__(16) unsigned short Blds[2][128 * 32];

  const int tid = threadIdx.x;
  const int lane = tid & 63;
  const int wave = tid >> 6;

  const unsigned short* agp[4];
  const unsigned short* bgp[2];
  int ldsoA[4], ldsoB[2];
#pragma unroll
  for (int j = 0; j < 4; ++j) {
    const int g = tid + 256 * j;
    const int row = g >> 2;
    const int sc = (g & 3) ^ ((row >> 1) & 3);
    int ar = m0 + row;
    if (ar >= count) ar = count - 1;
    agp[j] = H + (size_t)(offset + ar) * FC + kb + sc * 8;
    ldsoA[j] = (wave * 64 + 256 * j) * 8;
  }
#pragma unroll
  for (int j = 0; j < 2; ++j) {
    const int g = tid + 256 * j;
    const int row = g >> 2;
    const int sc = (g & 3) ^ ((row >> 1) & 3);
    bgp[j] = W2t + ((size_t)e * 1024 + n0 + row) * FC + kb + sc * 8;
    ldsoB[j] = (wave * 64 + 256 * j) * 8;
  }

  const int wm = (wave >> 1) * 128;
  const int wn = (wave & 1) * 64;
  const int l16 = lane & 15;
  const int lk = lane >> 4;
  int rdA[8], rdB[4];
#pragma unroll
  for (int mi = 0; mi < 8; ++mi) {
    const int row = wm + mi * 16 + l16;
    rdA[mi] = row * 32 + ((lk ^ ((row >> 1) & 3)) << 3);
  }
#pragma unroll
  for (int nj = 0; nj < 4; ++nj) {
    const int row = wn + nj * 16 + l16;
    rdB[nj] = row * 32 + ((lk ^ ((row >> 1) & 3)) << 3);
  }

  f32x4 acc[8][4] = {};

  auto STAGE = [&](int kt, int buf) {
#pragma unroll
    for (int j = 0; j < 4; ++j) gload_lds16(agp[j] + kt, &Alds[buf][ldsoA[j]]);
#pragma unroll
    for (int j = 0; j < 2; ++j) gload_lds16(bgp[j] + kt, &Blds[buf][ldsoB[j]]);
  };

  const int NTk = KS / 32;
  STAGE(0, 0);
  for (int t = 0; t < NTk; ++t) {
    __builtin_amdgcn_s_barrier();
    if (t + 1 < NTk) {
      STAGE((t + 1) * 32, (t + 1) & 1);
      asm volatile("s_waitcnt vmcnt(6)" ::: "memory");
    } else {
      asm volatile("s_waitcnt vmcnt(0)" ::: "memory");
    }
    __builtin_amdgcn_s_barrier();
    __builtin_amdgcn_sched_barrier(0);
    COMPUTE32(Alds[t & 1], Blds[t & 1]);
  }

#pragma unroll
  for (int mi = 0; mi < 8; ++mi) {
#pragma unroll
    for (int r = 0; r < 4; ++r) {
      const int rl = m0 + wm + mi * 16 + lk * 4 + r;
      if (rl >= count) continue;
      unsigned short* prow = Pb + (size_t)(offset + rl) * 1024;
#pragma unroll
      for (int nj = 0; nj < 4; ++nj) {
        const int c = n0 + wn + nj * 16 + l16;
        float v = acc[mi][nj][r];
        if (ks == 0 && firstChunk) v += b2[e * 1024 + c];
        if (firstChunk) {
          prow[c] = f2bf(v);
        } else {
          prow[c] = f2bf(bf2f(prow[c]) + v);
        }
      }
    }
  }
}

// ---- combine: out[t] = w0*(P0[s0]+P1[s0]) + w1*(P0[s1]+P1[s1]) (bf16 P) ----
__global__ __launch_bounds__(256) void combine_kernel(
    const unsigned short* __restrict__ P, const int* __restrict__ tok_slot,
    const float* __restrict__ tok_w, float* __restrict__ out) {
  const int t = blockIdx.x;
  const int d = threadIdx.x * 4;
  const int s0 = tok_slot[2 * t];
  const int s1 = tok_slot[2 * t + 1];
  const float w0 = tok_w[2 * t];
  const float w1 = tok_w[2 * t + 1];
  const ushort4 a0 = *(const ushort4*)&P[(size_t)s0 * 1024 + d];
  const ushort4 a1 = *(const ushort4*)&P[(size_t)(8192 + s0) * 1024 + d];
  const ushort4 c0 = *(const ushort4*)&P[(size_t)s1 * 1024 + d];
  const ushort4 c1 = *(const ushort4*)&P[(size_t)(8192 + s1) * 1024 + d];
  float4 r;
  r.x = w0 * (bf2f(a0.x) + bf2f(a1.x)) + w1 * (bf2f(c0.x) + bf2f(c1.x));
  r.y = w0 * (bf2f(a0.y) + bf2f(a1.y)) + w1 * (bf2f(c0.y) + bf2f(c1.y));
  r.z = w0 * (bf2f(a0.z) + bf2f(a1.z)) + w1 * (bf2f(c0.z) + bf2f(c1.z));
  r.w = w0 * (bf2f(a0.w) + bf2f(a1.w)) + w1 * (bf2f(c0.w) + bf2f(c1.w));
  *(float4*)&out[(size_t)t * 1024 + d] = r;
}

extern "C" void kernel_launch(void* const* d_in, const int* in_sizes, int n_in,
                              void* d_out, int out_size, void* d_ws,
                              size_t ws_size, hipStream_t stream) {
  const float* x = (const float*)d_in[0];
  const float* Wg = (const float*)d_in[1];
  const float* bg = (const float*)d_in[2];
  const float* W1 = (const float*)d_in[3];
  const float* b1 = (const float*)d_in[4];
  const float* W2 = (const float*)d_in[5];
  const float* b2 = (const float*)d_in[6];
  float* out = (float*)d_out;

  char* w = (char*)d_ws;
  int* counts = (int*)w;
  int* offsets = counts + 16;
  int* tok_e = (int*)(w + 1024);
  float* tok_w = (float*)(w + 1024 + 32768);
  int* pair_token = (int*)(w + 1024 + 65536);
  int* tok_slot = (int*)(w + 1024 + 98304);
  unsigned short* xb = (unsigned short*)(w + 256 * 1024);  // 8MB
  unsigned short* P =
      (unsigned short*)(w + 256 * 1024 + 8 * 1024 * 1024);  // 32MB bf16 x2
  char* big = w + 256 * 1024 + 8 * 1024 * 1024 + 32 * 1024 * 1024;
  const size_t avail =
      ws_size - (256 * 1024 + 8 * 1024 * 1024 + 32 * 1024 * 1024);

  // per-chunk: W1t 16384*FC + W2t 16384*FC + H 16384*FC bytes
  int FC = 4096;
  while (FC > 512 && (size_t)FC * 49152 > avail) FC >>= 1;

  unsigned short* W1t = (unsigned short*)big;
  unsigned short* W2t = W1t + (size_t)8 * FC * 1024;
  unsigned short* Hc = W2t + (size_t)8 * 1024 * FC;

  const int NT = FC / 128;
  const int nW1 = (FC / 64) * 4 * 8;    // 64f x 256k tiles
  const int nW2 = 16 * (FC / 256) * 8;  // 64d x 256f tiles

  if (FC == 4096) {
    prep_kernel<<<1024 + nW1 + nW2, 256, 0, stream>>>(
        x, Wg, bg, tok_e, tok_w, xb, W1, W2, W1t, W2t, FC, 0, nW1);
    scan_scatter_kernel<<<1, 256, 0, stream>>>(tok_e, counts, offsets,
                                               pair_token, tok_slot);
    gemm1_kernel<<<8 * 16 * NT, 256, 0, stream>>>(
        xb, W1t, b1, counts, offsets, pair_token, Hc, FC, 0, NT);
    gemm2_kernel<<<8 * 8 * 16 * 2, 256, 0, stream>>>(
        Hc, W2t, b2, counts, offsets, P, FC, 1);
  } else {
    gate_kernel<<<1024, 256, 0, stream>>>(x, Wg, bg, tok_e, tok_w, xb);
    scan_scatter_kernel<<<1, 256, 0, stream>>>(tok_e, counts, offsets,
                                               pair_token, tok_slot);
    for (int f0 = 0; f0 < 4096; f0 += FC) {
      transW_kernel<<<nW1 + nW2, 256, 0, stream>>>(W1, W2, W1t, W2t, FC, f0,
                                                   nW1);
      gemm1_kernel<<<8 * 16 * NT, 256, 0, stream>>>(
          xb, W1t, b1, counts, offsets, pair_token, Hc, FC, f0, NT);
      gemm2_kernel<<<8 * 8 * 16 * 2, 256, 0, stream>>>(
          Hc, W2t, b2, counts, offsets, P, FC, f0 == 0 ? 1 : 0);
    }
  }
  combine_kernel<<<4096, 256, 0, stream>>>(P, tok_slot, tok_w, out);
}

// Round 20
// 322.275 us; speedup vs baseline: 1.3111x; 1.0032x over previous
//
#include <hip/hip_runtime.h>
#include <hip/hip_bf16.h>

// SimpleMoE: B=2,S=2048 -> 4096 tokens, DIM=1024, FF=4096, E=8, top-2 routing.
// Round 20: GEMM cores frozen (r17). transW phase-1 MLP fix: all 16 float4
// loads issued up-front via inline-asm (VGPR 52 -> ~110, free under the LDS
// occupancy cap), one vmcnt(0), then convert+write. Rest identical to r19.

typedef __attribute__((ext_vector_type(8))) short bf16x8;
typedef __attribute__((ext_vector_type(4))) float f32x4;

#define MFMA16(a, b, c) __builtin_amdgcn_mfma_f32_16x16x32_bf16((a), (b), (c), 0, 0, 0)

__device__ __forceinline__ unsigned short f2bf(float f) {
  unsigned u = __builtin_bit_cast(unsigned, f);
  u += 0x7FFFu + ((u >> 16) & 1u);
  return (unsigned short)(u >> 16);
}

__device__ __forceinline__ float bf2f(unsigned short s) {
  return __builtin_bit_cast(float, (unsigned)s << 16);
}

__device__ __forceinline__ void gload_lds16(const void* g, void* l) {
  __builtin_amdgcn_global_load_lds(
      (const __attribute__((address_space(1))) unsigned int*)g,
      (__attribute__((address_space(3))) unsigned int*)l, 16, 0, 0);
}

// inline-asm LDS read: keeps the compiler from serializing ds_read behind
// in-flight global_load_lds (false alias) with a vmcnt(0).
__device__ __forceinline__ bf16x8 ldsr128(const void* p) {
  bf16x8 r;
  unsigned a = (unsigned)(unsigned long long)p;
  asm volatile("ds_read_b128 %0, %1" : "=v"(r) : "v"(a));
  return r;
}

// inline-asm global fp32x4 load: forces the issue (no compiler serialization
// to save VGPRs); completion gated by a later counted vmcnt.
__device__ __forceinline__ f32x4 gload4(const float* p) {
  f32x4 r;
  asm volatile("global_load_dwordx4 %0, %1, off" : "=v"(r) : "v"(p) : "memory");
  return r;
}

// ---------------- gate device body (one 256-thr block handles 4 tokens) -----
__device__ __forceinline__ void gate_body(
    int blk, const float* __restrict__ x, const float* __restrict__ Wg,
    const float* __restrict__ bg, int* __restrict__ tok_e,
    float* __restrict__ tok_w, unsigned short* __restrict__ xb) {
  const int wave = threadIdx.x >> 6;
  const int lane = threadIdx.x & 63;
  const int t = blk * 4 + wave;
  const float* xr = x + (size_t)t * 1024;
  unsigned short* xrow = xb + (size_t)t * 1024;
  double acc[8] = {0, 0, 0, 0, 0, 0, 0, 0};
  for (int i = 0; i < 16; ++i) {
    const int d = i * 64 + lane;
    const float vx = xr[d];
    xrow[d] = f2bf(vx);
    const double xv = (double)vx;
    const float* wr = Wg + d * 8;
#pragma unroll
    for (int e = 0; e < 8; ++e) acc[e] += xv * (double)wr[e];
  }
#pragma unroll
  for (int e = 0; e < 8; ++e) {
    double v = acc[e];
#pragma unroll
    for (int off = 32; off > 0; off >>= 1) v += __shfl_xor(v, off, 64);
    acc[e] = v + (double)bg[e];
  }
  if (lane == 0) {
    int e0 = 0;
#pragma unroll
    for (int e = 1; e < 8; ++e)
      if (acc[e] > acc[e0]) e0 = e;
    int e1 = (e0 == 0) ? 1 : 0;
#pragma unroll
    for (int e = 0; e < 8; ++e) {
      if (e != e0 && acc[e] > acc[e1]) e1 = e;
    }
    const double m = acc[e0];
    double s = 0.0;
#pragma unroll
    for (int e = 0; e < 8; ++e) s += exp(acc[e] - m);
    const double p0 = exp(acc[e0] - m) / s;
    const double p1 = exp(acc[e1] - m) / s;
    const double den = p0 + p1 + 1e-9;
    tok_e[2 * t] = e0;
    tok_e[2 * t + 1] = e1;
    tok_w[2 * t] = (float)(p0 / den);
    tok_w[2 * t + 1] = (float)(p1 / den);
  }
}

// ------- transW device body: 64(inner) x 256(outer) register-transpose ------
// Phase 1: ALL 16 float4 loads issued up-front (inline asm) -> one vmcnt(0)
// -> convert + swizzled LDS write. Phase 2: 64B-contiguous global writes.
__device__ __forceinline__ void transW_body(
    int bid, const float* __restrict__ W1, const float* __restrict__ W2,
    unsigned short* __restrict__ W1t, unsigned short* __restrict__ W2t, int FC,
    int f0, int nW1, unsigned short (*T)[264]) {
  const int tid = threadIdx.x;
  const int qi = (tid & 15) * 4;  // inner quad (contiguous source dim)
  const int ko = (tid >> 4) * 4;  // outer quad base

  const float* src;
  size_t srcStride;
  unsigned short* dstBase;
  size_t dstStride;

  if (bid < nW1) {
    // W1[e][k][f] -> W1t[e][f-f0][k]; inner=f (64), outer=k (256)
    const int nf = FC / 64;
    const int e = bid / (4 * nf);
    const int rem = bid % (4 * nf);
    const int fb = (rem % nf) * 64;
    const int kb = (rem / nf) * 256;
    src = W1 + ((size_t)e * 1024 + kb) * 4096 + f0 + fb + qi;
    srcStride = 4096;
    dstBase = W1t + ((size_t)e * FC + fb) * 1024 + kb;
    dstStride = 1024;
  } else {
    // W2[e][f][d] -> W2t[e][d][f-f0]; inner=d (64), outer=f (256)
    const int jd = bid - nW1;
    const int nf = FC / 256;
    const int e = jd / (16 * nf);
    const int rem = jd % (16 * nf);
    const int db = (rem % 16) * 64;
    const int fbl = (rem / 16) * 256;
    src = W2 + ((size_t)e * 4096 + f0 + fbl) * 1024 + db + qi;
    srcStride = 1024;
    dstBase = W2t + ((size_t)e * 1024 + db) * FC + fbl;
    dstStride = FC;
  }

  // issue all 16 loads (16 outstanding per thread)
  f32x4 r0[4], r1[4], r2[4], r3[4];
#pragma unroll
  for (int it = 0; it < 4; ++it) {
    const float* s = src + (size_t)(it * 64 + ko) * srcStride;
    r0[it] = gload4(s);
    r1[it] = gload4(s + srcStride);
    r2[it] = gload4(s + 2 * srcStride);
    r3[it] = gload4(s + 3 * srcStride);
  }
  asm volatile("s_waitcnt vmcnt(0)" ::: "memory");
  __builtin_amdgcn_sched_barrier(0);

#pragma unroll
  for (int it = 0; it < 4; ++it) {
    const int o0 = it * 64 + ko;
    const int c8 = o0 >> 3;
    const int off = o0 & 7;
#pragma unroll
    for (int i = 0; i < 4; ++i) {
      const int row = qi + i;
      const int cs = c8 ^ ((row >> 1) & 7);
      uint2 u;
      u.x = (unsigned)f2bf(r0[it][i]) | ((unsigned)f2bf(r1[it][i]) << 16);
      u.y = (unsigned)f2bf(r2[it][i]) | ((unsigned)f2bf(r3[it][i]) << 16);
      *(uint2*)&T[row][cs * 8 + off] = u;
    }
  }
  __syncthreads();
  const int rr = tid >> 2;  // 0..63 (inner-dim row)
  const int sg = tid & 3;
  unsigned short* dst = dstBase + (size_t)rr * dstStride;
  const int swz = (rr >> 1) & 7;
#pragma unroll
  for (int j = 0; j < 8; ++j) {
    const int c = sg + j * 4;  // logical 16B chunk; 4 lanes -> 64B contiguous
    *(uint4*)(dst + c * 8) = *(const uint4*)&T[rr][(c ^ swz) * 8];
  }
}

// -------- merged prep: blocks [0,1024) gate, [1024, 1024+nW1+nW2) transW ----
__global__ __launch_bounds__(256) void prep_kernel(
    const float* __restrict__ x, const float* __restrict__ Wg,
    const float* __restrict__ bg, int* __restrict__ tok_e,
    float* __restrict__ tok_w, unsigned short* __restrict__ xb,
    const float* __restrict__ W1, const float* __restrict__ W2,
    unsigned short* __restrict__ W1t, unsigned short* __restrict__ W2t, int FC,
    int f0, int nW1) {
  __shared__ __align__(16) unsigned short T[64][264];
  const int bid = blockIdx.x;
  if (bid < 1024) {
    gate_body(bid, x, Wg, bg, tok_e, tok_w, xb);
  } else {
    transW_body(bid - 1024, W1, W2, W1t, W2t, FC, f0, nW1, T);
  }
}

// -------- standalone versions (fallback when FC < 4096, chunked) ------------
__global__ __launch_bounds__(256) void gate_kernel(
    const float* __restrict__ x, const float* __restrict__ Wg,
    const float* __restrict__ bg, int* __restrict__ tok_e,
    float* __restrict__ tok_w, unsigned short* __restrict__ xb) {
  gate_body(blockIdx.x, x, Wg, bg, tok_e, tok_w, xb);
}

__global__ __launch_bounds__(256) void transW_kernel(
    const float* __restrict__ W1, const float* __restrict__ W2,
    unsigned short* __restrict__ W1t, unsigned short* __restrict__ W2t, int FC,
    int f0, int nW1) {
  __shared__ __align__(16) unsigned short T[64][264];
  transW_body(blockIdx.x, W1, W2, W1t, W2t, FC, f0, nW1, T);
}

// ------- scan + scatter (single block); computes counts internally ----------
__global__ __launch_bounds__(256) void scan_scatter_kernel(
    const int* __restrict__ tok_e, int* __restrict__ counts,
    int* __restrict__ offsets, int* __restrict__ pair_token,
    int* __restrict__ tok_slot) {
  __shared__ int scnt[8];
  __shared__ int scur[8];
  const int tid = threadIdx.x;
  if (tid < 8) scnt[tid] = 0;
  __syncthreads();
  for (int i = tid; i < 8192; i += 256) atomicAdd(&scnt[tok_e[i]], 1);
  __syncthreads();
  if (tid == 0) {
    int s = 0;
    for (int e = 0; e < 8; ++e) {
      counts[e] = scnt[e];
      offsets[e] = s;
      scur[e] = s;
      s += scnt[e];
    }
  }
  __syncthreads();
  for (int t = tid; t < 4096; t += 256) {
#pragma unroll
    for (int j = 0; j < 2; ++j) {
      const int e = tok_e[2 * t + j];
      const int slot = atomicAdd(&scur[e], 1);
      pair_token[slot] = t;
      tok_slot[2 * t + j] = slot;
    }
  }
}

// COMPUTE for 128x64 wave tile: 12 ds_read -> 32 MFMA.
#define COMPUTE32(ALDS, BLDS)                                             \
  {                                                                       \
    bf16x8 a[8], b[4];                                                    \
    _Pragma("unroll") for (int mi = 0; mi < 8; ++mi)                      \
        a[mi] = ldsr128(&ALDS[rdA[mi]]);                                  \
    _Pragma("unroll") for (int nj = 0; nj < 4; ++nj)                      \
        b[nj] = ldsr128(&BLDS[rdB[nj]]);                                  \
    asm volatile("s_waitcnt lgkmcnt(0)" ::: "memory");                    \
    __builtin_amdgcn_sched_barrier(0);                                    \
    _Pragma("unroll") for (int mi = 0; mi < 8; ++mi)                      \
        _Pragma("unroll") for (int nj = 0; nj < 4; ++nj)                  \
        acc[mi][nj] = MFMA16(a[mi], b[nj], acc[mi][nj]);                  \
    __builtin_amdgcn_sched_barrier(0);                                    \
  }

// ---------------- GEMM1: H[slot][n] = relu(xb[tok] @ W1t[e] + b1) -----------
// 256x128 tile, BK=32, 4 waves 2Mx2N (wave tile 128x64), gload_lds + XOR
// swizzle, 2-buf counted vmcnt(6), n-fastest tile order.
__global__ __launch_bounds__(256, 2) void gemm1_kernel(
    const unsigned short* __restrict__ xb,
    const unsigned short* __restrict__ W1t, const float* __restrict__ b1,
    const int* __restrict__ counts, const int* __restrict__ offsets,
    const int* __restrict__ pair_token, unsigned short* __restrict__ H, int FC,
    int f0, int NT) {
  const int bid = blockIdx.x;
  const int e = bid & 7;  // XCD pinning
  const int lid = bid >> 3;
  const int n0 = (lid % NT) * 128;
  const int m0 = (lid / NT) * 256;
  const int count = counts[e];
  if (m0 >= count) return;
  const int offset = offsets[e];

  __shared__ __align__(16) unsigned short Alds[2][256 * 32];
  __shared__ __align__(16) unsigned short Blds[2][128 * 32];
  __shared__ int toklds[256];

  const int tid = threadIdx.x;
  {
    int r = m0 + tid;
    if (r >= count) r = count - 1;
    toklds[tid] = pair_token[offset + r];
  }
  __syncthreads();

  const int lane = tid & 63;
  const int wave = tid >> 6;

  // staging: A 1024 chunks (4/thread), B 512 chunks (2/thread)
  const unsigned short* agp[4];
  const unsigned short* bgp[2];
  int ldsoA[4], ldsoB[2];
#pragma unroll
  for (int j = 0; j < 4; ++j) {
    const int g = tid + 256 * j;
    const int row = g >> 2;
    const int sc = (g & 3) ^ ((row >> 1) & 3);
    agp[j] = xb + (size_t)toklds[row] * 1024 + sc * 8;
    ldsoA[j] = (wave * 64 + 256 * j) * 8;
  }
#pragma unroll
  for (int j = 0; j < 2; ++j) {
    const int g = tid + 256 * j;
    const int row = g >> 2;
    const int sc = (g & 3) ^ ((row >> 1) & 3);
    bgp[j] = W1t + ((size_t)e * FC + n0 + row) * 1024 + sc * 8;
    ldsoB[j] = (wave * 64 + 256 * j) * 8;
  }

  const int wm = (wave >> 1) * 128;
  const int wn = (wave & 1) * 64;
  const int l16 = lane & 15;
  const int lk = lane >> 4;
  int rdA[8], rdB[4];
#pragma unroll
  for (int mi = 0; mi < 8; ++mi) {
    const int row = wm + mi * 16 + l16;
    rdA[mi] = row * 32 + ((lk ^ ((row >> 1) & 3)) << 3);
  }
#pragma unroll
  for (int nj = 0; nj < 4; ++nj) {
    const int row = wn + nj * 16 + l16;
    rdB[nj] = row * 32 + ((lk ^ ((row >> 1) & 3)) << 3);
  }

  f32x4 acc[8][4] = {};

  auto STAGE = [&](int kt, int buf) {  // kt in shorts (k index)
#pragma unroll
    for (int j = 0; j < 4; ++j) gload_lds16(agp[j] + kt, &Alds[buf][ldsoA[j]]);
#pragma unroll
    for (int j = 0; j < 2; ++j) gload_lds16(bgp[j] + kt, &Blds[buf][ldsoB[j]]);
  };

  const int NTk = 32;  // K = 1024 / 32
  STAGE(0, 0);
  for (int t = 0; t < NTk; ++t) {
    __builtin_amdgcn_s_barrier();  // all waves done reading buf[(t+1)&1]
    if (t + 1 < NTk) {
      STAGE((t + 1) * 32, (t + 1) & 1);
      asm volatile("s_waitcnt vmcnt(6)" ::: "memory");  // t's loads landed
    } else {
      asm volatile("s_waitcnt vmcnt(0)" ::: "memory");
    }
    __builtin_amdgcn_s_barrier();  // buf[t&1] staged by all waves
    __builtin_amdgcn_sched_barrier(0);
    COMPUTE32(Alds[t & 1], Blds[t & 1]);
  }

#pragma unroll
  for (int mi = 0; mi < 8; ++mi) {
#pragma unroll
    for (int r = 0; r < 4; ++r) {
      const int rl = m0 + wm + mi * 16 + lk * 4 + r;
      if (rl >= count) continue;
      unsigned short* hrow = H + (size_t)(offset + rl) * FC;
#pragma unroll
      for (int nj = 0; nj < 4; ++nj) {
        const int c = n0 + wn + nj * 16 + l16;
        float v = acc[mi][nj][r] + b1[e * 4096 + f0 + c];
        hrow[c] = f2bf(v > 0.f ? v : 0.f);
      }
    }
  }
}

// ------- GEMM2: P[ks][slot][d] (bf16) = slice_ks(H[slot] @ W2t[e]) (+ b2) ---
// 256x128 tile, split-K=2, private bf16 partial buffers.
__global__ __launch_bounds__(256, 2) void gemm2_kernel(
    const unsigned short* __restrict__ H,
    const unsigned short* __restrict__ W2t, const float* __restrict__ b2,
    const int* __restrict__ counts, const int* __restrict__ offsets,
    unsigned short* __restrict__ P, int FC, int firstChunk) {
  const int bid = blockIdx.x;
  const int e = bid & 7;  // XCD pinning
  const int r2 = bid >> 3;
  const int n0 = (r2 & 7) * 128;          // 8 n-tiles (N=1024), fastest
  const int m0 = ((r2 >> 3) & 15) * 256;  // 16 m-tiles of 256
  const int ks = r2 >> 7;                 // K split 0/1
  const int count = counts[e];
  if (m0 >= count) return;
  const int offset = offsets[e];
  const int KS = FC / 2;
  const int kb = ks * KS;
  unsigned short* Pb = P + (size_t)ks * 8192 * 1024;

  __shared__ __align__(16) unsigned short Alds[2][256 * 32];
  __shared__ __align__(16) unsigned short Blds[2][128 * 32];

  const int tid = threadIdx.x;
  const int lane = tid & 63;
  const int wave = tid >> 6;

  const unsigned short* agp[4];
  const unsigned short* bgp[2];
  int ldsoA[4], ldsoB[2];
#pragma unroll
  for (int j = 0; j < 4; ++j) {
    const int g = tid + 256 * j;
    const int row = g >> 2;
    const int sc = (g & 3) ^ ((row >> 1) & 3);
    int ar = m0 + row;
    if (ar >= count) ar = count - 1;
    agp[j] = H + (size_t)(offset + ar) * FC + kb + sc * 8;
    ldsoA[j] = (wave * 64 + 256 * j) * 8;
  }
#pragma unroll
  for (int j = 0; j < 2; ++j) {
    const int g = tid + 256 * j;
    const int row = g >> 2;
    const int sc = (g & 3) ^ ((row >> 1) & 3);
    bgp[j] = W2t + ((size_t)e * 1024 + n0 + row) * FC + kb + sc * 8;
    ldsoB[j] = (wave * 64 + 256 * j) * 8;
  }

  const int wm = (wave >> 1) * 128;
  const int wn = (wave & 1) * 64;
  const int l16 = lane & 15;
  const int lk = lane >> 4;
  int rdA[8], rdB[4];
#pragma unroll
  for (int mi = 0; mi < 8; ++mi) {
    const int row = wm + mi * 16 + l16;
    rdA[mi] = row * 32 + ((lk ^ ((row >> 1) & 3)) << 3);
  }
#pragma unroll
  for (int nj = 0; nj < 4; ++nj) {
    const int row = wn + nj * 16 + l16;
    rdB[nj] = row * 32 + ((lk ^ ((row >> 1) & 3)) << 3);
  }

  f32x4 acc[8][4] = {};

  auto STAGE = [&](int kt, int buf) {
#pragma unroll
    for (int j = 0; j < 4; ++j) gload_lds16(agp[j] + kt, &Alds[buf][ldsoA[j]]);
#pragma unroll
    for (int j = 0; j < 2; ++j) gload_lds16(bgp[j] + kt, &Blds[buf][ldsoB[j]]);
  };

  const int NTk = KS / 32;
  STAGE(0, 0);
  for (int t = 0; t < NTk; ++t) {
    __builtin_amdgcn_s_barrier();
    if (t + 1 < NTk) {
      STAGE((t + 1) * 32, (t + 1) & 1);
      asm volatile("s_waitcnt vmcnt(6)" ::: "memory");
    } else {
      asm volatile("s_waitcnt vmcnt(0)" ::: "memory");
    }
    __builtin_amdgcn_s_barrier();
    __builtin_amdgcn_sched_barrier(0);
    COMPUTE32(Alds[t & 1], Blds[t & 1]);
  }

#pragma unroll
  for (int mi = 0; mi < 8; ++mi) {
#pragma unroll
    for (int r = 0; r < 4; ++r) {
      const int rl = m0 + wm + mi * 16 + lk * 4 + r;
      if (rl >= count) continue;
      unsigned short* prow = Pb + (size_t)(offset + rl) * 1024;
#pragma unroll
      for (int nj = 0; nj < 4; ++nj) {
        const int c = n0 + wn + nj * 16 + l16;
        float v = acc[mi][nj][r];
        if (ks == 0 && firstChunk) v += b2[e * 1024 + c];
        if (firstChunk) {
          prow[c] = f2bf(v);
        } else {
          prow[c] = f2bf(bf2f(prow[c]) + v);
        }
      }
    }
  }
}

// ---- combine: out[t] = w0*(P0[s0]+P1[s0]) + w1*(P0[s1]+P1[s1]) (bf16 P) ----
__global__ __launch_bounds__(256) void combine_kernel(
    const unsigned short* __restrict__ P, const int* __restrict__ tok_slot,
    const float* __restrict__ tok_w, float* __restrict__ out) {
  const int t = blockIdx.x;
  const int d = threadIdx.x * 4;
  const int s0 = tok_slot[2 * t];
  const int s1 = tok_slot[2 * t + 1];
  const float w0 = tok_w[2 * t];
  const float w1 = tok_w[2 * t + 1];
  const ushort4 a0 = *(const ushort4*)&P[(size_t)s0 * 1024 + d];
  const ushort4 a1 = *(const ushort4*)&P[(size_t)(8192 + s0) * 1024 + d];
  const ushort4 c0 = *(const ushort4*)&P[(size_t)s1 * 1024 + d];
  const ushort4 c1 = *(const ushort4*)&P[(size_t)(8192 + s1) * 1024 + d];
  float4 r;
  r.x = w0 * (bf2f(a0.x) + bf2f(a1.x)) + w1 * (bf2f(c0.x) + bf2f(c1.x));
  r.y = w0 * (bf2f(a0.y) + bf2f(a1.y)) + w1 * (bf2f(c0.y) + bf2f(c1.y));
  r.z = w0 * (bf2f(a0.z) + bf2f(a1.z)) + w1 * (bf2f(c0.z) + bf2f(c1.z));
  r.w = w0 * (bf2f(a0.w) + bf2f(a1.w)) + w1 * (bf2f(c0.w) + bf2f(c1.w));
  *(float4*)&out[(size_t)t * 1024 + d] = r;
}

extern "C" void kernel_launch(void* const* d_in, const int* in_sizes, int n_in,
                              void* d_out, int out_size, void* d_ws,
                              size_t ws_size, hipStream_t stream) {
  const float* x = (const float*)d_in[0];
  const float* Wg = (const float*)d_in[1];
  const float* bg = (const float*)d_in[2];
  const float* W1 = (const float*)d_in[3];
  const float* b1 = (const float*)d_in[4];
  const float* W2 = (const float*)d_in[5];
  const float* b2 = (const float*)d_in[6];
  float* out = (float*)d_out;

  char* w = (char*)d_ws;
  int* counts = (int*)w;
  int* offsets = counts + 16;
  int* tok_e = (int*)(w + 1024);
  float* tok_w = (float*)(w + 1024 + 32768);
  int* pair_token = (int*)(w + 1024 + 65536);
  int* tok_slot = (int*)(w + 1024 + 98304);
  unsigned short* xb = (unsigned short*)(w + 256 * 1024);  // 8MB
  unsigned short* P =
      (unsigned short*)(w + 256 * 1024 + 8 * 1024 * 1024);  // 32MB bf16 x2
  char* big = w + 256 * 1024 + 8 * 1024 * 1024 + 32 * 1024 * 1024;
  const size_t avail =
      ws_size - (256 * 1024 + 8 * 1024 * 1024 + 32 * 1024 * 1024);

  // per-chunk: W1t 16384*FC + W2t 16384*FC + H 16384*FC bytes
  int FC = 4096;
  while (FC > 512 && (size_t)FC * 49152 > avail) FC >>= 1;

  unsigned short* W1t = (unsigned short*)big;
  unsigned short* W2t = W1t + (size_t)8 * FC * 1024;
  unsigned short* Hc = W2t + (size_t)8 * 1024 * FC;

  const int NT = FC / 128;
  const int nW1 = (FC / 64) * 4 * 8;    // 64f x 256k tiles
  const int nW2 = 16 * (FC / 256) * 8;  // 64d x 256f tiles

  if (FC == 4096) {
    prep_kernel<<<1024 + nW1 + nW2, 256, 0, stream>>>(
        x, Wg, bg, tok_e, tok_w, xb, W1, W2, W1t, W2t, FC, 0, nW1);
    scan_scatter_kernel<<<1, 256, 0, stream>>>(tok_e, counts, offsets,
                                               pair_token, tok_slot);
    gemm1_kernel<<<8 * 16 * NT, 256, 0, stream>>>(
        xb, W1t, b1, counts, offsets, pair_token, Hc, FC, 0, NT);
    gemm2_kernel<<<8 * 8 * 16 * 2, 256, 0, stream>>>(
        Hc, W2t, b2, counts, offsets, P, FC, 1);
  } else {
    gate_kernel<<<1024, 256, 0, stream>>>(x, Wg, bg, tok_e, tok_w, xb);
    scan_scatter_kernel<<<1, 256, 0, stream>>>(tok_e, counts, offsets,
                                               pair_token, tok_slot);
    for (int f0 = 0; f0 < 4096; f0 += FC) {
      transW_kernel<<<nW1 + nW2, 256, 0, stream>>>(W1, W2, W1t, W2t, FC, f0,
                                                   nW1);
      gemm1_kernel<<<8 * 16 * NT, 256, 0, stream>>>(
          xb, W1t, b1, counts, offsets, pair_token, Hc, FC, f0, NT);
      gemm2_kernel<<<8 * 8 * 16 * 2, 256, 0, stream>>>(
          Hc, W2t, b2, counts, offsets, P, FC, f0 == 0 ? 1 : 0);
    }
  }
  combine_kernel<<<4096, 256, 0, stream>>>(P, tok_slot, tok_w, out);
}

// Round 21
// 321.976 us; speedup vs baseline: 1.3123x; 1.0009x over previous
//
#include <hip/hip_runtime.h>
#include <hip/hip_bf16.h>

// SimpleMoE: B=2,S=2048 -> 4096 tokens, DIM=1024, FF=4096, E=8, top-2 routing.
// Round 21: transW phase-1 MLP fix, take 2 — 16 NAMED f32x4 asm-load results
// (arrays were demoted -> VGPR stayed 52, loads serialized). Forces 16
// outstanding loads/thread. Everything else identical to r20.

typedef __attribute__((ext_vector_type(8))) short bf16x8;
typedef __attribute__((ext_vector_type(4))) float f32x4;

#define MFMA16(a, b, c) __builtin_amdgcn_mfma_f32_16x16x32_bf16((a), (b), (c), 0, 0, 0)

__device__ __forceinline__ unsigned short f2bf(float f) {
  unsigned u = __builtin_bit_cast(unsigned, f);
  u += 0x7FFFu + ((u >> 16) & 1u);
  return (unsigned short)(u >> 16);
}

__device__ __forceinline__ float bf2f(unsigned short s) {
  return __builtin_bit_cast(float, (unsigned)s << 16);
}

__device__ __forceinline__ void gload_lds16(const void* g, void* l) {
  __builtin_amdgcn_global_load_lds(
      (const __attribute__((address_space(1))) unsigned int*)g,
      (__attribute__((address_space(3))) unsigned int*)l, 16, 0, 0);
}

// inline-asm LDS read: keeps the compiler from serializing ds_read behind
// in-flight global_load_lds (false alias) with a vmcnt(0).
__device__ __forceinline__ bf16x8 ldsr128(const void* p) {
  bf16x8 r;
  unsigned a = (unsigned)(unsigned long long)p;
  asm volatile("ds_read_b128 %0, %1" : "=v"(r) : "v"(a));
  return r;
}

// inline-asm global fp32x4 load; completion gated by a later counted vmcnt.
__device__ __forceinline__ f32x4 gload4(const float* p) {
  f32x4 r;
  asm volatile("global_load_dwordx4 %0, %1, off" : "=v"(r) : "v"(p) : "memory");
  return r;
}

// ---------------- gate device body (one 256-thr block handles 4 tokens) -----
__device__ __forceinline__ void gate_body(
    int blk, const float* __restrict__ x, const float* __restrict__ Wg,
    const float* __restrict__ bg, int* __restrict__ tok_e,
    float* __restrict__ tok_w, unsigned short* __restrict__ xb) {
  const int wave = threadIdx.x >> 6;
  const int lane = threadIdx.x & 63;
  const int t = blk * 4 + wave;
  const float* xr = x + (size_t)t * 1024;
  unsigned short* xrow = xb + (size_t)t * 1024;
  double acc[8] = {0, 0, 0, 0, 0, 0, 0, 0};
  for (int i = 0; i < 16; ++i) {
    const int d = i * 64 + lane;
    const float vx = xr[d];
    xrow[d] = f2bf(vx);
    const double xv = (double)vx;
    const float* wr = Wg + d * 8;
#pragma unroll
    for (int e = 0; e < 8; ++e) acc[e] += xv * (double)wr[e];
  }
#pragma unroll
  for (int e = 0; e < 8; ++e) {
    double v = acc[e];
#pragma unroll
    for (int off = 32; off > 0; off >>= 1) v += __shfl_xor(v, off, 64);
    acc[e] = v + (double)bg[e];
  }
  if (lane == 0) {
    int e0 = 0;
#pragma unroll
    for (int e = 1; e < 8; ++e)
      if (acc[e] > acc[e0]) e0 = e;
    int e1 = (e0 == 0) ? 1 : 0;
#pragma unroll
    for (int e = 0; e < 8; ++e) {
      if (e != e0 && acc[e] > acc[e1]) e1 = e;
    }
    const double m = acc[e0];
    double s = 0.0;
#pragma unroll
    for (int e = 0; e < 8; ++e) s += exp(acc[e] - m);
    const double p0 = exp(acc[e0] - m) / s;
    const double p1 = exp(acc[e1] - m) / s;
    const double den = p0 + p1 + 1e-9;
    tok_e[2 * t] = e0;
    tok_e[2 * t + 1] = e1;
    tok_w[2 * t] = (float)(p0 / den);
    tok_w[2 * t + 1] = (float)(p1 / den);
  }
}

// ------- transW device body: 64(inner) x 256(outer) register-transpose ------
// Phase 1: 16 NAMED f32x4 loads issued up-front -> one vmcnt(0) -> convert +
// swizzled LDS write. Phase 2: 64B-contiguous global writes.
__device__ __forceinline__ void transW_body(
    int bid, const float* __restrict__ W1, const float* __restrict__ W2,
    unsigned short* __restrict__ W1t, unsigned short* __restrict__ W2t, int FC,
    int f0, int nW1, unsigned short (*T)[264]) {
  const int tid = threadIdx.x;
  const int qi = (tid & 15) * 4;  // inner quad (contiguous source dim)
  const int ko = (tid >> 4) * 4;  // outer quad base

  const float* src;
  size_t srcStride;
  unsigned short* dstBase;
  size_t dstStride;

  if (bid < nW1) {
    // W1[e][k][f] -> W1t[e][f-f0][k]; inner=f (64), outer=k (256)
    const int nf = FC / 64;
    const int e = bid / (4 * nf);
    const int rem = bid % (4 * nf);
    const int fb = (rem % nf) * 64;
    const int kb = (rem / nf) * 256;
    src = W1 + ((size_t)e * 1024 + kb) * 4096 + f0 + fb + qi;
    srcStride = 4096;
    dstBase = W1t + ((size_t)e * FC + fb) * 1024 + kb;
    dstStride = 1024;
  } else {
    // W2[e][f][d] -> W2t[e][d][f-f0]; inner=d (64), outer=f (256)
    const int jd = bid - nW1;
    const int nf = FC / 256;
    const int e = jd / (16 * nf);
    const int rem = jd % (16 * nf);
    const int db = (rem % 16) * 64;
    const int fbl = (rem / 16) * 256;
    src = W2 + ((size_t)e * 4096 + f0 + fbl) * 1024 + db + qi;
    srcStride = 1024;
    dstBase = W2t + ((size_t)e * 1024 + db) * FC + fbl;
    dstStride = FC;
  }

  // issue all 16 loads into NAMED registers (16 outstanding per thread)
  const float* s0 = src + (size_t)(ko + 0) * srcStride;
  const float* s1 = src + (size_t)(64 + ko) * srcStride;
  const float* s2 = src + (size_t)(128 + ko) * srcStride;
  const float* s3 = src + (size_t)(192 + ko) * srcStride;
  f32x4 v00 = gload4(s0);
  f32x4 v01 = gload4(s0 + srcStride);
  f32x4 v02 = gload4(s0 + 2 * srcStride);
  f32x4 v03 = gload4(s0 + 3 * srcStride);
  f32x4 v10 = gload4(s1);
  f32x4 v11 = gload4(s1 + srcStride);
  f32x4 v12 = gload4(s1 + 2 * srcStride);
  f32x4 v13 = gload4(s1 + 3 * srcStride);
  f32x4 v20 = gload4(s2);
  f32x4 v21 = gload4(s2 + srcStride);
  f32x4 v22 = gload4(s2 + 2 * srcStride);
  f32x4 v23 = gload4(s2 + 3 * srcStride);
  f32x4 v30 = gload4(s3);
  f32x4 v31 = gload4(s3 + srcStride);
  f32x4 v32 = gload4(s3 + 2 * srcStride);
  f32x4 v33 = gload4(s3 + 3 * srcStride);
  asm volatile("s_waitcnt vmcnt(0)" ::: "memory");
  __builtin_amdgcn_sched_barrier(0);

#define TW_STORE(IT, A, B, C, D)                                          \
  {                                                                       \
    const int o0 = (IT)*64 + ko;                                          \
    const int c8 = o0 >> 3;                                               \
    const int off = o0 & 7;                                               \
    _Pragma("unroll") for (int i = 0; i < 4; ++i) {                       \
      const int row = qi + i;                                             \
      const int cs = c8 ^ ((row >> 1) & 7);                               \
      uint2 u;                                                            \
      u.x = (unsigned)f2bf((A)[i]) | ((unsigned)f2bf((B)[i]) << 16);      \
      u.y = (unsigned)f2bf((C)[i]) | ((unsigned)f2bf((D)[i]) << 16);      \
      *(uint2*)&T[row][cs * 8 + off] = u;                                 \
    }                                                                     \
  }
  TW_STORE(0, v00, v01, v02, v03)
  TW_STORE(1, v10, v11, v12, v13)
  TW_STORE(2, v20, v21, v22, v23)
  TW_STORE(3, v30, v31, v32, v33)
#undef TW_STORE

  __syncthreads();
  const int rr = tid >> 2;  // 0..63 (inner-dim row)
  const int sg = tid & 3;
  unsigned short* dst = dstBase + (size_t)rr * dstStride;
  const int swz = (rr >> 1) & 7;
#pragma unroll
  for (int j = 0; j < 8; ++j) {
    const int c = sg + j * 4;  // logical 16B chunk; 4 lanes -> 64B contiguous
    *(uint4*)(dst + c * 8) = *(const uint4*)&T[rr][(c ^ swz) * 8];
  }
}

// -------- merged prep: blocks [0,1024) gate, [1024, 1024+nW1+nW2) transW ----
__global__ __launch_bounds__(256) void prep_kernel(
    const float* __restrict__ x, const float* __restrict__ Wg,
    const float* __restrict__ bg, int* __restrict__ tok_e,
    float* __restrict__ tok_w, unsigned short* __restrict__ xb,
    const float* __restrict__ W1, const float* __restrict__ W2,
    unsigned short* __restrict__ W1t, unsigned short* __restrict__ W2t, int FC,
    int f0, int nW1) {
  __shared__ __align__(16) unsigned short T[64][264];
  const int bid = blockIdx.x;
  if (bid < 1024) {
    gate_body(bid, x, Wg, bg, tok_e, tok_w, xb);
  } else {
    transW_body(bid - 1024, W1, W2, W1t, W2t, FC, f0, nW1, T);
  }
}

// -------- standalone versions (fallback when FC < 4096, chunked) ------------
__global__ __launch_bounds__(256) void gate_kernel(
    const float* __restrict__ x, const float* __restrict__ Wg,
    const float* __restrict__ bg, int* __restrict__ tok_e,
    float* __restrict__ tok_w, unsigned short* __restrict__ xb) {
  gate_body(blockIdx.x, x, Wg, bg, tok_e, tok_w, xb);
}

__global__ __launch_bounds__(256) void transW_kernel(
    const float* __restrict__ W1, const float* __restrict__ W2,
    unsigned short* __restrict__ W1t, unsigned short* __restrict__ W2t, int FC,
    int f0, int nW1) {
  __shared__ __align__(16) unsigned short T[64][264];
  transW_body(blockIdx.x, W1, W2, W1t, W2t, FC, f0, nW1, T);
}

// ------- scan + scatter (single block); computes counts internally ----------
__global__ __launch_bounds__(256) void scan_scatter_kernel(
    const int* __restrict__ tok_e, int* __restrict__ counts,
    int* __restrict__ offsets, int* __restrict__ pair_token,
    int* __restrict__ tok_slot) {
  __shared__ int scnt[8];
  __shared__ int scur[8];
  const int tid = threadIdx.x;
  if (tid < 8) scnt[tid] = 0;
  __syncthreads();
  for (int i = tid; i < 8192; i += 256) atomicAdd(&scnt[tok_e[i]], 1);
  __syncthreads();
  if (tid == 0) {
    int s = 0;
    for (int e = 0; e < 8; ++e) {
      counts[e] = scnt[e];
      offsets[e] = s;
      scur[e] = s;
      s += scnt[e];
    }
  }
  __syncthreads();
  for (int t = tid; t < 4096; t += 256) {
#pragma unroll
    for (int j = 0; j < 2; ++j) {
      const int e = tok_e[2 * t + j];
      const int slot = atomicAdd(&scur[e], 1);
      pair_token[slot] = t;
      tok_slot[2 * t + j] = slot;
    }
  }
}

// COMPUTE for 128x64 wave tile: 12 ds_read -> 32 MFMA.
#define COMPUTE32(ALDS, BLDS)                                             \
  {                                                                       \
    bf16x8 a[8], b[4];                                                    \
    _Pragma("unroll") for (int mi = 0; mi < 8; ++mi)                      \
        a[mi] = ldsr128(&ALDS[rdA[mi]]);                                  \
    _Pragma("unroll") for (int nj = 0; nj < 4; ++nj)                      \
        b[nj] = ldsr128(&BLDS[rdB[nj]]);                                  \
    asm volatile("s_waitcnt lgkmcnt(0)" ::: "memory");                    \
    __builtin_amdgcn_sched_barrier(0);                                    \
    _Pragma("unroll") for (int mi = 0; mi < 8; ++mi)                      \
        _Pragma("unroll") for (int nj = 0; nj < 4; ++nj)                  \
        acc[mi][nj] = MFMA16(a[mi], b[nj], acc[mi][nj]);                  \
    __builtin_amdgcn_sched_barrier(0);                                    \
  }

// ---------------- GEMM1: H[slot][n] = relu(xb[tok] @ W1t[e] + b1) -----------
// 256x128 tile, BK=32, 4 waves 2Mx2N (wave tile 128x64), gload_lds + XOR
// swizzle, 2-buf counted vmcnt(6), n-fastest tile order.
__global__ __launch_bounds__(256, 2) void gemm1_kernel(
    const unsigned short* __restrict__ xb,
    const unsigned short* __restrict__ W1t, const float* __restrict__ b1,
    const int* __restrict__ counts, const int* __restrict__ offsets,
    const int* __restrict__ pair_token, unsigned short* __restrict__ H, int FC,
    int f0, int NT) {
  const int bid = blockIdx.x;
  const int e = bid & 7;  // XCD pinning
  const int lid = bid >> 3;
  const int n0 = (lid % NT) * 128;
  const int m0 = (lid / NT) * 256;
  const int count = counts[e];
  if (m0 >= count) return;
  const int offset = offsets[e];

  __shared__ __align__(16) unsigned short Alds[2][256 * 32];
  __shared__ __align__(16) unsigned short Blds[2][128 * 32];
  __shared__ int toklds[256];

  const int tid = threadIdx.x;
  {
    int r = m0 + tid;
    if (r >= count) r = count - 1;
    toklds[tid] = pair_token[offset + r];
  }
  __syncthreads();

  const int lane = tid & 63;
  const int wave = tid >> 6;

  // staging: A 1024 chunks (4/thread), B 512 chunks (2/thread)
  const unsigned short* agp[4];
  const unsigned short* bgp[2];
  int ldsoA[4], ldsoB[2];
#pragma unroll
  for (int j = 0; j < 4; ++j) {
    const int g = tid + 256 * j;
    const int row = g >> 2;
    const int sc = (g & 3) ^ ((row >> 1) & 3);
    agp[j] = xb + (size_t)toklds[row] * 1024 + sc * 8;
    ldsoA[j] = (wave * 64 + 256 * j) * 8;
  }
#pragma unroll
  for (int j = 0; j < 2; ++j) {
    const int g = tid + 256 * j;
    const int row = g >> 2;
    const int sc = (g & 3) ^ ((row >> 1) & 3);
    bgp[j] = W1t + ((size_t)e * FC + n0 + row) * 1024 + sc * 8;
    ldsoB[j] = (wave * 64 + 256 * j) * 8;
  }

  const int wm = (wave >> 1) * 128;
  const int wn = (wave & 1) * 64;
  const int l16 = lane & 15;
  const int lk = lane >> 4;
  int rdA[8], rdB[4];
#pragma unroll
  for (int mi = 0; mi < 8; ++mi) {
    const int row = wm + mi * 16 + l16;
    rdA[mi] = row * 32 + ((lk ^ ((row >> 1) & 3)) << 3);
  }
#pragma unroll
  for (int nj = 0; nj < 4; ++nj) {
    const int row = wn + nj * 16 + l16;
    rdB[nj] = row * 32 + ((lk ^ ((row >> 1) & 3)) << 3);
  }

  f32x4 acc[8][4] = {};

  auto STAGE = [&](int kt, int buf) {  // kt in shorts (k index)
#pragma unroll
    for (int j = 0; j < 4; ++j) gload_lds16(agp[j] + kt, &Alds[buf][ldsoA[j]]);
#pragma unroll
    for (int j = 0; j < 2; ++j) gload_lds16(bgp[j] + kt, &Blds[buf][ldsoB[j]]);
  };

  const int NTk = 32;  // K = 1024 / 32
  STAGE(0, 0);
  for (int t = 0; t < NTk; ++t) {
    __builtin_amdgcn_s_barrier();  // all waves done reading buf[(t+1)&1]
    if (t + 1 < NTk) {
      STAGE((t + 1) * 32, (t + 1) & 1);
      asm volatile("s_waitcnt vmcnt(6)" ::: "memory");  // t's loads landed
    } else {
      asm volatile("s_waitcnt vmcnt(0)" ::: "memory");
    }
    __builtin_amdgcn_s_barrier();  // buf[t&1] staged by all waves
    __builtin_amdgcn_sched_barrier(0);
    COMPUTE32(Alds[t & 1], Blds[t & 1]);
  }

#pragma unroll
  for (int mi = 0; mi < 8; ++mi) {
#pragma unroll
    for (int r = 0; r < 4; ++r) {
      const int rl = m0 + wm + mi * 16 + lk * 4 + r;
      if (rl >= count) continue;
      unsigned short* hrow = H + (size_t)(offset + rl) * FC;
#pragma unroll
      for (int nj = 0; nj < 4; ++nj) {
        const int c = n0 + wn + nj * 16 + l16;
        float v = acc[mi][nj][r] + b1[e * 4096 + f0 + c];
        hrow[c] = f2bf(v > 0.f ? v : 0.f);
      }
    }
  }
}

// ------- GEMM2: P[ks][slot][d] (bf16) = slice_ks(H[slot] @ W2t[e]) (+ b2) ---
// 256x128 tile, split-K=2, private bf16 partial buffers.
__global__ __launch_bounds__(256, 2) void gemm2_kernel(
    const unsigned short* __restrict__ H,
    const unsigned short* __restrict__ W2t, const float* __restrict__ b2,
    const int* __restrict__ counts, const int* __restrict__ offsets,
    unsigned short* __restrict__ P, int FC, int firstChunk) {
  const int bid = blockIdx.x;
  const int e = bid & 7;  // XCD pinning
  const int r2 = bid >> 3;
  const int n0 = (r2 & 7) * 128;          // 8 n-tiles (N=1024), fastest
  const int m0 = ((r2 >> 3) & 15) * 256;  // 16 m-tiles of 256
  const int ks = r2 >> 7;                 // K split 0/1
  const int count = counts[e];
  if (m0 >= count) return;
  const int offset = offsets[e];
  const int KS = FC / 2;
  const int kb = ks * KS;
  unsigned short* Pb = P + (size_t)ks * 8192 * 1024;

  __shared__ __align__(16) unsigned short Alds[2][256 * 32];
  __shared__ __align__(16) unsigned short Blds[2][128 * 32];

  const int tid = threadIdx.x;
  const int lane = tid & 63;
  const int wave = tid >> 6;

  const unsigned short* agp[4];
  const unsigned short* bgp[2];
  int ldsoA[4], ldsoB[2];
#pragma unroll
  for (int j = 0; j < 4; ++j) {
    const int g = tid + 256 * j;
    const int row = g >> 2;
    const int sc = (g & 3) ^ ((row >> 1) & 3);
    int ar = m0 + row;
    if (ar >= count) ar = count - 1;
    agp[j] = H + (size_t)(offset + ar) * FC + kb + sc * 8;
    ldsoA[j] = (wave * 64 + 256 * j) * 8;
  }
#pragma unroll
  for (int j = 0; j < 2; ++j) {
    const int g = tid + 256 * j;
    const int row = g >> 2;
    const int sc = (g & 3) ^ ((row >> 1) & 3);
    bgp[j] = W2t + ((size_t)e * 1024 + n0 + row) * FC + kb + sc * 8;
    ldsoB[j] = (wave * 64 + 256 * j) * 8;
  }

  const int wm = (wave >> 1) * 128;
  const int wn = (wave & 1) * 64;
  const int l16 = lane & 15;
  const int lk = lane >> 4;
  int rdA[8], rdB[4];
#pragma unroll
  for (int mi = 0; mi < 8; ++mi) {
    const int row = wm + mi * 16 + l16;
    rdA[mi] = row * 32 + ((lk ^ ((row >> 1) & 3)) << 3);
  }
#pragma unroll
  for (int nj = 0; nj < 4; ++nj) {
    const int row = wn + nj * 16 + l16;
    rdB[nj] = row * 32 + ((lk ^ ((row >> 1) & 3)) << 3);
  }

  f32x4 acc[8][4] = {};

  auto STAGE = [&](int kt, int buf) {
#pragma unroll
    for (int j = 0; j < 4; ++j) gload_lds16(agp[j] + kt, &Alds[buf][ldsoA[j]]);
#pragma unroll
    for (int j = 0; j < 2; ++j) gload_lds16(bgp[j] + kt, &Blds[buf][ldsoB[j]]);
  };

  const int NTk = KS / 32;
  STAGE(0, 0);
  for (int t = 0; t < NTk; ++t) {
    __builtin_amdgcn_s_barrier();
    if (t + 1 < NTk) {
      STAGE((t + 1) * 32, (t + 1) & 1);
      asm volatile("s_waitcnt vmcnt(6)" ::: "memory");
    } else {
      asm volatile("s_waitcnt vmcnt(0)" ::: "memory");
    }
    __builtin_amdgcn_s_barrier();
    __builtin_amdgcn_sched_barrier(0);
    COMPUTE32(Alds[t & 1], Blds[t & 1]);
  }

#pragma unroll
  for (int mi = 0; mi < 8; ++mi) {
#pragma unroll
    for (int r = 0; r < 4; ++r) {
      const int rl = m0 + wm + mi * 16 + lk * 4 + r;
      if (rl >= count) continue;
      unsigned short* prow = Pb + (size_t)(offset + rl) * 1024;
#pragma unroll
      for (int nj = 0; nj < 4; ++nj) {
        const int c = n0 + wn + nj * 16 + l16;
        float v = acc[mi][nj][r];
        if (ks == 0 && firstChunk) v += b2[e * 1024 + c];
        if (firstChunk) {
          prow[c] = f2bf(v);
        } else {
          prow[c] = f2bf(bf2f(prow[c]) + v);
        }
      }
    }
  }
}

// ---- combine: out[t] = w0*(P0[s0]+P1[s0]) + w1*(P0[s1]+P1[s1]) (bf16 P) ----
__global__ __launch_bounds__(256) void combine_kernel(
    const unsigned short* __restrict__ P, const int* __restrict__ tok_slot,
    const float* __restrict__ tok_w, float* __restrict__ out) {
  const int t = blockIdx.x;
  const int d = threadIdx.x * 4;
  const int s0 = tok_slot[2 * t];
  const int s1 = tok_slot[2 * t + 1];
  const float w0 = tok_w[2 * t];
  const float w1 = tok_w[2 * t + 1];
  const ushort4 a0 = *(const ushort4*)&P[(size_t)s0 * 1024 + d];
  const ushort4 a1 = *(const ushort4*)&P[(size_t)(8192 + s0) * 1024 + d];
  const ushort4 c0 = *(const ushort4*)&P[(size_t)s1 * 1024 + d];
  const ushort4 c1 = *(const ushort4*)&P[(size_t)(8192 + s1) * 1024 + d];
  float4 r;
  r.x = w0 * (bf2f(a0.x) + bf2f(a1.x)) + w1 * (bf2f(c0.x) + bf2f(c1.x));
  r.y = w0 * (bf2f(a0.y) + bf2f(a1.y)) + w1 * (bf2f(c0.y) + bf2f(c1.y));
  r.z = w0 * (bf2f(a0.z) + bf2f(a1.z)) + w1 * (bf2f(c0.z) + bf2f(c1.z));
  r.w = w0 * (bf2f(a0.w) + bf2f(a1.w)) + w1 * (bf2f(c0.w) + bf2f(c1.w));
  *(float4*)&out[(size_t)t * 1024 + d] = r;
}

extern "C" void kernel_launch(void* const* d_in, const int* in_sizes, int n_in,
                              void* d_out, int out_size, void* d_ws,
                              size_t ws_size, hipStream_t stream) {
  const float* x = (const float*)d_in[0];
  const float* Wg = (const float*)d_in[1];
  const float* bg = (const float*)d_in[2];
  const float* W1 = (const float*)d_in[3];
  const float* b1 = (const float*)d_in[4];
  const float* W2 = (const float*)d_in[5];
  const float* b2 = (const float*)d_in[6];
  float* out = (float*)d_out;

  char* w = (char*)d_ws;
  int* counts = (int*)w;
  int* offsets = counts + 16;
  int* tok_e = (int*)(w + 1024);
  float* tok_w = (float*)(w + 1024 + 32768);
  int* pair_token = (int*)(w + 1024 + 65536);
  int* tok_slot = (int*)(w + 1024 + 98304);
  unsigned short* xb = (unsigned short*)(w + 256 * 1024);  // 8MB
  unsigned short* P =
      (unsigned short*)(w + 256 * 1024 + 8 * 1024 * 1024);  // 32MB bf16 x2
  char* big = w + 256 * 1024 + 8 * 1024 * 1024 + 32 * 1024 * 1024;
  const size_t avail =
      ws_size - (256 * 1024 + 8 * 1024 * 1024 + 32 * 1024 * 1024);

  // per-chunk: W1t 16384*FC + W2t 16384*FC + H 16384*FC bytes
  int FC = 4096;
  while (FC > 512 && (size_t)FC * 49152 > avail) FC >>= 1;

  unsigned short* W1t = (unsigned short*)big;
  unsigned short* W2t = W1t + (size_t)8 * FC * 1024;
  unsigned short* Hc = W2t + (size_t)8 * 1024 * FC;

  const int NT = FC / 128;
  const int nW1 = (FC / 64) * 4 * 8;    // 64f x 256k tiles
  const int nW2 = 16 * (FC / 256) * 8;  // 64d x 256f tiles

  if (FC == 4096) {
    prep_kernel<<<1024 + nW1 + nW2, 256, 0, stream>>>(
        x, Wg, bg, tok_e, tok_w, xb, W1, W2, W1t, W2t, FC, 0, nW1);
    scan_scatter_kernel<<<1, 256, 0, stream>>>(tok_e, counts, offsets,
                                               pair_token, tok_slot);
    gemm1_kernel<<<8 * 16 * NT, 256, 0, stream>>>(
        xb, W1t, b1, counts, offsets, pair_token, Hc, FC, 0, NT);
    gemm2_kernel<<<8 * 8 * 16 * 2, 256, 0, stream>>>(
        Hc, W2t, b2, counts, offsets, P, FC, 1);
  } else {
    gate_kernel<<<1024, 256, 0, stream>>>(x, Wg, bg, tok_e, tok_w, xb);
    scan_scatter_kernel<<<1, 256, 0, stream>>>(tok_e, counts, offsets,
                                               pair_token, tok_slot);
    for (int f0 = 0; f0 < 4096; f0 += FC) {
      transW_kernel<<<nW1 + nW2, 256, 0, stream>>>(W1, W2, W1t, W2t, FC, f0,
                                                   nW1);
      gemm1_kernel<<<8 * 16 * NT, 256, 0, stream>>>(
          xb, W1t, b1, counts, offsets, pair_token, Hc, FC, f0, NT);
      gemm2_kernel<<<8 * 8 * 16 * 2, 256, 0, stream>>>(
          Hc, W2t, b2, counts, offsets, P, FC, f0 == 0 ? 1 : 0);
    }
  }
  combine_kernel<<<4096, 256, 0, stream>>>(P, tok_slot, tok_w, out);
}

// Round 22
// 321.578 us; speedup vs baseline: 1.3139x; 1.0012x over previous
//
#include <hip/hip_runtime.h>
#include <hip/hip_bf16.h>

// SimpleMoE: B=2,S=2048 -> 4096 tokens, DIM=1024, FF=4096, E=8, top-2 routing.
// Round 22: transW tiles rotated to 256(contiguous-inner) x 64(outer):
// wave reads = 1KB fully-coalesced spans (was 256B fragments); phase-2
// writes 128B/row (was 64B). LDS T[256][72]=36KB keeps 4 blocks/CU.
// Everything else identical to r21 (GEMM cores frozen at r17).

typedef __attribute__((ext_vector_type(8))) short bf16x8;
typedef __attribute__((ext_vector_type(4))) float f32x4;

#define MFMA16(a, b, c) __builtin_amdgcn_mfma_f32_16x16x32_bf16((a), (b), (c), 0, 0, 0)

__device__ __forceinline__ unsigned short f2bf(float f) {
  unsigned u = __builtin_bit_cast(unsigned, f);
  u += 0x7FFFu + ((u >> 16) & 1u);
  return (unsigned short)(u >> 16);
}

__device__ __forceinline__ float bf2f(unsigned short s) {
  return __builtin_bit_cast(float, (unsigned)s << 16);
}

__device__ __forceinline__ void gload_lds16(const void* g, void* l) {
  __builtin_amdgcn_global_load_lds(
      (const __attribute__((address_space(1))) unsigned int*)g,
      (__attribute__((address_space(3))) unsigned int*)l, 16, 0, 0);
}

// inline-asm LDS read: keeps the compiler from serializing ds_read behind
// in-flight global_load_lds (false alias) with a vmcnt(0).
__device__ __forceinline__ bf16x8 ldsr128(const void* p) {
  bf16x8 r;
  unsigned a = (unsigned)(unsigned long long)p;
  asm volatile("ds_read_b128 %0, %1" : "=v"(r) : "v"(a));
  return r;
}

// ---------------- gate device body (one 256-thr block handles 4 tokens) -----
__device__ __forceinline__ void gate_body(
    int blk, const float* __restrict__ x, const float* __restrict__ Wg,
    const float* __restrict__ bg, int* __restrict__ tok_e,
    float* __restrict__ tok_w, unsigned short* __restrict__ xb) {
  const int wave = threadIdx.x >> 6;
  const int lane = threadIdx.x & 63;
  const int t = blk * 4 + wave;
  const float* xr = x + (size_t)t * 1024;
  unsigned short* xrow = xb + (size_t)t * 1024;
  double acc[8] = {0, 0, 0, 0, 0, 0, 0, 0};
  for (int i = 0; i < 16; ++i) {
    const int d = i * 64 + lane;
    const float vx = xr[d];
    xrow[d] = f2bf(vx);
    const double xv = (double)vx;
    const float* wr = Wg + d * 8;
#pragma unroll
    for (int e = 0; e < 8; ++e) acc[e] += xv * (double)wr[e];
  }
#pragma unroll
  for (int e = 0; e < 8; ++e) {
    double v = acc[e];
#pragma unroll
    for (int off = 32; off > 0; off >>= 1) v += __shfl_xor(v, off, 64);
    acc[e] = v + (double)bg[e];
  }
  if (lane == 0) {
    int e0 = 0;
#pragma unroll
    for (int e = 1; e < 8; ++e)
      if (acc[e] > acc[e0]) e0 = e;
    int e1 = (e0 == 0) ? 1 : 0;
#pragma unroll
    for (int e = 0; e < 8; ++e) {
      if (e != e0 && acc[e] > acc[e1]) e1 = e;
    }
    const double m = acc[e0];
    double s = 0.0;
#pragma unroll
    for (int e = 0; e < 8; ++e) s += exp(acc[e] - m);
    const double p0 = exp(acc[e0] - m) / s;
    const double p1 = exp(acc[e1] - m) / s;
    const double den = p0 + p1 + 1e-9;
    tok_e[2 * t] = e0;
    tok_e[2 * t + 1] = e1;
    tok_w[2 * t] = (float)(p0 / den);
    tok_w[2 * t + 1] = (float)(p1 / den);
  }
}

// ------- transW device body: 256(inner,contiguous) x 64(outer) tile ---------
// Phase 1: each wave-instruction reads a FULL 1KB contiguous span (64 lanes x
// float4 across the inner dim). 4 named loads in flight per group. Pack 4
// outer-elems/row into uint2 LDS writes. Phase 2: 8 lanes/row -> 128B
// contiguous global writes per row.
__device__ __forceinline__ void transW_body(
    int bid, const float* __restrict__ W1, const float* __restrict__ W2,
    unsigned short* __restrict__ W1t, unsigned short* __restrict__ W2t, int FC,
    int f0, int nW1, unsigned short (*T)[72]) {
  const int tid = threadIdx.x;
  const int qi = (tid & 63) * 4;   // inner quad base (0..252)
  const int kt = (tid >> 6) * 16;  // outer 16-row band base (0..48)

  const float* src;        // includes +qi
  size_t srcStride;        // fp32 elems between outer rows
  unsigned short* dstBase; // output row r (inner) at dstBase + r*dstStride
  size_t dstStride;

  if (bid < nW1) {
    // W1[e][k][f] -> W1t[e][f-f0][k]; inner=f (256), outer=k (64)
    const int nf = FC / 256;  // f tiles
    const int e = bid / (16 * nf);
    const int rem = bid % (16 * nf);
    const int fb = (rem % nf) * 256;
    const int kb = (rem / nf) * 64;
    src = W1 + ((size_t)e * 1024 + kb) * 4096 + f0 + fb + qi;
    srcStride = 4096;
    dstBase = W1t + ((size_t)e * FC + fb) * 1024 + kb;
    dstStride = 1024;
  } else {
    // W2[e][f][d] -> W2t[e][d][f-f0]; inner=d (256), outer=f (64)
    const int jd = bid - nW1;
    const int nf = FC / 64;  // f tiles
    const int e = jd / (4 * nf);
    const int rem = jd % (4 * nf);
    const int db = (rem % 4) * 256;
    const int fbl = (rem / 4) * 64;
    src = W2 + ((size_t)e * 4096 + f0 + fbl) * 1024 + db + qi;
    srcStride = 1024;
    dstBase = W2t + ((size_t)e * 1024 + db) * FC + fbl;
    dstStride = FC;
  }

  // phase 1: 4 groups x 4 outer rows; rows kt+g*4 .. kt+g*4+3
#pragma unroll
  for (int g = 0; g < 4; ++g) {
    const float* s = src + (size_t)(kt + g * 4) * srcStride;
    const float4 v0 = *(const float4*)s;
    const float4 v1 = *(const float4*)(s + srcStride);
    const float4 v2 = *(const float4*)(s + 2 * srcStride);
    const float4 v3 = *(const float4*)(s + 3 * srcStride);
    uint2 u;
    u.x = (unsigned)f2bf(v0.x) | ((unsigned)f2bf(v1.x) << 16);
    u.y = (unsigned)f2bf(v2.x) | ((unsigned)f2bf(v3.x) << 16);
    *(uint2*)&T[qi + 0][kt + g * 4] = u;
    u.x = (unsigned)f2bf(v0.y) | ((unsigned)f2bf(v1.y) << 16);
    u.y = (unsigned)f2bf(v2.y) | ((unsigned)f2bf(v3.y) << 16);
    *(uint2*)&T[qi + 1][kt + g * 4] = u;
    u.x = (unsigned)f2bf(v0.z) | ((unsigned)f2bf(v1.z) << 16);
    u.y = (unsigned)f2bf(v2.z) | ((unsigned)f2bf(v3.z) << 16);
    *(uint2*)&T[qi + 2][kt + g * 4] = u;
    u.x = (unsigned)f2bf(v0.w) | ((unsigned)f2bf(v1.w) << 16);
    u.y = (unsigned)f2bf(v2.w) | ((unsigned)f2bf(v3.w) << 16);
    *(uint2*)&T[qi + 3][kt + g * 4] = u;
  }
  __syncthreads();

  // phase 2: row = (tid>>3) + 32*j, chunk = tid&7; 8 lanes -> 128B/row
  const int chunk = tid & 7;
#pragma unroll
  for (int j = 0; j < 8; ++j) {
    const int row = (tid >> 3) + 32 * j;
    *(uint4*)(dstBase + (size_t)row * dstStride + chunk * 8) =
        *(const uint4*)&T[row][chunk * 8];
  }
}

// -------- merged prep: blocks [0,1024) gate, [1024, 1024+nW1+nW2) transW ----
__global__ __launch_bounds__(256) void prep_kernel(
    const float* __restrict__ x, const float* __restrict__ Wg,
    const float* __restrict__ bg, int* __restrict__ tok_e,
    float* __restrict__ tok_w, unsigned short* __restrict__ xb,
    const float* __restrict__ W1, const float* __restrict__ W2,
    unsigned short* __restrict__ W1t, unsigned short* __restrict__ W2t, int FC,
    int f0, int nW1) {
  __shared__ __align__(16) unsigned short T[256][72];
  const int bid = blockIdx.x;
  if (bid < 1024) {
    gate_body(bid, x, Wg, bg, tok_e, tok_w, xb);
  } else {
    transW_body(bid - 1024, W1, W2, W1t, W2t, FC, f0, nW1, T);
  }
}

// -------- standalone versions (fallback when FC < 4096, chunked) ------------
__global__ __launch_bounds__(256) void gate_kernel(
    const float* __restrict__ x, const float* __restrict__ Wg,
    const float* __restrict__ bg, int* __restrict__ tok_e,
    float* __restrict__ tok_w, unsigned short* __restrict__ xb) {
  gate_body(blockIdx.x, x, Wg, bg, tok_e, tok_w, xb);
}

__global__ __launch_bounds__(256) void transW_kernel(
    const float* __restrict__ W1, const float* __restrict__ W2,
    unsigned short* __restrict__ W1t, unsigned short* __restrict__ W2t, int FC,
    int f0, int nW1) {
  __shared__ __align__(16) unsigned short T[256][72];
  transW_body(blockIdx.x, W1, W2, W1t, W2t, FC, f0, nW1, T);
}

// ------- scan + scatter (single block); computes counts internally ----------
__global__ __launch_bounds__(256) void scan_scatter_kernel(
    const int* __restrict__ tok_e, int* __restrict__ counts,
    int* __restrict__ offsets, int* __restrict__ pair_token,
    int* __restrict__ tok_slot) {
  __shared__ int scnt[8];
  __shared__ int scur[8];
  const int tid = threadIdx.x;
  if (tid < 8) scnt[tid] = 0;
  __syncthreads();
  for (int i = tid; i < 8192; i += 256) atomicAdd(&scnt[tok_e[i]], 1);
  __syncthreads();
  if (tid == 0) {
    int s = 0;
    for (int e = 0; e < 8; ++e) {
      counts[e] = scnt[e];
      offsets[e] = s;
      scur[e] = s;
      s += scnt[e];
    }
  }
  __syncthreads();
  for (int t = tid; t < 4096; t += 256) {
#pragma unroll
    for (int j = 0; j < 2; ++j) {
      const int e = tok_e[2 * t + j];
      const int slot = atomicAdd(&scur[e], 1);
      pair_token[slot] = t;
      tok_slot[2 * t + j] = slot;
    }
  }
}

// COMPUTE for 128x64 wave tile: 12 ds_read -> 32 MFMA.
#define COMPUTE32(ALDS, BLDS)                                             \
  {                                                                       \
    bf16x8 a[8], b[4];                                                    \
    _Pragma("unroll") for (int mi = 0; mi < 8; ++mi)                      \
        a[mi] = ldsr128(&ALDS[rdA[mi]]);                                  \
    _Pragma("unroll") for (int nj = 0; nj < 4; ++nj)                      \
        b[nj] = ldsr128(&BLDS[rdB[nj]]);                                  \
    asm volatile("s_waitcnt lgkmcnt(0)" ::: "memory");                    \
    __builtin_amdgcn_sched_barrier(0);                                    \
    _Pragma("unroll") for (int mi = 0; mi < 8; ++mi)                      \
        _Pragma("unroll") for (int nj = 0; nj < 4; ++nj)                  \
        acc[mi][nj] = MFMA16(a[mi], b[nj], acc[mi][nj]);                  \
    __builtin_amdgcn_sched_barrier(0);                                    \
  }

// ---------------- GEMM1: H[slot][n] = relu(xb[tok] @ W1t[e] + b1) -----------
// 256x128 tile, BK=32, 4 waves 2Mx2N (wave tile 128x64), gload_lds + XOR
// swizzle, 2-buf counted vmcnt(6), n-fastest tile order.
__global__ __launch_bounds__(256, 2) void gemm1_kernel(
    const unsigned short* __restrict__ xb,
    const unsigned short* __restrict__ W1t, const float* __restrict__ b1,
    const int* __restrict__ counts, const int* __restrict__ offsets,
    const int* __restrict__ pair_token, unsigned short* __restrict__ H, int FC,
    int f0, int NT) {
  const int bid = blockIdx.x;
  const int e = bid & 7;  // XCD pinning
  const int lid = bid >> 3;
  const int n0 = (lid % NT) * 128;
  const int m0 = (lid / NT) * 256;
  const int count = counts[e];
  if (m0 >= count) return;
  const int offset = offsets[e];

  __shared__ __align__(16) unsigned short Alds[2][256 * 32];
  __shared__ __align__(16) unsigned short Blds[2][128 * 32];
  __shared__ int toklds[256];

  const int tid = threadIdx.x;
  {
    int r = m0 + tid;
    if (r >= count) r = count - 1;
    toklds[tid] = pair_token[offset + r];
  }
  __syncthreads();

  const int lane = tid & 63;
  const int wave = tid >> 6;

  // staging: A 1024 chunks (4/thread), B 512 chunks (2/thread)
  const unsigned short* agp[4];
  const unsigned short* bgp[2];
  int ldsoA[4], ldsoB[2];
#pragma unroll
  for (int j = 0; j < 4; ++j) {
    const int g = tid + 256 * j;
    const int row = g >> 2;
    const int sc = (g & 3) ^ ((row >> 1) & 3);
    agp[j] = xb + (size_t)toklds[row] * 1024 + sc * 8;
    ldsoA[j] = (wave * 64 + 256 * j) * 8;
  }
#pragma unroll
  for (int j = 0; j < 2; ++j) {
    const int g = tid + 256 * j;
    const int row = g >> 2;
    const int sc = (g & 3) ^ ((row >> 1) & 3);
    bgp[j] = W1t + ((size_t)e * FC + n0 + row) * 1024 + sc * 8;
    ldsoB[j] = (wave * 64 + 256 * j) * 8;
  }

  const int wm = (wave >> 1) * 128;
  const int wn = (wave & 1) * 64;
  const int l16 = lane & 15;
  const int lk = lane >> 4;
  int rdA[8], rdB[4];
#pragma unroll
  for (int mi = 0; mi < 8; ++mi) {
    const int row = wm + mi * 16 + l16;
    rdA[mi] = row * 32 + ((lk ^ ((row >> 1) & 3)) << 3);
  }
#pragma unroll
  for (int nj = 0; nj < 4; ++nj) {
    const int row = wn + nj * 16 + l16;
    rdB[nj] = row * 32 + ((lk ^ ((row >> 1) & 3)) << 3);
  }

  f32x4 acc[8][4] = {};

  auto STAGE = [&](int kt, int buf) {  // kt in shorts (k index)
#pragma unroll
    for (int j = 0; j < 4; ++j) gload_lds16(agp[j] + kt, &Alds[buf][ldsoA[j]]);
#pragma unroll
    for (int j = 0; j < 2; ++j) gload_lds16(bgp[j] + kt, &Blds[buf][ldsoB[j]]);
  };

  const int NTk = 32;  // K = 1024 / 32
  STAGE(0, 0);
  for (int t = 0; t < NTk; ++t) {
    __builtin_amdgcn_s_barrier();  // all waves done reading buf[(t+1)&1]
    if (t + 1 < NTk) {
      STAGE((t + 1) * 32, (t + 1) & 1);
      asm volatile("s_waitcnt vmcnt(6)" ::: "memory");  // t's loads landed
    } else {
      asm volatile("s_waitcnt vmcnt(0)" ::: "memory");
    }
    __builtin_amdgcn_s_barrier();  // buf[t&1] staged by all waves
    __builtin_amdgcn_sched_barrier(0);
    COMPUTE32(Alds[t & 1], Blds[t & 1]);
  }

#pragma unroll
  for (int mi = 0; mi < 8; ++mi) {
#pragma unroll
    for (int r = 0; r < 4; ++r) {
      const int rl = m0 + wm + mi * 16 + lk * 4 + r;
      if (rl >= count) continue;
      unsigned short* hrow = H + (size_t)(offset + rl) * FC;
#pragma unroll
      for (int nj = 0; nj < 4; ++nj) {
        const int c = n0 + wn + nj * 16 + l16;
        float v = acc[mi][nj][r] + b1[e * 4096 + f0 + c];
        hrow[c] = f2bf(v > 0.f ? v : 0.f);
      }
    }
  }
}

// ------- GEMM2: P[ks][slot][d] (bf16) = slice_ks(H[slot] @ W2t[e]) (+ b2) ---
// 256x128 tile, split-K=2, private bf16 partial buffers.
__global__ __launch_bounds__(256, 2) void gemm2_kernel(
    const unsigned short* __restrict__ H,
    const unsigned short* __restrict__ W2t, const float* __restrict__ b2,
    const int* __restrict__ counts, const int* __restrict__ offsets,
    unsigned short* __restrict__ P, int FC, int firstChunk) {
  const int bid = blockIdx.x;
  const int e = bid & 7;  // XCD pinning
  const int r2 = bid >> 3;
  const int n0 = (r2 & 7) * 128;          // 8 n-tiles (N=1024), fastest
  const int m0 = ((r2 >> 3) & 15) * 256;  // 16 m-tiles of 256
  const int ks = r2 >> 7;                 // K split 0/1
  const int count = counts[e];
  if (m0 >= count) return;
  const int offset = offsets[e];
  const int KS = FC / 2;
  const int kb = ks * KS;
  unsigned short* Pb = P + (size_t)ks * 8192 * 1024;

  __shared__ __align__(16) unsigned short Alds[2][256 * 32];
  __shared__ __align__(16) unsigned short Blds[2][128 * 32];

  const int tid = threadIdx.x;
  const int lane = tid & 63;
  const int wave = tid >> 6;

  const unsigned short* agp[4];
  const unsigned short* bgp[2];
  int ldsoA[4], ldsoB[2];
#pragma unroll
  for (int j = 0; j < 4; ++j) {
    const int g = tid + 256 * j;
    const int row = g >> 2;
    const int sc = (g & 3) ^ ((row >> 1) & 3);
    int ar = m0 + row;
    if (ar >= count) ar = count - 1;
    agp[j] = H + (size_t)(offset + ar) * FC + kb + sc * 8;
    ldsoA[j] = (wave * 64 + 256 * j) * 8;
  }
#pragma unroll
  for (int j = 0; j < 2; ++j) {
    const int g = tid + 256 * j;
    const int row = g >> 2;
    const int sc = (g & 3) ^ ((row >> 1) & 3);
    bgp[j] = W2t + ((size_t)e * 1024 + n0 + row) * FC + kb + sc * 8;
    ldsoB[j] = (wave * 64 + 256 * j) * 8;
  }

  const int wm = (wave >> 1) * 128;
  const int wn = (wave & 1) * 64;
  const int l16 = lane & 15;
  const int lk = lane >> 4;
  int rdA[8], rdB[4];
#pragma unroll
  for (int mi = 0; mi < 8; ++mi) {
    const int row = wm + mi * 16 + l16;
    rdA[mi] = row * 32 + ((lk ^ ((row >> 1) & 3)) << 3);
  }
#pragma unroll
  for (int nj = 0; nj < 4; ++nj) {
    const int row = wn + nj * 16 + l16;
    rdB[nj] = row * 32 + ((lk ^ ((row >> 1) & 3)) << 3);
  }

  f32x4 acc[8][4] = {};

  auto STAGE = [&](int kt, int buf) {
#pragma unroll
    for (int j = 0; j < 4; ++j) gload_lds16(agp[j] + kt, &Alds[buf][ldsoA[j]]);
#pragma unroll
    for (int j = 0; j < 2; ++j) gload_lds16(bgp[j] + kt, &Blds[buf][ldsoB[j]]);
  };

  const int NTk = KS / 32;
  STAGE(0, 0);
  for (int t = 0; t < NTk; ++t) {
    __builtin_amdgcn_s_barrier();
    if (t + 1 < NTk) {
      STAGE((t + 1) * 32, (t + 1) & 1);
      asm volatile("s_waitcnt vmcnt(6)" ::: "memory");
    } else {
      asm volatile("s_waitcnt vmcnt(0)" ::: "memory");
    }
    __builtin_amdgcn_s_barrier();
    __builtin_amdgcn_sched_barrier(0);
    COMPUTE32(Alds[t & 1], Blds[t & 1]);
  }

#pragma unroll
  for (int mi = 0; mi < 8; ++mi) {
#pragma unroll
    for (int r = 0; r < 4; ++r) {
      const int rl = m0 + wm + mi * 16 + lk * 4 + r;
      if (rl >= count) continue;
      unsigned short* prow = Pb + (size_t)(offset + rl) * 1024;
#pragma unroll
      for (int nj = 0; nj < 4; ++nj) {
        const int c = n0 + wn + nj * 16 + l16;
        float v = acc[mi][nj][r];
        if (ks == 0 && firstChunk) v += b2[e * 1024 + c];
        if (firstChunk) {
          prow[c] = f2bf(v);
        } else {
          prow[c] = f2bf(bf2f(prow[c]) + v);
        }
      }
    }
  }
}

// ---- combine: out[t] = w0*(P0[s0]+P1[s0]) + w1*(P0[s1]+P1[s1]) (bf16 P) ----
__global__ __launch_bounds__(256) void combine_kernel(
    const unsigned short* __restrict__ P, const int* __restrict__ tok_slot,
    const float* __restrict__ tok_w, float* __restrict__ out) {
  const int t = blockIdx.x;
  const int d = threadIdx.x * 4;
  const int s0 = tok_slot[2 * t];
  const int s1 = tok_slot[2 * t + 1];
  const float w0 = tok_w[2 * t];
  const float w1 = tok_w[2 * t + 1];
  const ushort4 a0 = *(const ushort4*)&P[(size_t)s0 * 1024 + d];
  const ushort4 a1 = *(const ushort4*)&P[(size_t)(8192 + s0) * 1024 + d];
  const ushort4 c0 = *(const ushort4*)&P[(size_t)s1 * 1024 + d];
  const ushort4 c1 = *(const ushort4*)&P[(size_t)(8192 + s1) * 1024 + d];
  float4 r;
  r.x = w0 * (bf2f(a0.x) + bf2f(a1.x)) + w1 * (bf2f(c0.x) + bf2f(c1.x));
  r.y = w0 * (bf2f(a0.y) + bf2f(a1.y)) + w1 * (bf2f(c0.y) + bf2f(c1.y));
  r.z = w0 * (bf2f(a0.z) + bf2f(a1.z)) + w1 * (bf2f(c0.z) + bf2f(c1.z));
  r.w = w0 * (bf2f(a0.w) + bf2f(a1.w)) + w1 * (bf2f(c0.w) + bf2f(c1.w));
  *(float4*)&out[(size_t)t * 1024 + d] = r;
}

extern "C" void kernel_launch(void* const* d_in, const int* in_sizes, int n_in,
                              void* d_out, int out_size, void* d_ws,
                              size_t ws_size, hipStream_t stream) {
  const float* x = (const float*)d_in[0];
  const float* Wg = (const float*)d_in[1];
  const float* bg = (const float*)d_in[2];
  const float* W1 = (const float*)d_in[3];
  const float* b1 = (const float*)d_in[4];
  const float* W2 = (const float*)d_in[5];
  const float* b2 = (const float*)d_in[6];
  float* out = (float*)d_out;

  char* w = (char*)d_ws;
  int* counts = (int*)w;
  int* offsets = counts + 16;
  int* tok_e = (int*)(w + 1024);
  float* tok_w = (float*)(w + 1024 + 32768);
  int* pair_token = (int*)(w + 1024 + 65536);
  int* tok_slot = (int*)(w + 1024 + 98304);
  unsigned short* xb = (unsigned short*)(w + 256 * 1024);  // 8MB
  unsigned short* P =
      (unsigned short*)(w + 256 * 1024 + 8 * 1024 * 1024);  // 32MB bf16 x2
  char* big = w + 256 * 1024 + 8 * 1024 * 1024 + 32 * 1024 * 1024;
  const size_t avail =
      ws_size - (256 * 1024 + 8 * 1024 * 1024 + 32 * 1024 * 1024);

  // per-chunk: W1t 16384*FC + W2t 16384*FC + H 16384*FC bytes
  int FC = 4096;
  while (FC > 512 && (size_t)FC * 49152 > avail) FC >>= 1;

  unsigned short* W1t = (unsigned short*)big;
  unsigned short* W2t = W1t + (size_t)8 * FC * 1024;
  unsigned short* Hc = W2t + (size_t)8 * 1024 * FC;

  const int NT = FC / 128;
  const int nW1 = 8 * (FC / 256) * 16;  // 256f x 64k tiles
  const int nW2 = 8 * 4 * (FC / 64);    // 256d x 64f tiles

  if (FC == 4096) {
    prep_kernel<<<1024 + nW1 + nW2, 256, 0, stream>>>(
        x, Wg, bg, tok_e, tok_w, xb, W1, W2, W1t, W2t, FC, 0, nW1);
    scan_scatter_kernel<<<1, 256, 0, stream>>>(tok_e, counts, offsets,
                                               pair_token, tok_slot);
    gemm1_kernel<<<8 * 16 * NT, 256, 0, stream>>>(
        xb, W1t, b1, counts, offsets, pair_token, Hc, FC, 0, NT);
    gemm2_kernel<<<8 * 8 * 16 * 2, 256, 0, stream>>>(
        Hc, W2t, b2, counts, offsets, P, FC, 1);
  } else {
    gate_kernel<<<1024, 256, 0, stream>>>(x, Wg, bg, tok_e, tok_w, xb);
    scan_scatter_kernel<<<1, 256, 0, stream>>>(tok_e, counts, offsets,
                                               pair_token, tok_slot);
    for (int f0 = 0; f0 < 4096; f0 += FC) {
      transW_kernel<<<nW1 + nW2, 256, 0, stream>>>(W1, W2, W1t, W2t, FC, f0,
                                                   nW1);
      gemm1_kernel<<<8 * 16 * NT, 256, 0, stream>>>(
          xb, W1t, b1, counts, offsets, pair_token, Hc, FC, f0, NT);
      gemm2_kernel<<<8 * 8 * 16 * 2, 256, 0, stream>>>(
          Hc, W2t, b2, counts, offsets, P, FC, f0 == 0 ? 1 : 0);
    }
  }
  combine_kernel<<<4096, 256, 0, stream>>>(P, tok_slot, tok_w, out);
}